// Round 1
// baseline (920.510 us; speedup 1.0000x reference)
//
#include <hip/hip_runtime.h>
#include <hip/hip_bf16.h>

#define NDIM 64
#define NREL 8
#define NACT 4
#define SCALE 0.125f
#define LN_EPS 1e-5f

__device__ __forceinline__ float wave_sum64(float v) {
#pragma unroll
  for (int off = 32; off > 0; off >>= 1) v += __shfl_xor(v, off, 64);
  return v;
}

// K0: relkey[r][o] = mean_o'(W_r[r]) @ Wk2 + Wk_bias ; keyrule[j][o] = rule_emb[rid[j]] @ Wk3
__global__ void k0_precompute(const float* __restrict__ W_r,
                              const float* __restrict__ Wk_w,
                              const float* __restrict__ Wk_bias,
                              const float* __restrict__ rule_emb,
                              const int* __restrict__ rule_ids,
                              float* __restrict__ relkey,
                              float* __restrict__ keyrule) {
  __shared__ float relemb[NREL * NDIM];
  int tid = threadIdx.x;
  for (int idx = tid; idx < NREL * NDIM; idx += 256) {
    int r = idx >> 6, i = idx & 63;
    const float* wr = W_r + (size_t)(r * NDIM + i) * NDIM;
    float s = 0.f;
#pragma unroll
    for (int o = 0; o < NDIM; ++o) s += wr[o];
    relemb[idx] = s * (1.0f / NDIM);
  }
  __syncthreads();
  for (int idx = tid; idx < NREL * NDIM; idx += 256) {
    int r = idx >> 6, o = idx & 63;
    float s = Wk_bias[o];
#pragma unroll
    for (int i = 0; i < NDIM; ++i) s += relemb[r * NDIM + i] * Wk_w[(NDIM + i) * NDIM + o];
    relkey[idx] = s;
  }
  if (tid < NACT * NDIM) {
    int j = tid >> 6, o = tid & 63;
    int rid = rule_ids[j];
    float s = 0.f;
#pragma unroll
    for (int i = 0; i < NDIM; ++i) s += rule_emb[rid * NDIM + i] * Wk_w[(2 * NDIM + i) * NDIM + o];
    keyrule[tid] = s;
  }
}

// K1: per-node Q = x@Wq+bq, KB = x@Wk1, QR[n][r] = Q·relkey[r], SR[n][j] = Q·keyrule[j]
__global__ void k1_node(const float* __restrict__ x,
                        const float* __restrict__ Wq_w,
                        const float* __restrict__ Wq_bias,
                        const float* __restrict__ Wk_w,
                        const float* __restrict__ relkey,
                        const float* __restrict__ keyrule,
                        float* __restrict__ Q, float* __restrict__ KB,
                        float* __restrict__ QR, float* __restrict__ SR,
                        int n_nodes) {
  int lane = threadIdx.x & 63;
  int wv = threadIdx.x >> 6;
  int gw = blockIdx.x * 4 + wv;
  int nw = gridDim.x * 4;
  float wq[NDIM], wk[NDIM];
#pragma unroll
  for (int i = 0; i < NDIM; ++i) {
    wq[i] = Wq_w[i * NDIM + lane];
    wk[i] = Wk_w[i * NDIM + lane];
  }
  float rk[NREL];
#pragma unroll
  for (int r = 0; r < NREL; ++r) rk[r] = relkey[r * NDIM + lane];
  float kr[NACT];
#pragma unroll
  for (int j = 0; j < NACT; ++j) kr[j] = keyrule[j * NDIM + lane];
  float bq = Wq_bias[lane];
  for (int n = gw; n < n_nodes; n += nw) {
    float xv = x[(size_t)n * NDIM + lane];
    float q = bq, kb = 0.f;
#pragma unroll
    for (int i = 0; i < NDIM; ++i) {
      float xi = __shfl(xv, i, 64);
      q += xi * wq[i];
      kb += xi * wk[i];
    }
    Q[(size_t)n * NDIM + lane] = q;
    KB[(size_t)n * NDIM + lane] = kb;
#pragma unroll
    for (int r = 0; r < NREL; ++r) {
      float s = wave_sum64(q * rk[r]);
      if (lane == r) QR[(size_t)n * NREL + r] = s;
    }
#pragma unroll
    for (int j = 0; j < NACT; ++j) {
      float s = wave_sum64(q * kr[j]);
      if (lane == j) SR[(size_t)n * NACT + j] = s;
    }
  }
}

__global__ void k2_hist(const int* __restrict__ dst, int* __restrict__ counts, int E) {
  int e = blockIdx.x * blockDim.x + threadIdx.x;
  if (e < E) atomicAdd(&counts[dst[e]], 1);
}

// single-block exclusive scan over counts -> offsets[0..n], cursor copy
__global__ void k2_scan(const int* __restrict__ counts, int* __restrict__ offsets,
                        int* __restrict__ cursor, int n) {
  __shared__ int buf[1024];
  __shared__ int running_s;
  int tid = threadIdx.x;
  if (tid == 0) running_s = 0;
  __syncthreads();
  for (int base = 0; base < n; base += 1024) {
    int v = (base + tid < n) ? counts[base + tid] : 0;
    buf[tid] = v;
    __syncthreads();
    int xinc = v;
    for (int off = 1; off < 1024; off <<= 1) {
      int y = (tid >= off) ? buf[tid - off] : 0;
      __syncthreads();
      xinc += y;
      buf[tid] = xinc;
      __syncthreads();
    }
    int run = running_s;
    int excl = run + xinc - v;
    if (base + tid < n) {
      offsets[base + tid] = excl;
      cursor[base + tid] = excl;
    }
    __syncthreads();
    if (tid == 0) running_s = run + buf[1023];
    __syncthreads();
  }
  if (tid == 0) offsets[n] = running_s;
}

__global__ void k2_scatter(const int* __restrict__ dst, int* __restrict__ cursor,
                           int* __restrict__ csr, int E) {
  int e = blockIdx.x * blockDim.x + threadIdx.x;
  if (e < E) {
    int p = atomicAdd(&cursor[dst[e]], 1);
    csr[p] = e;
  }
}

// K4: one wave per node. Pass1: per-edge score (wave-wide dot) + online max/sum (stores raw
// scores for pass2). Pass2: per-edge mean-attn weight, accumulate w*x[src] into A[n][et][:].
__global__ void k4_attn(const float* __restrict__ x,
                        const float* __restrict__ Q, const float* __restrict__ KB,
                        const float* __restrict__ QR, const float* __restrict__ SR,
                        const int* __restrict__ offsets, const int* __restrict__ csr,
                        const int* __restrict__ srcp, const int* __restrict__ etp,
                        float* __restrict__ scores, __hip_bfloat16* __restrict__ A,
                        int n_nodes) {
  __shared__ float A_lds[4][NREL * NDIM];
  int lane = threadIdx.x & 63;
  int wv = threadIdx.x >> 6;
  int n = blockIdx.x * 4 + wv;
  if (n >= n_nodes) return;
  float* Aw = A_lds[wv];
#pragma unroll
  for (int c = 0; c < NREL; ++c) Aw[c * NDIM + lane] = 0.f;
  int s0 = offsets[n], s1 = offsets[n + 1];
  float qo = Q[(size_t)n * NDIM + lane];
  float4 sr4 = *reinterpret_cast<const float4*>(SR + (size_t)n * 4);
  float m0 = -1e30f, m1 = -1e30f, m2 = -1e30f, m3 = -1e30f;
  float t0 = 0.f, t1 = 0.f, t2 = 0.f, t3 = 0.f;
  for (int idx = s0; idx < s1; ++idx) {
    int e = csr[idx];
    int sN = srcp[e];
    int r = etp[e];
    float kv = KB[(size_t)sN * NDIM + lane];
    float dot = wave_sum64(qo * kv);
    float base = dot + QR[(size_t)n * NREL + r];
    float4 sc;
    sc.x = (base + sr4.x) * SCALE;
    sc.y = (base + sr4.y) * SCALE;
    sc.z = (base + sr4.z) * SCALE;
    sc.w = (base + sr4.w) * SCALE;
    if (lane == 0) *reinterpret_cast<float4*>(scores + (size_t)idx * 4) = sc;
    float nm;
    nm = fmaxf(m0, sc.x); t0 = t0 * __expf(m0 - nm) + __expf(sc.x - nm); m0 = nm;
    nm = fmaxf(m1, sc.y); t1 = t1 * __expf(m1 - nm) + __expf(sc.y - nm); m1 = nm;
    nm = fmaxf(m2, sc.z); t2 = t2 * __expf(m2 - nm) + __expf(sc.z - nm); m2 = nm;
    nm = fmaxf(m3, sc.w); t3 = t3 * __expf(m3 - nm) + __expf(sc.w - nm); m3 = nm;
  }
  float i0 = (t0 > 0.f) ? 1.f / t0 : 0.f;
  float i1 = (t1 > 0.f) ? 1.f / t1 : 0.f;
  float i2 = (t2 > 0.f) ? 1.f / t2 : 0.f;
  float i3 = (t3 > 0.f) ? 1.f / t3 : 0.f;
  for (int idx = s0; idx < s1; ++idx) {
    float4 sc = *reinterpret_cast<const float4*>(scores + (size_t)idx * 4);
    float w = 0.25f * (__expf(sc.x - m0) * i0 + __expf(sc.y - m1) * i1 +
                       __expf(sc.z - m2) * i2 + __expf(sc.w - m3) * i3);
    int e = csr[idx];
    int sN = srcp[e];
    int r = etp[e];
    float xv = x[(size_t)sN * NDIM + lane];
    Aw[r * NDIM + lane] += w * xv;
  }
#pragma unroll
  for (int c = 0; c < NREL; ++c)
    A[(size_t)n * (NREL * NDIM) + c * NDIM + lane] = __float2bfloat16(Aw[c * NDIM + lane]);
}

// K5: out = relu(LN(A(50000x512,bf16) @ W_r(512x64) + bias))
__global__ void k5_gemm_ln(const __hip_bfloat16* __restrict__ A,
                           const float* __restrict__ W_r,
                           const float* __restrict__ bias,
                           const float* __restrict__ ln_g, const float* __restrict__ ln_b,
                           float* __restrict__ out, int n_nodes) {
  __shared__ float As[64][65];
  __shared__ float Ws[64][65];
  __shared__ float Cs[64][64];
  int tid = threadIdx.x;
  int tx = tid & 15, ty = tid >> 4;
  int n0 = blockIdx.x * 64;
  float acc[4][4] = {};
  for (int kb = 0; kb < 512; kb += 64) {
    for (int idx = tid; idx < 64 * 64; idx += 256) {
      int r = idx >> 6, c = idx & 63;
      int n = n0 + r;
      As[r][c] = (n < n_nodes) ? __bfloat162float(A[(size_t)n * 512 + kb + c]) : 0.f;
      Ws[r][c] = W_r[(size_t)(kb + r) * 64 + c];
    }
    __syncthreads();
#pragma unroll 8
    for (int k = 0; k < 64; ++k) {
      float a0 = As[ty * 4 + 0][k], a1 = As[ty * 4 + 1][k];
      float a2 = As[ty * 4 + 2][k], a3 = As[ty * 4 + 3][k];
      float w0 = Ws[k][tx * 4 + 0], w1 = Ws[k][tx * 4 + 1];
      float w2 = Ws[k][tx * 4 + 2], w3 = Ws[k][tx * 4 + 3];
      acc[0][0] += a0 * w0; acc[0][1] += a0 * w1; acc[0][2] += a0 * w2; acc[0][3] += a0 * w3;
      acc[1][0] += a1 * w0; acc[1][1] += a1 * w1; acc[1][2] += a1 * w2; acc[1][3] += a1 * w3;
      acc[2][0] += a2 * w0; acc[2][1] += a2 * w1; acc[2][2] += a2 * w2; acc[2][3] += a2 * w3;
      acc[3][0] += a3 * w0; acc[3][1] += a3 * w1; acc[3][2] += a3 * w2; acc[3][3] += a3 * w3;
    }
    __syncthreads();
  }
#pragma unroll
  for (int i = 0; i < 4; ++i)
#pragma unroll
    for (int j = 0; j < 4; ++j)
      Cs[ty * 4 + i][tx * 4 + j] = acc[i][j] + bias[tx * 4 + j];
  __syncthreads();
  int lane = tid & 63;
  int wv = tid >> 6;
  float g = ln_g[lane], b = ln_b[lane];
  for (int rr = 0; rr < 16; ++rr) {
    int row = wv * 16 + rr;
    int n = n0 + row;
    if (n >= n_nodes) break;
    float v = Cs[row][lane];
    float mu = wave_sum64(v) * (1.f / 64);
    float d = v - mu;
    float var = wave_sum64(d * d) * (1.f / 64);
    float y = d * rsqrtf(var + LN_EPS) * g + b;
    out[(size_t)n * 64 + lane] = fmaxf(y, 0.f);
  }
}

extern "C" void kernel_launch(void* const* d_in, const int* in_sizes, int n_in,
                              void* d_out, int out_size, void* d_ws, size_t ws_size,
                              hipStream_t stream) {
  (void)n_in; (void)out_size; (void)ws_size;
  const float* x = (const float*)d_in[0];
  const int* ei = (const int*)d_in[1];
  const int* et = (const int*)d_in[2];
  const int* rid = (const int*)d_in[3];
  const float* W_r = (const float*)d_in[4];
  const float* Wq_w = (const float*)d_in[5];
  const float* Wq_b = (const float*)d_in[6];
  const float* Wk_w = (const float*)d_in[7];
  const float* Wk_b = (const float*)d_in[8];
  const float* rule_emb = (const float*)d_in[9];
  const float* bias = (const float*)d_in[10];
  const float* ln_g = (const float*)d_in[11];
  const float* ln_b = (const float*)d_in[12];

  int N = in_sizes[0] / NDIM;
  int E = in_sizes[2];
  const int* srcp = ei;
  const int* dstp = ei + E;

  char* p = (char*)d_ws;
  auto alloc = [&](size_t bytes) {
    void* r = (void*)p;
    p += (bytes + 255) & ~(size_t)255;
    return r;
  };
  float* Q = (float*)alloc((size_t)N * NDIM * 4);
  float* KB = (float*)alloc((size_t)N * NDIM * 4);
  float* QR = (float*)alloc((size_t)N * NREL * 4);
  float* SR = (float*)alloc((size_t)N * NACT * 4);
  float* relkey = (float*)alloc(NREL * NDIM * 4);
  float* keyrule = (float*)alloc(NACT * NDIM * 4);
  int* counts = (int*)alloc((size_t)N * 4);
  int* offsets = (int*)alloc((size_t)(N + 1) * 4);
  int* cursor = (int*)alloc((size_t)N * 4);
  int* csr = (int*)alloc((size_t)E * 4);
  float* scores = (float*)alloc((size_t)E * 4 * 4);
  __hip_bfloat16* A = (__hip_bfloat16*)alloc((size_t)N * (NREL * NDIM) * 2);

  hipMemsetAsync(counts, 0, (size_t)N * 4, stream);
  k0_precompute<<<1, 256, 0, stream>>>(W_r, Wk_w, Wk_b, rule_emb, rid, relkey, keyrule);
  k1_node<<<1024, 256, 0, stream>>>(x, Wq_w, Wq_b, Wk_w, relkey, keyrule, Q, KB, QR, SR, N);
  k2_hist<<<(E + 255) / 256, 256, 0, stream>>>(dstp, counts, E);
  k2_scan<<<1, 1024, 0, stream>>>(counts, offsets, cursor, N);
  k2_scatter<<<(E + 255) / 256, 256, 0, stream>>>(dstp, cursor, csr, E);
  k4_attn<<<(N + 3) / 4, 256, 0, stream>>>(x, Q, KB, QR, SR, offsets, csr, srcp, et, scores, A, N);
  k5_gemm_ln<<<(N + 63) / 64, 256, 0, stream>>>(A, W_r, bias, ln_g, ln_b, (float*)d_out, N);
}

// Round 3
// 473.818 us; speedup vs baseline: 1.9428x; 1.9428x over previous
//
#include <hip/hip_runtime.h>
#include <hip/hip_bf16.h>

#define NDIM 64
#define NREL 8
#define SCALE 0.125f
#define LN_EPS 1e-5f

__device__ __forceinline__ float wave_sum64(float v) {
#pragma unroll
  for (int off = 32; off > 0; off >>= 1) v += __shfl_xor(v, off, 64);
  return v;
}
__device__ __forceinline__ float wave_max64(float v) {
#pragma unroll
  for (int off = 32; off > 0; off >>= 1) v = fmaxf(v, __shfl_xor(v, off, 64));
  return v;
}

// K0: relkey[r][o] = mean_last(W_r[r]) @ Wk2   (Wk_bias cancels in segment softmax)
__global__ void k0_relkey(const float* __restrict__ W_r,
                          const float* __restrict__ Wk_w,
                          float* __restrict__ relkey) {
  __shared__ float relemb[NREL * NDIM];
  int tid = threadIdx.x;
  for (int idx = tid; idx < NREL * NDIM; idx += 256) {
    int r = idx >> 6, i = idx & 63;
    const float* wr = W_r + (size_t)(r * NDIM + i) * NDIM;
    float s = 0.f;
#pragma unroll
    for (int o = 0; o < NDIM; ++o) s += wr[o];
    relemb[idx] = s * (1.0f / NDIM);
  }
  __syncthreads();
  for (int idx = tid; idx < NREL * NDIM; idx += 256) {
    int r = idx >> 6, o = idx & 63;
    float s = 0.f;
#pragma unroll
    for (int i = 0; i < NDIM; ++i) s += relemb[r * NDIM + i] * Wk_w[(NDIM + i) * NDIM + o];
    relkey[idx] = s;
  }
}

// K1: [Q | KB] = x @ [Wq | Wk1], Q += Wq_bias. Tiled fp32 GEMM, 64 rows x 128 cols per block.
__global__ void k1_qkb(const float* __restrict__ x,
                       const float* __restrict__ Wq_w,
                       const float* __restrict__ Wq_bias,
                       const float* __restrict__ Wk_w,
                       float* __restrict__ Q, float* __restrict__ KB, int n_nodes) {
  __shared__ float xs[64][68];
  __shared__ float ws[64][128];
  int tid = threadIdx.x;
  int n0 = blockIdx.x * 64;
  for (int idx = tid; idx < 64 * 128; idx += 256) {
    int r = idx >> 7, c = idx & 127;
    ws[r][c] = (c < 64) ? Wq_w[r * 64 + c] : Wk_w[r * 64 + (c - 64)];
  }
  for (int idx = tid; idx < 64 * 16; idx += 256) {
    int r = idx >> 4, c4 = (idx & 15) * 4;
    int n = n0 + r;
    float4 v = make_float4(0.f, 0.f, 0.f, 0.f);
    if (n < n_nodes) v = *reinterpret_cast<const float4*>(x + (size_t)n * 64 + c4);
    *reinterpret_cast<float4*>(&xs[r][c4]) = v;
  }
  __syncthreads();
  int tx = tid & 15, ty = tid >> 4;
  float acc[4][8] = {};
  for (int k = 0; k < 64; k += 4) {
    float4 a[4];
#pragma unroll
    for (int i = 0; i < 4; ++i) a[i] = *reinterpret_cast<float4*>(&xs[ty * 4 + i][k]);
#pragma unroll
    for (int kk = 0; kk < 4; ++kk) {
      float4 w0 = *reinterpret_cast<float4*>(&ws[k + kk][tx * 8]);
      float4 w1 = *reinterpret_cast<float4*>(&ws[k + kk][tx * 8 + 4]);
#pragma unroll
      for (int i = 0; i < 4; ++i) {
        float av = (kk == 0) ? a[i].x : (kk == 1) ? a[i].y : (kk == 2) ? a[i].z : a[i].w;
        acc[i][0] += av * w0.x; acc[i][1] += av * w0.y;
        acc[i][2] += av * w0.z; acc[i][3] += av * w0.w;
        acc[i][4] += av * w1.x; acc[i][5] += av * w1.y;
        acc[i][6] += av * w1.z; acc[i][7] += av * w1.w;
      }
    }
  }
#pragma unroll
  for (int i = 0; i < 4; ++i) {
    int n = n0 + ty * 4 + i;
    if (n >= n_nodes) continue;
#pragma unroll
    for (int j = 0; j < 8; ++j) {
      int c = tx * 8 + j;
      if (c < 64) Q[(size_t)n * 64 + c] = acc[i][j] + Wq_bias[c];
      else KB[(size_t)n * 64 + (c - 64)] = acc[i][j];
    }
  }
}

// K1b: QR[n][r] = Q[n] . relkey[r]
__global__ void k1b_qr(const float* __restrict__ Q, const float* __restrict__ relkey,
                       float* __restrict__ QR, int n_nodes) {
  int lane = threadIdx.x & 63, wv = threadIdx.x >> 6;
  int n = blockIdx.x * 4 + wv;
  if (n >= n_nodes) return;
  float q = Q[(size_t)n * 64 + lane];
#pragma unroll
  for (int r = 0; r < NREL; ++r) {
    float s = wave_sum64(q * relkey[r * 64 + lane]);
    if (lane == r) QR[(size_t)n * NREL + r] = s;
  }
}

__global__ void k2_hist(const int* __restrict__ dst, int* __restrict__ counts, int E) {
  int e = blockIdx.x * blockDim.x + threadIdx.x;
  if (e < E) atomicAdd(&counts[dst[e]], 1);
}

// hierarchical scan: A (per-1024-block exclusive) -> B (block sums) -> C (add)
__global__ void scan_a(const int* __restrict__ counts, int* __restrict__ partial,
                       int* __restrict__ blocksums, int n) {
  __shared__ int wsum[4];
  int tid = threadIdx.x, lane = tid & 63, wv = tid >> 6;
  int base = blockIdx.x * 1024 + tid * 4;
  int4 v = make_int4(0, 0, 0, 0);
  if (base + 3 < n) v = *reinterpret_cast<const int4*>(counts + base);
  else {
    if (base < n) v.x = counts[base];
    if (base + 1 < n) v.y = counts[base + 1];
    if (base + 2 < n) v.z = counts[base + 2];
  }
  int tsum = v.x + v.y + v.z + v.w;
  int s = tsum;
#pragma unroll
  for (int off = 1; off < 64; off <<= 1) {
    int y = __shfl_up(s, off, 64);
    if (lane >= off) s += y;
  }
  if (lane == 63) wsum[wv] = s;
  __syncthreads();
  int woff = 0;
  for (int w = 0; w < wv; ++w) woff += wsum[w];
  int o0 = woff + s - tsum;
  if (base < n) partial[base] = o0;
  if (base + 1 < n) partial[base + 1] = o0 + v.x;
  if (base + 2 < n) partial[base + 2] = o0 + v.x + v.y;
  if (base + 3 < n) partial[base + 3] = o0 + v.x + v.y + v.z;
  if (tid == 255) blocksums[blockIdx.x] = woff + s;
}

__global__ void scan_b(const int* __restrict__ blocksums, int* __restrict__ blockoff,
                       int nb, int* __restrict__ offsets, int n) {
  int lane = threadIdx.x;
  int v = (lane < nb) ? blocksums[lane] : 0;
  int s = v;
#pragma unroll
  for (int off = 1; off < 64; off <<= 1) {
    int y = __shfl_up(s, off, 64);
    if (lane >= off) s += y;
  }
  if (lane < nb) blockoff[lane] = s - v;
  if (lane == 63) offsets[n] = s;
}

__global__ void scan_c(const int* __restrict__ partial, const int* __restrict__ blockoff,
                       int* __restrict__ offsets, int* __restrict__ cursor, int n) {
  int i = blockIdx.x * 256 + threadIdx.x;
  if (i < n) {
    int v = partial[i] + blockoff[i >> 10];
    offsets[i] = v;
    cursor[i] = v;
  }
}

__global__ void k2_scatter(const int* __restrict__ dst, int* __restrict__ cursor,
                           int* __restrict__ csr, int E) {
  int e = blockIdx.x * blockDim.x + threadIdx.x;
  if (e < E) {
    int p = atomicAdd(&cursor[dst[e]], 1);
    csr[p] = e;
  }
}

// K3: edge-parallel scores in CSR position order. 16 lanes per edge, float4 gathers.
__global__ void k3_scores(const float* __restrict__ Q, const float* __restrict__ KB,
                          const float* __restrict__ QR,
                          const int* __restrict__ csr, const int* __restrict__ srcp,
                          const int* __restrict__ dstp, const int* __restrict__ etp,
                          float* __restrict__ scores, int E) {
  int tid = threadIdx.x;
  int lane = tid & 63;
  int li = lane & 15, sub = lane >> 4, wv = tid >> 6;
  int pos = blockIdx.x * 16 + wv * 4 + sub;
  if (pos >= E) return;
  int e = csr[pos];
  int dn = dstp[e], sn = srcp[e], r = etp[e];
  float4 q = *reinterpret_cast<const float4*>(Q + (size_t)dn * 64 + li * 4);
  float4 k = *reinterpret_cast<const float4*>(KB + (size_t)sn * 64 + li * 4);
  float p = q.x * k.x + q.y * k.y + q.z * k.z + q.w * k.w;
#pragma unroll
  for (int off = 1; off < 16; off <<= 1) p += __shfl_xor(p, off, 64);
  if (li == 0) scores[pos] = (p + QR[(size_t)dn * NREL + r]) * SCALE;
}

// K4: one wave per node. Lane-parallel softmax over contiguous scores,
// then broadcast loop accumulating w*x[src] into 8 register accumulators.
__global__ void k4_agg(const float* __restrict__ x, const float* __restrict__ scores,
                       const int* __restrict__ offsets, const int* __restrict__ csr,
                       const int* __restrict__ srcp, const int* __restrict__ etp,
                       __hip_bfloat16* __restrict__ A, int n_nodes) {
  int lane = threadIdx.x & 63, wv = threadIdx.x >> 6;
  int n = blockIdx.x * 4 + wv;
  if (n >= n_nodes) return;
  int s0 = offsets[n], s1 = offsets[n + 1];
  float acc[8] = {0.f, 0.f, 0.f, 0.f, 0.f, 0.f, 0.f, 0.f};
  if (s1 > s0) {
    float m = -1e30f;
    for (int c = s0; c < s1; c += 64) {
      int p = c + lane;
      float s = (p < s1) ? scores[p] : -1e30f;
      m = fmaxf(m, s);
    }
    m = wave_max64(m);
    float t = 0.f;
    for (int c = s0; c < s1; c += 64) {
      int p = c + lane;
      t += (p < s1) ? __expf(scores[p] - m) : 0.f;
    }
    t = wave_sum64(t);
    float inv = 1.0f / t;
    for (int c = s0; c < s1; c += 64) {
      int p = c + lane;
      bool valid = p < s1;
      int e = valid ? csr[p] : 0;
      int sl = valid ? srcp[e] : 0;
      int rl = valid ? etp[e] : 0;
      float wl = valid ? __expf(scores[p] - m) * inv : 0.f;
      int cnt = min(64, s1 - c);
#pragma unroll 4
      for (int i = 0; i < cnt; ++i) {
        float wgt = __shfl(wl, i, 64);
        int sn = __shfl(sl, i, 64);
        int rr = __shfl(rl, i, 64);
        float v = wgt * x[((size_t)sn << 6) + lane];
#pragma unroll
        for (int r = 0; r < 8; ++r) acc[r] += (rr == r) ? v : 0.f;
      }
    }
  }
#pragma unroll
  for (int r = 0; r < 8; ++r)
    A[(size_t)n * 512 + r * 64 + lane] = __float2bfloat16(acc[r]);
}

// K5: out = relu(LN(A(50000x512 bf16) @ W_r(512x64) + bias))
__global__ void k5_gemm_ln(const __hip_bfloat16* __restrict__ A,
                           const float* __restrict__ W_r,
                           const float* __restrict__ bias,
                           const float* __restrict__ ln_g, const float* __restrict__ ln_b,
                           float* __restrict__ out, int n_nodes) {
  __shared__ float As[64][68];
  __shared__ float Ws[64][64];
  __shared__ float Cs[64][64];
  int tid = threadIdx.x, tx = tid & 15, ty = tid >> 4;
  int n0 = blockIdx.x * 64;
  float acc[4][4] = {};
  for (int kb = 0; kb < 512; kb += 64) {
    {
      int r = tid >> 2, c0 = (tid & 3) * 16;
      int n = n0 + r;
      if (n < n_nodes) {
        const ushort* ap = (const ushort*)(A + (size_t)n * 512 + kb + c0);
        uint4 u0 = *reinterpret_cast<const uint4*>(ap);
        uint4 u1 = *reinterpret_cast<const uint4*>(ap + 8);
        ushort us[16];
        *reinterpret_cast<uint4*>(us) = u0;
        *reinterpret_cast<uint4*>(us + 8) = u1;
#pragma unroll
        for (int j = 0; j < 16; ++j)
          As[r][c0 + j] = __uint_as_float(((unsigned)us[j]) << 16);
      } else {
#pragma unroll
        for (int j = 0; j < 16; ++j) As[r][c0 + j] = 0.f;
      }
    }
    for (int idx = tid; idx < 64 * 64; idx += 256) {
      int r = idx >> 6, c = idx & 63;
      Ws[r][c] = W_r[(size_t)(kb + r) * 64 + c];
    }
    __syncthreads();
    for (int k = 0; k < 64; k += 4) {
      float4 a[4];
#pragma unroll
      for (int i = 0; i < 4; ++i) a[i] = *reinterpret_cast<float4*>(&As[ty * 4 + i][k]);
#pragma unroll
      for (int kk = 0; kk < 4; ++kk) {
        float4 w = *reinterpret_cast<float4*>(&Ws[k + kk][tx * 4]);
#pragma unroll
        for (int i = 0; i < 4; ++i) {
          float av = (kk == 0) ? a[i].x : (kk == 1) ? a[i].y : (kk == 2) ? a[i].z : a[i].w;
          acc[i][0] += av * w.x;
          acc[i][1] += av * w.y;
          acc[i][2] += av * w.z;
          acc[i][3] += av * w.w;
        }
      }
    }
    __syncthreads();
  }
#pragma unroll
  for (int i = 0; i < 4; ++i)
#pragma unroll
    for (int j = 0; j < 4; ++j)
      Cs[ty * 4 + i][tx * 4 + j] = acc[i][j] + bias[tx * 4 + j];
  __syncthreads();
  int lane = tid & 63, wv = tid >> 6;
  float g = ln_g[lane], b = ln_b[lane];
  for (int rr = 0; rr < 16; ++rr) {
    int row = wv * 16 + rr;
    int n = n0 + row;
    if (n >= n_nodes) break;
    float v = Cs[row][lane];
    float mu = wave_sum64(v) * (1.f / 64);
    float d = v - mu;
    float var = wave_sum64(d * d) * (1.f / 64);
    float y = d * rsqrtf(var + LN_EPS) * g + b;
    out[(size_t)n * 64 + lane] = fmaxf(y, 0.f);
  }
}

extern "C" void kernel_launch(void* const* d_in, const int* in_sizes, int n_in,
                              void* d_out, int out_size, void* d_ws, size_t ws_size,
                              hipStream_t stream) {
  (void)n_in; (void)out_size; (void)ws_size;
  const float* x = (const float*)d_in[0];
  const int* ei = (const int*)d_in[1];
  const int* et = (const int*)d_in[2];
  const float* W_r = (const float*)d_in[4];
  const float* Wq_w = (const float*)d_in[5];
  const float* Wq_b = (const float*)d_in[6];
  const float* Wk_w = (const float*)d_in[7];
  const float* bias = (const float*)d_in[10];
  const float* ln_g = (const float*)d_in[11];
  const float* ln_b = (const float*)d_in[12];

  int N = in_sizes[0] / NDIM;
  int E = in_sizes[2];
  const int* srcp = ei;
  const int* dstp = ei + E;

  char* p = (char*)d_ws;
  auto alloc = [&](size_t bytes) {
    void* r = (void*)p;
    p += (bytes + 255) & ~(size_t)255;
    return r;
  };
  float* Q = (float*)alloc((size_t)N * NDIM * 4);
  float* KB = (float*)alloc((size_t)N * NDIM * 4);
  float* QR = (float*)alloc((size_t)N * NREL * 4);
  float* relkey = (float*)alloc(NREL * NDIM * 4);
  int* counts = (int*)alloc((size_t)N * 4);
  int* partial = (int*)alloc((size_t)N * 4);
  int* offsets = (int*)alloc((size_t)(N + 1) * 4);
  int* cursor = (int*)alloc((size_t)N * 4);
  int* blocksums = (int*)alloc(64 * 4);
  int* blockoff = (int*)alloc(64 * 4);
  int* csr = (int*)alloc((size_t)E * 4);
  float* scores = (float*)alloc((size_t)E * 4);
  __hip_bfloat16* A = (__hip_bfloat16*)alloc((size_t)N * (NREL * NDIM) * 2);

  int nscan = (N + 1023) / 1024;

  hipMemsetAsync(counts, 0, (size_t)N * 4, stream);
  k0_relkey<<<1, 256, 0, stream>>>(W_r, Wk_w, relkey);
  k1_qkb<<<(N + 63) / 64, 256, 0, stream>>>(x, Wq_w, Wq_b, Wk_w, Q, KB, N);
  k1b_qr<<<(N + 3) / 4, 256, 0, stream>>>(Q, relkey, QR, N);
  k2_hist<<<(E + 255) / 256, 256, 0, stream>>>(dstp, counts, E);
  scan_a<<<nscan, 256, 0, stream>>>(counts, partial, blocksums, N);
  scan_b<<<1, 64, 0, stream>>>(blocksums, blockoff, nscan, offsets, N);
  scan_c<<<(N + 255) / 256, 256, 0, stream>>>(partial, blockoff, offsets, cursor, N);
  k2_scatter<<<(E + 255) / 256, 256, 0, stream>>>(dstp, cursor, csr, E);
  k3_scores<<<(E + 15) / 16, 256, 0, stream>>>(Q, KB, QR, csr, srcp, dstp, et, scores, E);
  k4_agg<<<(N + 3) / 4, 256, 0, stream>>>(x, scores, offsets, csr, srcp, et, A, N);
  k5_gemm_ln<<<(N + 63) / 64, 256, 0, stream>>>(A, W_r, bias, ln_g, ln_b, (float*)d_out, N);
}

// Round 5
// 468.262 us; speedup vs baseline: 1.9658x; 1.0119x over previous
//
#include <hip/hip_runtime.h>
#include <hip/hip_bf16.h>

#define NDIM 64
#define NREL 8
#define SCALE 0.125f
#define LN_EPS 1e-5f

typedef __bf16 bf16x8v __attribute__((ext_vector_type(8)));
typedef float f32x4v __attribute__((ext_vector_type(4)));

__device__ __forceinline__ float wave_sum64(float v) {
#pragma unroll
  for (int off = 32; off > 0; off >>= 1) v += __shfl_xor(v, off, 64);
  return v;
}
__device__ __forceinline__ float wave_max64(float v) {
#pragma unroll
  for (int off = 32; off > 0; off >>= 1) v = fmaxf(v, __shfl_xor(v, off, 64));
  return v;
}

// K0: relkey[r][o] = mean_last(W_r[r]) @ Wk2   (Wk_bias cancels in segment softmax)
__global__ void k0_relkey(const float* __restrict__ W_r,
                          const float* __restrict__ Wk_w,
                          float* __restrict__ relkey) {
  __shared__ float relemb[NREL * NDIM];
  int tid = threadIdx.x;
  for (int idx = tid; idx < NREL * NDIM; idx += 256) {
    int r = idx >> 6, i = idx & 63;
    const float* wr = W_r + (size_t)(r * NDIM + i) * NDIM;
    float s = 0.f;
#pragma unroll
    for (int o = 0; o < NDIM; ++o) s += wr[o];
    relemb[idx] = s * (1.0f / NDIM);
  }
  __syncthreads();
  for (int idx = tid; idx < NREL * NDIM; idx += 256) {
    int r = idx >> 6, o = idx & 63;
    float s = 0.f;
#pragma unroll
    for (int i = 0; i < NDIM; ++i) s += relemb[r * NDIM + i] * Wk_w[(NDIM + i) * NDIM + o];
    relkey[idx] = s;
  }
}

// K0b: pack W_r (viewed as [512][64]) into MFMA B-fragment order, hi/lo bf16 split.
// Fragment element (ct, ks, lane, j) <- W[ks*32 + (lane>>4)*8 + j][ct*16 + (lane&15)]
__global__ void k0b_packw(const float* __restrict__ W_r,
                          __hip_bfloat16* __restrict__ Whi,
                          __hip_bfloat16* __restrict__ Wlo) {
  int idx = blockIdx.x * 256 + threadIdx.x;
  if (idx >= 4 * 16 * 64 * 8) return;
  int j = idx & 7;
  int l = (idx >> 3) & 63;
  int ks = (idx >> 9) & 15;
  int ct = idx >> 13;
  int k = ks * 32 + (l >> 4) * 8 + j;
  int col = ct * 16 + (l & 15);
  float v = W_r[(size_t)k * 64 + col];
  __hip_bfloat16 h = __float2bfloat16(v);
  Whi[idx] = h;
  Wlo[idx] = __float2bfloat16(v - __bfloat162float(h));
}

// K1: [Q | KB] = x @ [Wq | Wk1], Q += Wq_bias. Tiled fp32 GEMM, 64 rows x 128 cols per block.
__global__ void k1_qkb(const float* __restrict__ x,
                       const float* __restrict__ Wq_w,
                       const float* __restrict__ Wq_bias,
                       const float* __restrict__ Wk_w,
                       float* __restrict__ Q, float* __restrict__ KB, int n_nodes) {
  __shared__ float xs[64][68];
  __shared__ float ws[64][128];
  int tid = threadIdx.x;
  int n0 = blockIdx.x * 64;
  for (int idx = tid; idx < 64 * 128; idx += 256) {
    int r = idx >> 7, c = idx & 127;
    ws[r][c] = (c < 64) ? Wq_w[r * 64 + c] : Wk_w[r * 64 + (c - 64)];
  }
  for (int idx = tid; idx < 64 * 16; idx += 256) {
    int r = idx >> 4, c4 = (idx & 15) * 4;
    int n = n0 + r;
    float4 v = make_float4(0.f, 0.f, 0.f, 0.f);
    if (n < n_nodes) v = *reinterpret_cast<const float4*>(x + (size_t)n * 64 + c4);
    *reinterpret_cast<float4*>(&xs[r][c4]) = v;
  }
  __syncthreads();
  int tx = tid & 15, ty = tid >> 4;
  float acc[4][8] = {};
  for (int k = 0; k < 64; k += 4) {
    float4 a[4];
#pragma unroll
    for (int i = 0; i < 4; ++i) a[i] = *reinterpret_cast<float4*>(&xs[ty * 4 + i][k]);
#pragma unroll
    for (int kk = 0; kk < 4; ++kk) {
      float4 w0 = *reinterpret_cast<float4*>(&ws[k + kk][tx * 8]);
      float4 w1 = *reinterpret_cast<float4*>(&ws[k + kk][tx * 8 + 4]);
#pragma unroll
      for (int i = 0; i < 4; ++i) {
        float av = (kk == 0) ? a[i].x : (kk == 1) ? a[i].y : (kk == 2) ? a[i].z : a[i].w;
        acc[i][0] += av * w0.x; acc[i][1] += av * w0.y;
        acc[i][2] += av * w0.z; acc[i][3] += av * w0.w;
        acc[i][4] += av * w1.x; acc[i][5] += av * w1.y;
        acc[i][6] += av * w1.z; acc[i][7] += av * w1.w;
      }
    }
  }
#pragma unroll
  for (int i = 0; i < 4; ++i) {
    int n = n0 + ty * 4 + i;
    if (n >= n_nodes) continue;
#pragma unroll
    for (int j = 0; j < 8; ++j) {
      int c = tx * 8 + j;
      if (c < 64) Q[(size_t)n * 64 + c] = acc[i][j] + Wq_bias[c];
      else KB[(size_t)n * 64 + (c - 64)] = acc[i][j];
    }
  }
}

// K1b: QR[n][r] = Q[n] . relkey[r]
__global__ void k1b_qr(const float* __restrict__ Q, const float* __restrict__ relkey,
                       float* __restrict__ QR, int n_nodes) {
  int lane = threadIdx.x & 63, wv = threadIdx.x >> 6;
  int n = blockIdx.x * 4 + wv;
  if (n >= n_nodes) return;
  float q = Q[(size_t)n * 64 + lane];
#pragma unroll
  for (int r = 0; r < NREL; ++r) {
    float s = wave_sum64(q * relkey[r * 64 + lane]);
    if (lane == r) QR[(size_t)n * NREL + r] = s;
  }
}

__global__ void k2_hist(const int* __restrict__ dst, int* __restrict__ counts, int E) {
  int e = blockIdx.x * blockDim.x + threadIdx.x;
  if (e < E) atomicAdd(&counts[dst[e]], 1);
}

// hierarchical scan: A (per-1024-block exclusive) -> B (block sums) -> C (add)
__global__ void scan_a(const int* __restrict__ counts, int* __restrict__ partial,
                       int* __restrict__ blocksums, int n) {
  __shared__ int wsum[4];
  int tid = threadIdx.x, lane = tid & 63, wv = tid >> 6;
  int base = blockIdx.x * 1024 + tid * 4;
  int4 v = make_int4(0, 0, 0, 0);
  if (base + 3 < n) v = *reinterpret_cast<const int4*>(counts + base);
  else {
    if (base < n) v.x = counts[base];
    if (base + 1 < n) v.y = counts[base + 1];
    if (base + 2 < n) v.z = counts[base + 2];
  }
  int tsum = v.x + v.y + v.z + v.w;
  int s = tsum;
#pragma unroll
  for (int off = 1; off < 64; off <<= 1) {
    int y = __shfl_up(s, off, 64);
    if (lane >= off) s += y;
  }
  if (lane == 63) wsum[wv] = s;
  __syncthreads();
  int woff = 0;
  for (int w = 0; w < wv; ++w) woff += wsum[w];
  int o0 = woff + s - tsum;
  if (base < n) partial[base] = o0;
  if (base + 1 < n) partial[base + 1] = o0 + v.x;
  if (base + 2 < n) partial[base + 2] = o0 + v.x + v.y;
  if (base + 3 < n) partial[base + 3] = o0 + v.x + v.y + v.z;
  if (tid == 255) blocksums[blockIdx.x] = woff + s;
}

__global__ void scan_b(const int* __restrict__ blocksums, int* __restrict__ blockoff,
                       int nb, int* __restrict__ offsets, int n) {
  int lane = threadIdx.x;
  int v = (lane < nb) ? blocksums[lane] : 0;
  int s = v;
#pragma unroll
  for (int off = 1; off < 64; off <<= 1) {
    int y = __shfl_up(s, off, 64);
    if (lane >= off) s += y;
  }
  if (lane < nb) blockoff[lane] = s - v;
  if (lane == 63) offsets[n] = s;
}

__global__ void scan_c(const int* __restrict__ partial, const int* __restrict__ blockoff,
                       int* __restrict__ offsets, int* __restrict__ cursor, int n) {
  int i = blockIdx.x * 256 + threadIdx.x;
  if (i < n) {
    int v = partial[i] + blockoff[i >> 10];
    offsets[i] = v;
    cursor[i] = v;
  }
}

__global__ void k2_scatter(const int* __restrict__ dst, int* __restrict__ cursor,
                           int* __restrict__ csr, int E) {
  int e = blockIdx.x * blockDim.x + threadIdx.x;
  if (e < E) {
    int p = atomicAdd(&cursor[dst[e]], 1);
    csr[p] = e;
  }
}

// K3: edge-parallel scores in CSR position order. 16 lanes per edge, float4 gathers.
__global__ void k3_scores(const float* __restrict__ Q, const float* __restrict__ KB,
                          const float* __restrict__ QR,
                          const int* __restrict__ csr, const int* __restrict__ srcp,
                          const int* __restrict__ dstp, const int* __restrict__ etp,
                          float* __restrict__ scores, int E) {
  int tid = threadIdx.x;
  int lane = tid & 63;
  int li = lane & 15, sub = lane >> 4, wv = tid >> 6;
  int pos = blockIdx.x * 16 + wv * 4 + sub;
  if (pos >= E) return;
  int e = csr[pos];
  int dn = dstp[e], sn = srcp[e], r = etp[e];
  float4 q = *reinterpret_cast<const float4*>(Q + (size_t)dn * 64 + li * 4);
  float4 k = *reinterpret_cast<const float4*>(KB + (size_t)sn * 64 + li * 4);
  float p = q.x * k.x + q.y * k.y + q.z * k.z + q.w * k.w;
#pragma unroll
  for (int off = 1; off < 16; off <<= 1) p += __shfl_xor(p, off, 64);
  if (li == 0) scores[pos] = (p + QR[(size_t)dn * NREL + r]) * SCALE;
}

// K4: one wave per node. Lane-parallel softmax over contiguous scores, then
// 4-edge-parallel accumulation: each 16-lane group owns one edge and a float4
// column slice of x[src]; predicated adds into acc[8][4]; cross-group reduce at end.
__global__ void k4_agg(const float* __restrict__ x, const float* __restrict__ scores,
                       const int* __restrict__ offsets, const int* __restrict__ csr,
                       const int* __restrict__ srcp, const int* __restrict__ etp,
                       __hip_bfloat16* __restrict__ A, int n_nodes) {
  int lane = threadIdx.x & 63, wv = threadIdx.x >> 6;
  int n = blockIdx.x * 4 + wv;
  if (n >= n_nodes) return;
  int li = lane & 15, sub = lane >> 4;
  int s0 = offsets[n], s1 = offsets[n + 1];
  float acc[8][4] = {};
  if (s1 > s0) {
    float m = -1e30f;
    for (int c = s0; c < s1; c += 64) {
      int p = c + lane;
      float s = (p < s1) ? scores[p] : -1e30f;
      m = fmaxf(m, s);
    }
    m = wave_max64(m);
    float t = 0.f;
    for (int c = s0; c < s1; c += 64) {
      int p = c + lane;
      t += (p < s1) ? __expf(scores[p] - m) : 0.f;
    }
    t = wave_sum64(t);
    float inv = 1.0f / t;
    for (int c = s0; c < s1; c += 4) {
      int p = c + sub;
      bool valid = p < s1;
      int e = valid ? csr[p] : 0;
      int sn = valid ? srcp[e] : 0;
      int rr = valid ? etp[e] : 0;
      float wgt = valid ? __expf(scores[p] - m) * inv : 0.f;
      float4 xv = make_float4(0.f, 0.f, 0.f, 0.f);
      if (valid) xv = *reinterpret_cast<const float4*>(x + ((size_t)sn << 6) + li * 4);
      float4 v = make_float4(wgt * xv.x, wgt * xv.y, wgt * xv.z, wgt * xv.w);
#pragma unroll
      for (int r = 0; r < 8; ++r) {
        bool hit = (rr == r);
        acc[r][0] += hit ? v.x : 0.f;
        acc[r][1] += hit ? v.y : 0.f;
        acc[r][2] += hit ? v.z : 0.f;
        acc[r][3] += hit ? v.w : 0.f;
      }
    }
  }
#pragma unroll
  for (int r = 0; r < 8; ++r)
#pragma unroll
    for (int j = 0; j < 4; ++j) {
      acc[r][j] += __shfl_xor(acc[r][j], 16, 64);
      acc[r][j] += __shfl_xor(acc[r][j], 32, 64);
    }
  // sub s writes rel rows 2s, 2s+1 (values identical across subs after reduce)
#pragma unroll
  for (int r = 0; r < 8; ++r) {
    if ((r >> 1) == sub) {
#pragma unroll
      for (int j = 0; j < 4; ++j)
        A[(size_t)n * 512 + r * 64 + li * 4 + j] = __float2bfloat16(acc[r][j]);
    }
  }
}

// K5: out = relu(LN(A(50000x512 bf16) @ (Whi+Wlo) + bias)) via MFMA, LDS-free.
// Wave w of 4 handles rows n0+w*16 .. +16; acc[ct] covers cols ct*16..+16.
__global__ void __launch_bounds__(256) k5_mfma_ln(
    const __hip_bfloat16* __restrict__ A,
    const __hip_bfloat16* __restrict__ Whi,
    const __hip_bfloat16* __restrict__ Wlo,
    const float* __restrict__ bias,
    const float* __restrict__ ln_g, const float* __restrict__ ln_b,
    float* __restrict__ out, int n_nodes) {
  int tid = threadIdx.x;
  int lane = tid & 63, w = tid >> 6;
  int li = lane & 15, gr = lane >> 4;
  int n0 = blockIdx.x * 64;
  int arow_n = n0 + w * 16 + li;  // A-fragment row for this lane
  bool rvalid = arow_n < n_nodes;
  const __hip_bfloat16* arow = A + (size_t)arow_n * 512 + gr * 8;
  const bf16x8v* wh = reinterpret_cast<const bf16x8v*>(Whi);
  const bf16x8v* wl = reinterpret_cast<const bf16x8v*>(Wlo);
  f32x4v acc[4];
#pragma unroll
  for (int ct = 0; ct < 4; ++ct) acc[ct] = (f32x4v){0.f, 0.f, 0.f, 0.f};
  for (int ks = 0; ks < 16; ++ks) {
    uint4 au = make_uint4(0u, 0u, 0u, 0u);
    if (rvalid) au = *reinterpret_cast<const uint4*>(arow + ks * 32);
    bf16x8v a = __builtin_bit_cast(bf16x8v, au);
#pragma unroll
    for (int ct = 0; ct < 4; ++ct) {
      bf16x8v bh = wh[(ct * 16 + ks) * 64 + lane];
      bf16x8v bl = wl[(ct * 16 + ks) * 64 + lane];
      acc[ct] = __builtin_amdgcn_mfma_f32_16x16x32_bf16(a, bh, acc[ct], 0, 0, 0);
      acc[ct] = __builtin_amdgcn_mfma_f32_16x16x32_bf16(a, bl, acc[ct], 0, 0, 0);
    }
  }
  // C layout: col = ct*16 + (lane&15), row = w*16 + (lane>>4)*4 + reg
  float bi[4], g[4], bb[4];
#pragma unroll
  for (int ct = 0; ct < 4; ++ct) {
    int col = ct * 16 + li;
    bi[ct] = bias[col];
    g[ct] = ln_g[col];
    bb[ct] = ln_b[col];
  }
#pragma unroll
  for (int reg = 0; reg < 4; ++reg) {
    float v[4];
#pragma unroll
    for (int ct = 0; ct < 4; ++ct) v[ct] = acc[ct][reg] + bi[ct];
    float s = v[0] + v[1] + v[2] + v[3];
    s += __shfl_xor(s, 1, 64);
    s += __shfl_xor(s, 2, 64);
    s += __shfl_xor(s, 4, 64);
    s += __shfl_xor(s, 8, 64);
    float mu = s * (1.0f / 64.0f);
    float sq = 0.f;
#pragma unroll
    for (int ct = 0; ct < 4; ++ct) {
      float d = v[ct] - mu;
      sq += d * d;
    }
    sq += __shfl_xor(sq, 1, 64);
    sq += __shfl_xor(sq, 2, 64);
    sq += __shfl_xor(sq, 4, 64);
    sq += __shfl_xor(sq, 8, 64);
    float inv = rsqrtf(sq * (1.0f / 64.0f) + LN_EPS);
    int n = n0 + w * 16 + gr * 4 + reg;
    if (n < n_nodes) {
#pragma unroll
      for (int ct = 0; ct < 4; ++ct) {
        float y = (v[ct] - mu) * inv * g[ct] + bb[ct];
        out[(size_t)n * 64 + ct * 16 + li] = fmaxf(y, 0.f);
      }
    }
  }
}

extern "C" void kernel_launch(void* const* d_in, const int* in_sizes, int n_in,
                              void* d_out, int out_size, void* d_ws, size_t ws_size,
                              hipStream_t stream) {
  (void)n_in; (void)out_size; (void)ws_size;
  const float* x = (const float*)d_in[0];
  const int* ei = (const int*)d_in[1];
  const int* et = (const int*)d_in[2];
  const float* W_r = (const float*)d_in[4];
  const float* Wq_w = (const float*)d_in[5];
  const float* Wq_b = (const float*)d_in[6];
  const float* Wk_w = (const float*)d_in[7];
  const float* bias = (const float*)d_in[10];
  const float* ln_g = (const float*)d_in[11];
  const float* ln_b = (const float*)d_in[12];

  int N = in_sizes[0] / NDIM;
  int E = in_sizes[2];
  const int* srcp = ei;
  const int* dstp = ei + E;

  char* p = (char*)d_ws;
  auto alloc = [&](size_t bytes) {
    void* r = (void*)p;
    p += (bytes + 255) & ~(size_t)255;
    return r;
  };
  float* Q = (float*)alloc((size_t)N * NDIM * 4);
  float* KB = (float*)alloc((size_t)N * NDIM * 4);
  float* QR = (float*)alloc((size_t)N * NREL * 4);
  float* relkey = (float*)alloc(NREL * NDIM * 4);
  int* counts = (int*)alloc((size_t)N * 4);
  int* partial = (int*)alloc((size_t)N * 4);
  int* offsets = (int*)alloc((size_t)(N + 1) * 4);
  int* cursor = (int*)alloc((size_t)N * 4);
  int* blocksums = (int*)alloc(64 * 4);
  int* blockoff = (int*)alloc(64 * 4);
  int* csr = (int*)alloc((size_t)E * 4);
  float* scores = (float*)alloc((size_t)E * 4);
  __hip_bfloat16* A = (__hip_bfloat16*)alloc((size_t)N * (NREL * NDIM) * 2);
  __hip_bfloat16* Whi = (__hip_bfloat16*)alloc(4 * 16 * 64 * 8 * 2);
  __hip_bfloat16* Wlo = (__hip_bfloat16*)alloc(4 * 16 * 64 * 8 * 2);

  int nscan = (N + 1023) / 1024;

  hipMemsetAsync(counts, 0, (size_t)N * 4, stream);
  k0_relkey<<<1, 256, 0, stream>>>(W_r, Wk_w, relkey);
  k0b_packw<<<(4 * 16 * 64 * 8 + 255) / 256, 256, 0, stream>>>(W_r, Whi, Wlo);
  k1_qkb<<<(N + 63) / 64, 256, 0, stream>>>(x, Wq_w, Wq_b, Wk_w, Q, KB, N);
  k1b_qr<<<(N + 3) / 4, 256, 0, stream>>>(Q, relkey, QR, N);
  k2_hist<<<(E + 255) / 256, 256, 0, stream>>>(dstp, counts, E);
  scan_a<<<nscan, 256, 0, stream>>>(counts, partial, blocksums, N);
  scan_b<<<1, 64, 0, stream>>>(blocksums, blockoff, nscan, offsets, N);
  scan_c<<<(N + 255) / 256, 256, 0, stream>>>(partial, blockoff, offsets, cursor, N);
  k2_scatter<<<(E + 255) / 256, 256, 0, stream>>>(dstp, cursor, csr, E);
  k3_scores<<<(E + 15) / 16, 256, 0, stream>>>(Q, KB, QR, csr, srcp, dstp, et, scores, E);
  k4_agg<<<(N + 3) / 4, 256, 0, stream>>>(x, scores, offsets, csr, srcp, et, A, N);
  k5_mfma_ln<<<(N + 63) / 64, 256, 0, stream>>>(A, Whi, Wlo, bias, ln_g, ln_b,
                                                (float*)d_out, N);
}

// Round 6
// 412.768 us; speedup vs baseline: 2.2301x; 1.1344x over previous
//
#include <hip/hip_runtime.h>
#include <hip/hip_bf16.h>

#define NDIM 64
#define NREL 8
#define SCALE 0.125f
#define LN_EPS 1e-5f

typedef __bf16 bf16x8v __attribute__((ext_vector_type(8)));
typedef float f32x4v __attribute__((ext_vector_type(4)));

__device__ __forceinline__ float wave_sum64(float v) {
#pragma unroll
  for (int off = 32; off > 0; off >>= 1) v += __shfl_xor(v, off, 64);
  return v;
}
__device__ __forceinline__ float wave_max64(float v) {
#pragma unroll
  for (int off = 32; off > 0; off >>= 1) v = fmaxf(v, __shfl_xor(v, off, 64));
  return v;
}

// K0: relkey[r][o] = mean_last(W_r[r]) @ Wk2   (Wk_bias cancels in segment softmax)
__global__ void k0_relkey(const float* __restrict__ W_r,
                          const float* __restrict__ Wk_w,
                          float* __restrict__ relkey) {
  __shared__ float relemb[NREL * NDIM];
  int tid = threadIdx.x;
  for (int idx = tid; idx < NREL * NDIM; idx += 256) {
    int r = idx >> 6, i = idx & 63;
    const float* wr = W_r + (size_t)(r * NDIM + i) * NDIM;
    float s = 0.f;
#pragma unroll
    for (int o = 0; o < NDIM; ++o) s += wr[o];
    relemb[idx] = s * (1.0f / NDIM);
  }
  __syncthreads();
  for (int idx = tid; idx < NREL * NDIM; idx += 256) {
    int r = idx >> 6, o = idx & 63;
    float s = 0.f;
#pragma unroll
    for (int i = 0; i < NDIM; ++i) s += relemb[r * NDIM + i] * Wk_w[(NDIM + i) * NDIM + o];
    relkey[idx] = s;
  }
}

// K0b: pack W_r (viewed as [512][64]) into MFMA B-fragment order, hi/lo bf16 split.
__global__ void k0b_packw(const float* __restrict__ W_r,
                          __hip_bfloat16* __restrict__ Whi,
                          __hip_bfloat16* __restrict__ Wlo) {
  int idx = blockIdx.x * 256 + threadIdx.x;
  if (idx >= 4 * 16 * 64 * 8) return;
  int j = idx & 7;
  int l = (idx >> 3) & 63;
  int ks = (idx >> 9) & 15;
  int ct = idx >> 13;
  int k = ks * 32 + (l >> 4) * 8 + j;
  int col = ct * 16 + (l & 15);
  float v = W_r[(size_t)k * 64 + col];
  __hip_bfloat16 h = __float2bfloat16(v);
  Whi[idx] = h;
  Wlo[idx] = __float2bfloat16(v - __bfloat162float(h));
}

// K1: [Q | KB] = x @ [Wq | Wk1], Q += Wq_bias; fused QR[n][r] = Q[n].relkey[r].
__global__ void k1_qkb(const float* __restrict__ x,
                       const float* __restrict__ Wq_w,
                       const float* __restrict__ Wq_bias,
                       const float* __restrict__ Wk_w,
                       const float* __restrict__ relkey,
                       float* __restrict__ Q, float* __restrict__ KB,
                       float* __restrict__ QR, int n_nodes) {
  __shared__ float xs[64][68];
  __shared__ float ws[64][128];
  __shared__ float rks[NREL][NDIM];
  int tid = threadIdx.x;
  int n0 = blockIdx.x * 64;
  for (int idx = tid; idx < 64 * 128; idx += 256) {
    int r = idx >> 7, c = idx & 127;
    ws[r][c] = (c < 64) ? Wq_w[r * 64 + c] : Wk_w[r * 64 + (c - 64)];
  }
  for (int idx = tid; idx < NREL * NDIM; idx += 256)
    rks[idx >> 6][idx & 63] = relkey[idx];
  for (int idx = tid; idx < 64 * 16; idx += 256) {
    int r = idx >> 4, c4 = (idx & 15) * 4;
    int n = n0 + r;
    float4 v = make_float4(0.f, 0.f, 0.f, 0.f);
    if (n < n_nodes) v = *reinterpret_cast<const float4*>(x + (size_t)n * 64 + c4);
    *reinterpret_cast<float4*>(&xs[r][c4]) = v;
  }
  __syncthreads();
  int tx = tid & 15, ty = tid >> 4;
  float acc[4][8] = {};
  for (int k = 0; k < 64; k += 4) {
    float4 a[4];
#pragma unroll
    for (int i = 0; i < 4; ++i) a[i] = *reinterpret_cast<float4*>(&xs[ty * 4 + i][k]);
#pragma unroll
    for (int kk = 0; kk < 4; ++kk) {
      float4 w0 = *reinterpret_cast<float4*>(&ws[k + kk][tx * 8]);
      float4 w1 = *reinterpret_cast<float4*>(&ws[k + kk][tx * 8 + 4]);
#pragma unroll
      for (int i = 0; i < 4; ++i) {
        float av = (kk == 0) ? a[i].x : (kk == 1) ? a[i].y : (kk == 2) ? a[i].z : a[i].w;
        acc[i][0] += av * w0.x; acc[i][1] += av * w0.y;
        acc[i][2] += av * w0.z; acc[i][3] += av * w0.w;
        acc[i][4] += av * w1.x; acc[i][5] += av * w1.y;
        acc[i][6] += av * w1.z; acc[i][7] += av * w1.w;
      }
    }
  }
  // store Q/KB; keep Q values (zero for KB-half lanes) for fused QR
  float qv[4][8];
#pragma unroll
  for (int i = 0; i < 4; ++i) {
    int n = n0 + ty * 4 + i;
    bool nv = n < n_nodes;
#pragma unroll
    for (int j = 0; j < 8; ++j) {
      int c = tx * 8 + j;
      if (c < 64) {
        qv[i][j] = acc[i][j] + Wq_bias[c];
        if (nv) Q[(size_t)n * 64 + c] = qv[i][j];
      } else {
        qv[i][j] = 0.f;
        if (nv) KB[(size_t)n * 64 + (c - 64)] = acc[i][j];
      }
    }
  }
#pragma unroll
  for (int r = 0; r < NREL; ++r) {
    float rk8[8];
    *reinterpret_cast<float4*>(&rk8[0]) =
        *reinterpret_cast<float4*>(&rks[r][(tx & 7) * 8]);
    *reinterpret_cast<float4*>(&rk8[4]) =
        *reinterpret_cast<float4*>(&rks[r][(tx & 7) * 8 + 4]);
#pragma unroll
    for (int i = 0; i < 4; ++i) {
      float pq = 0.f;
#pragma unroll
      for (int j = 0; j < 8; ++j) pq += qv[i][j] * rk8[j];
      pq += __shfl_xor(pq, 1, 64);
      pq += __shfl_xor(pq, 2, 64);
      pq += __shfl_xor(pq, 4, 64);
      pq += __shfl_xor(pq, 8, 64);
      int n = n0 + ty * 4 + i;
      if (tx == r && n < n_nodes) QR[(size_t)n * NREL + r] = pq;
    }
  }
}

__global__ void k2_hist(const int* __restrict__ dst, int* __restrict__ counts, int E) {
  int e = blockIdx.x * blockDim.x + threadIdx.x;
  if (e < E) atomicAdd(&counts[dst[e]], 1);
}

// hierarchical scan: A (per-1024-block exclusive) -> B (block sums) -> C (add)
__global__ void scan_a(const int* __restrict__ counts, int* __restrict__ partial,
                       int* __restrict__ blocksums, int n) {
  __shared__ int wsum[4];
  int tid = threadIdx.x, lane = tid & 63, wv = tid >> 6;
  int base = blockIdx.x * 1024 + tid * 4;
  int4 v = make_int4(0, 0, 0, 0);
  if (base + 3 < n) v = *reinterpret_cast<const int4*>(counts + base);
  else {
    if (base < n) v.x = counts[base];
    if (base + 1 < n) v.y = counts[base + 1];
    if (base + 2 < n) v.z = counts[base + 2];
  }
  int tsum = v.x + v.y + v.z + v.w;
  int s = tsum;
#pragma unroll
  for (int off = 1; off < 64; off <<= 1) {
    int y = __shfl_up(s, off, 64);
    if (lane >= off) s += y;
  }
  if (lane == 63) wsum[wv] = s;
  __syncthreads();
  int woff = 0;
  for (int w = 0; w < wv; ++w) woff += wsum[w];
  int o0 = woff + s - tsum;
  if (base < n) partial[base] = o0;
  if (base + 1 < n) partial[base + 1] = o0 + v.x;
  if (base + 2 < n) partial[base + 2] = o0 + v.x + v.y;
  if (base + 3 < n) partial[base + 3] = o0 + v.x + v.y + v.z;
  if (tid == 255) blocksums[blockIdx.x] = woff + s;
}

__global__ void scan_b(const int* __restrict__ blocksums, int* __restrict__ blockoff,
                       int nb, int* __restrict__ offsets, int n) {
  int lane = threadIdx.x;
  int v = (lane < nb) ? blocksums[lane] : 0;
  int s = v;
#pragma unroll
  for (int off = 1; off < 64; off <<= 1) {
    int y = __shfl_up(s, off, 64);
    if (lane >= off) s += y;
  }
  if (lane < nb) blockoff[lane] = s - v;
  if (lane == 63) offsets[n] = s;
}

__global__ void scan_c(const int* __restrict__ partial, const int* __restrict__ blockoff,
                       int* __restrict__ offsets, int* __restrict__ cursor, int n) {
  int i = blockIdx.x * 256 + threadIdx.x;
  if (i < n) {
    int v = partial[i] + blockoff[i >> 10];
    offsets[i] = v;
    cursor[i] = v;
  }
}

__global__ void k2_scatter(const int* __restrict__ dst, int* __restrict__ cursor,
                           int* __restrict__ csr, int E) {
  int e = blockIdx.x * blockDim.x + threadIdx.x;
  if (e < E) {
    int p = atomicAdd(&cursor[dst[e]], 1);
    csr[p] = e;
  }
}

// K3: edge-parallel scores in CSR position order. 16 lanes per edge, float4 gathers.
__global__ void k3_scores(const float* __restrict__ Q, const float* __restrict__ KB,
                          const float* __restrict__ QR,
                          const int* __restrict__ csr, const int* __restrict__ srcp,
                          const int* __restrict__ dstp, const int* __restrict__ etp,
                          float* __restrict__ scores, int E) {
  int tid = threadIdx.x;
  int lane = tid & 63;
  int li = lane & 15, sub = lane >> 4, wv = tid >> 6;
  int pos = blockIdx.x * 16 + wv * 4 + sub;
  if (pos >= E) return;
  int e = csr[pos];
  int dn = dstp[e], sn = srcp[e], r = etp[e];
  float4 q = *reinterpret_cast<const float4*>(Q + (size_t)dn * 64 + li * 4);
  float4 k = *reinterpret_cast<const float4*>(KB + (size_t)sn * 64 + li * 4);
  float p = q.x * k.x + q.y * k.y + q.z * k.z + q.w * k.w;
#pragma unroll
  for (int off = 1; off < 16; off <<= 1) p += __shfl_xor(p, off, 64);
  if (li == 0) scores[pos] = (p + QR[(size_t)dn * NREL + r]) * SCALE;
}

#define ACC_SWITCH(rr, v)                    \
  switch (rr) {                              \
    case 0: acc[0] += (v); break;            \
    case 1: acc[1] += (v); break;            \
    case 2: acc[2] += (v); break;            \
    case 3: acc[3] += (v); break;            \
    case 4: acc[4] += (v); break;            \
    case 5: acc[5] += (v); break;            \
    case 6: acc[6] += (v); break;            \
    case 7: acc[7] += (v); break;            \
  }

// K4: one wave per node. Fast path (deg<=64): edge data loaded once into lane
// registers; softmax via 2 wave reduces; broadcast loop with v_readlane-scalarized
// src/rel (uniform switch -> 1 FMA/edge/lane, SGPR-based x row gather).
__global__ void k4_agg(const float* __restrict__ x, const float* __restrict__ scores,
                       const int* __restrict__ offsets, const int* __restrict__ csr,
                       const int* __restrict__ srcp, const int* __restrict__ etp,
                       __hip_bfloat16* __restrict__ A, int n_nodes) {
  int lane = threadIdx.x & 63, wv = threadIdx.x >> 6;
  int n = blockIdx.x * 4 + wv;
  if (n >= n_nodes) return;
  int s0 = offsets[n], s1 = offsets[n + 1];
  int deg = s1 - s0;
  float acc[8] = {0.f, 0.f, 0.f, 0.f, 0.f, 0.f, 0.f, 0.f};
  if (deg > 0 && deg <= 64) {
    int p = s0 + lane;
    bool valid = p < s1;
    int e = valid ? csr[p] : 0;
    float sc = valid ? scores[p] : -1e30f;
    int sl = valid ? srcp[e] : 0;
    int rl = valid ? etp[e] : 0;
    float m = wave_max64(sc);
    float ex = valid ? __expf(sc - m) : 0.f;
    float t = wave_sum64(ex);
    float wl = ex * (1.0f / t);
    for (int i = 0; i < deg; ++i) {
      float wgt = __int_as_float(__builtin_amdgcn_readlane(__float_as_int(wl), i));
      int sn = __builtin_amdgcn_readlane(sl, i);
      int rr = __builtin_amdgcn_readlane(rl, i);
      float v = wgt * x[((size_t)sn << 6) + lane];
      ACC_SWITCH(rr, v)
    }
  } else if (deg > 64) {
    float m = -1e30f;
    for (int c = s0; c < s1; c += 64) {
      int p = c + lane;
      float s = (p < s1) ? scores[p] : -1e30f;
      m = fmaxf(m, s);
    }
    m = wave_max64(m);
    float t = 0.f;
    for (int c = s0; c < s1; c += 64) {
      int p = c + lane;
      t += (p < s1) ? __expf(scores[p] - m) : 0.f;
    }
    t = wave_sum64(t);
    float inv = 1.0f / t;
    for (int c = s0; c < s1; c += 64) {
      int p = c + lane;
      bool valid = p < s1;
      int e = valid ? csr[p] : 0;
      int sl = valid ? srcp[e] : 0;
      int rl = valid ? etp[e] : 0;
      float wl = valid ? __expf(scores[p] - m) * inv : 0.f;
      int cnt = min(64, s1 - c);
      for (int i = 0; i < cnt; ++i) {
        float wgt = __int_as_float(__builtin_amdgcn_readlane(__float_as_int(wl), i));
        int sn = __builtin_amdgcn_readlane(sl, i);
        int rr = __builtin_amdgcn_readlane(rl, i);
        float v = wgt * x[((size_t)sn << 6) + lane];
        ACC_SWITCH(rr, v)
      }
    }
  }
#pragma unroll
  for (int r = 0; r < 8; ++r)
    A[(size_t)n * 512 + r * 64 + lane] = __float2bfloat16(acc[r]);
}

// K5: out = relu(LN(A(50000x512 bf16) @ (Whi+Wlo) + bias)) via MFMA, LDS-free.
__global__ void __launch_bounds__(256) k5_mfma_ln(
    const __hip_bfloat16* __restrict__ A,
    const __hip_bfloat16* __restrict__ Whi,
    const __hip_bfloat16* __restrict__ Wlo,
    const float* __restrict__ bias,
    const float* __restrict__ ln_g, const float* __restrict__ ln_b,
    float* __restrict__ out, int n_nodes) {
  int tid = threadIdx.x;
  int lane = tid & 63, w = tid >> 6;
  int li = lane & 15, gr = lane >> 4;
  int n0 = blockIdx.x * 64;
  int arow_n = n0 + w * 16 + li;
  bool rvalid = arow_n < n_nodes;
  const __hip_bfloat16* arow = A + (size_t)arow_n * 512 + gr * 8;
  const bf16x8v* wh = reinterpret_cast<const bf16x8v*>(Whi);
  const bf16x8v* wl = reinterpret_cast<const bf16x8v*>(Wlo);
  f32x4v acc[4];
#pragma unroll
  for (int ct = 0; ct < 4; ++ct) acc[ct] = (f32x4v){0.f, 0.f, 0.f, 0.f};
  for (int ks = 0; ks < 16; ++ks) {
    uint4 au = make_uint4(0u, 0u, 0u, 0u);
    if (rvalid) au = *reinterpret_cast<const uint4*>(arow + ks * 32);
    bf16x8v a = __builtin_bit_cast(bf16x8v, au);
#pragma unroll
    for (int ct = 0; ct < 4; ++ct) {
      bf16x8v bh = wh[(ct * 16 + ks) * 64 + lane];
      bf16x8v bl = wl[(ct * 16 + ks) * 64 + lane];
      acc[ct] = __builtin_amdgcn_mfma_f32_16x16x32_bf16(a, bh, acc[ct], 0, 0, 0);
      acc[ct] = __builtin_amdgcn_mfma_f32_16x16x32_bf16(a, bl, acc[ct], 0, 0, 0);
    }
  }
  float bi[4], g[4], bb[4];
#pragma unroll
  for (int ct = 0; ct < 4; ++ct) {
    int col = ct * 16 + li;
    bi[ct] = bias[col];
    g[ct] = ln_g[col];
    bb[ct] = ln_b[col];
  }
#pragma unroll
  for (int reg = 0; reg < 4; ++reg) {
    float v[4];
#pragma unroll
    for (int ct = 0; ct < 4; ++ct) v[ct] = acc[ct][reg] + bi[ct];
    float s = v[0] + v[1] + v[2] + v[3];
    s += __shfl_xor(s, 1, 64);
    s += __shfl_xor(s, 2, 64);
    s += __shfl_xor(s, 4, 64);
    s += __shfl_xor(s, 8, 64);
    float mu = s * (1.0f / 64.0f);
    float sq = 0.f;
#pragma unroll
    for (int ct = 0; ct < 4; ++ct) {
      float d = v[ct] - mu;
      sq += d * d;
    }
    sq += __shfl_xor(sq, 1, 64);
    sq += __shfl_xor(sq, 2, 64);
    sq += __shfl_xor(sq, 4, 64);
    sq += __shfl_xor(sq, 8, 64);
    float inv = rsqrtf(sq * (1.0f / 64.0f) + LN_EPS);
    int n = n0 + w * 16 + gr * 4 + reg;
    if (n < n_nodes) {
#pragma unroll
      for (int ct = 0; ct < 4; ++ct) {
        float y = (v[ct] - mu) * inv * g[ct] + bb[ct];
        out[(size_t)n * 64 + ct * 16 + li] = fmaxf(y, 0.f);
      }
    }
  }
}

extern "C" void kernel_launch(void* const* d_in, const int* in_sizes, int n_in,
                              void* d_out, int out_size, void* d_ws, size_t ws_size,
                              hipStream_t stream) {
  (void)n_in; (void)out_size; (void)ws_size;
  const float* x = (const float*)d_in[0];
  const int* ei = (const int*)d_in[1];
  const int* et = (const int*)d_in[2];
  const float* W_r = (const float*)d_in[4];
  const float* Wq_w = (const float*)d_in[5];
  const float* Wq_b = (const float*)d_in[6];
  const float* Wk_w = (const float*)d_in[7];
  const float* bias = (const float*)d_in[10];
  const float* ln_g = (const float*)d_in[11];
  const float* ln_b = (const float*)d_in[12];

  int N = in_sizes[0] / NDIM;
  int E = in_sizes[2];
  const int* srcp = ei;
  const int* dstp = ei + E;

  char* p = (char*)d_ws;
  auto alloc = [&](size_t bytes) {
    void* r = (void*)p;
    p += (bytes + 255) & ~(size_t)255;
    return r;
  };
  float* Q = (float*)alloc((size_t)N * NDIM * 4);
  float* KB = (float*)alloc((size_t)N * NDIM * 4);
  float* QR = (float*)alloc((size_t)N * NREL * 4);
  float* relkey = (float*)alloc(NREL * NDIM * 4);
  int* counts = (int*)alloc((size_t)N * 4);
  int* partial = (int*)alloc((size_t)N * 4);
  int* offsets = (int*)alloc((size_t)(N + 1) * 4);
  int* cursor = (int*)alloc((size_t)N * 4);
  int* blocksums = (int*)alloc(64 * 4);
  int* blockoff = (int*)alloc(64 * 4);
  int* csr = (int*)alloc((size_t)E * 4);
  float* scores = (float*)alloc((size_t)E * 4);
  __hip_bfloat16* A = (__hip_bfloat16*)alloc((size_t)N * (NREL * NDIM) * 2);
  __hip_bfloat16* Whi = (__hip_bfloat16*)alloc(4 * 16 * 64 * 8 * 2);
  __hip_bfloat16* Wlo = (__hip_bfloat16*)alloc(4 * 16 * 64 * 8 * 2);

  int nscan = (N + 1023) / 1024;

  hipMemsetAsync(counts, 0, (size_t)N * 4, stream);
  k0_relkey<<<1, 256, 0, stream>>>(W_r, Wk_w, relkey);
  k0b_packw<<<(4 * 16 * 64 * 8 + 255) / 256, 256, 0, stream>>>(W_r, Whi, Wlo);
  k1_qkb<<<(N + 63) / 64, 256, 0, stream>>>(x, Wq_w, Wq_b, Wk_w, relkey, Q, KB, QR, N);
  k2_hist<<<(E + 255) / 256, 256, 0, stream>>>(dstp, counts, E);
  scan_a<<<nscan, 256, 0, stream>>>(counts, partial, blocksums, N);
  scan_b<<<1, 64, 0, stream>>>(blocksums, blockoff, nscan, offsets, N);
  scan_c<<<(N + 255) / 256, 256, 0, stream>>>(partial, blockoff, offsets, cursor, N);
  k2_scatter<<<(E + 255) / 256, 256, 0, stream>>>(dstp, cursor, csr, E);
  k3_scores<<<(E + 15) / 16, 256, 0, stream>>>(Q, KB, QR, csr, srcp, dstp, et, scores, E);
  k4_agg<<<(N + 3) / 4, 256, 0, stream>>>(x, scores, offsets, csr, srcp, et, A, N);
  k5_mfma_ln<<<(N + 63) / 64, 256, 0, stream>>>(A, Whi, Wlo, bias, ln_g, ln_b,
                                                (float*)d_out, N);
}

// Round 9
// 403.870 us; speedup vs baseline: 2.2792x; 1.0220x over previous
//
#include <hip/hip_runtime.h>
#include <hip/hip_bf16.h>

#define NDIM 64
#define NREL 8
#define SCALE 0.125f
#define LN_EPS 1e-5f

typedef __bf16 bf16x8v __attribute__((ext_vector_type(8)));
typedef float f32x4v __attribute__((ext_vector_type(4)));

__device__ __forceinline__ float wave_sum64(float v) {
#pragma unroll
  for (int off = 32; off > 0; off >>= 1) v += __shfl_xor(v, off, 64);
  return v;
}
__device__ __forceinline__ float wave_max64(float v) {
#pragma unroll
  for (int off = 32; off > 0; off >>= 1) v = fmaxf(v, __shfl_xor(v, off, 64));
  return v;
}
__device__ __forceinline__ unsigned short f2bf_u(float f) {
  __hip_bfloat16 h = __float2bfloat16(f);
  return *reinterpret_cast<unsigned short*>(&h);
}

// K0: relkey[r][o] = mean_last(W_r[r]) @ Wk2   (Wk_bias cancels in segment softmax)
__global__ void k0_relkey(const float* __restrict__ W_r,
                          const float* __restrict__ Wk_w,
                          float* __restrict__ relkey) {
  __shared__ float relemb[NREL * NDIM];
  int tid = threadIdx.x;
  for (int idx = tid; idx < NREL * NDIM; idx += 256) {
    int r = idx >> 6, i = idx & 63;
    const float* wr = W_r + (size_t)(r * NDIM + i) * NDIM;
    float s = 0.f;
#pragma unroll
    for (int o = 0; o < NDIM; ++o) s += wr[o];
    relemb[idx] = s * (1.0f / NDIM);
  }
  __syncthreads();
  for (int idx = tid; idx < NREL * NDIM; idx += 256) {
    int r = idx >> 6, o = idx & 63;
    float s = 0.f;
#pragma unroll
    for (int i = 0; i < NDIM; ++i) s += relemb[r * NDIM + i] * Wk_w[(NDIM + i) * NDIM + o];
    relkey[idx] = s;
  }
}

// K0b: pack W_r (viewed as [512][64]) into MFMA B-fragment order, hi/lo bf16 split.
__global__ void k0b_packw(const float* __restrict__ W_r,
                          __hip_bfloat16* __restrict__ Whi,
                          __hip_bfloat16* __restrict__ Wlo) {
  int idx = blockIdx.x * 256 + threadIdx.x;
  if (idx >= 4 * 16 * 64 * 8) return;
  int j = idx & 7;
  int l = (idx >> 3) & 63;
  int ks = (idx >> 9) & 15;
  int ct = idx >> 13;
  int k = ks * 32 + (l >> 4) * 8 + j;
  int col = ct * 16 + (l & 15);
  float v = W_r[(size_t)k * 64 + col];
  __hip_bfloat16 h = __float2bfloat16(v);
  Whi[idx] = h;
  Wlo[idx] = __float2bfloat16(v - __bfloat162float(h));
}

// K1c: xbf = bf16(x), vectorized grid-stride copy.
__global__ void k1c_xbf(const float* __restrict__ x, __hip_bfloat16* __restrict__ xbf,
                        int total4) {
  int i = blockIdx.x * blockDim.x + threadIdx.x;
  int stride = gridDim.x * blockDim.x;
  for (; i < total4; i += stride) {
    float4 v = *reinterpret_cast<const float4*>(x + (size_t)i * 4);
    ushort4 u;
    u.x = f2bf_u(v.x); u.y = f2bf_u(v.y); u.z = f2bf_u(v.z); u.w = f2bf_u(v.w);
    *reinterpret_cast<ushort4*>(reinterpret_cast<unsigned short*>(xbf) +
                                (size_t)i * 4) = u;
  }
}

// K1: [Q | KB] = x @ [Wq | Wk1], Q += Wq_bias; fused QR[n][r] = Q[n].relkey[r].
__global__ void k1_qkb(const float* __restrict__ x,
                       const float* __restrict__ Wq_w,
                       const float* __restrict__ Wq_bias,
                       const float* __restrict__ Wk_w,
                       const float* __restrict__ relkey,
                       float* __restrict__ Q, float* __restrict__ KB,
                       float* __restrict__ QR, int n_nodes) {
  __shared__ float xs[64][68];
  __shared__ float ws[64][128];
  __shared__ float rks[NREL][NDIM];
  int tid = threadIdx.x;
  int n0 = blockIdx.x * 64;
  for (int idx = tid; idx < 64 * 128; idx += 256) {
    int r = idx >> 7, c = idx & 127;
    ws[r][c] = (c < 64) ? Wq_w[r * 64 + c] : Wk_w[r * 64 + (c - 64)];
  }
  for (int idx = tid; idx < NREL * NDIM; idx += 256)
    rks[idx >> 6][idx & 63] = relkey[idx];
  for (int idx = tid; idx < 64 * 16; idx += 256) {
    int r = idx >> 4, c4 = (idx & 15) * 4;
    int n = n0 + r;
    float4 v = make_float4(0.f, 0.f, 0.f, 0.f);
    if (n < n_nodes) v = *reinterpret_cast<const float4*>(x + (size_t)n * 64 + c4);
    *reinterpret_cast<float4*>(&xs[r][c4]) = v;
  }
  __syncthreads();
  int tx = tid & 15, ty = tid >> 4;
  float acc[4][8] = {};
  for (int k = 0; k < 64; k += 4) {
    float4 a[4];
#pragma unroll
    for (int i = 0; i < 4; ++i) a[i] = *reinterpret_cast<float4*>(&xs[ty * 4 + i][k]);
#pragma unroll
    for (int kk = 0; kk < 4; ++kk) {
      float4 w0 = *reinterpret_cast<float4*>(&ws[k + kk][tx * 8]);
      float4 w1 = *reinterpret_cast<float4*>(&ws[k + kk][tx * 8 + 4]);
#pragma unroll
      for (int i = 0; i < 4; ++i) {
        float av = (kk == 0) ? a[i].x : (kk == 1) ? a[i].y : (kk == 2) ? a[i].z : a[i].w;
        acc[i][0] += av * w0.x; acc[i][1] += av * w0.y;
        acc[i][2] += av * w0.z; acc[i][3] += av * w0.w;
        acc[i][4] += av * w1.x; acc[i][5] += av * w1.y;
        acc[i][6] += av * w1.z; acc[i][7] += av * w1.w;
      }
    }
  }
  float qv[4][8];
#pragma unroll
  for (int i = 0; i < 4; ++i) {
    int n = n0 + ty * 4 + i;
    bool nv = n < n_nodes;
#pragma unroll
    for (int j = 0; j < 8; ++j) {
      int c = tx * 8 + j;
      if (c < 64) {
        qv[i][j] = acc[i][j] + Wq_bias[c];
        if (nv) Q[(size_t)n * 64 + c] = qv[i][j];
      } else {
        qv[i][j] = 0.f;
        if (nv) KB[(size_t)n * 64 + (c - 64)] = acc[i][j];
      }
    }
  }
#pragma unroll
  for (int r = 0; r < NREL; ++r) {
    float rk8[8];
    *reinterpret_cast<float4*>(&rk8[0]) =
        *reinterpret_cast<float4*>(&rks[r][(tx & 7) * 8]);
    *reinterpret_cast<float4*>(&rk8[4]) =
        *reinterpret_cast<float4*>(&rks[r][(tx & 7) * 8 + 4]);
#pragma unroll
    for (int i = 0; i < 4; ++i) {
      float pq = 0.f;
#pragma unroll
      for (int j = 0; j < 8; ++j) pq += qv[i][j] * rk8[j];
      pq += __shfl_xor(pq, 1, 64);
      pq += __shfl_xor(pq, 2, 64);
      pq += __shfl_xor(pq, 4, 64);
      pq += __shfl_xor(pq, 8, 64);
      int n = n0 + ty * 4 + i;
      if (tx == r && n < n_nodes) QR[(size_t)n * NREL + r] = pq;
    }
  }
}

__global__ void k2_hist(const int* __restrict__ dst, int* __restrict__ counts, int E) {
  int e = blockIdx.x * blockDim.x + threadIdx.x;
  if (e < E) atomicAdd(&counts[dst[e]], 1);
}

// hierarchical scan: A (per-1024-block exclusive) -> B (block sums) -> C (add)
__global__ void scan_a(const int* __restrict__ counts, int* __restrict__ partial,
                       int* __restrict__ blocksums, int n) {
  __shared__ int wsum[4];
  int tid = threadIdx.x, lane = tid & 63, wv = tid >> 6;
  int base = blockIdx.x * 1024 + tid * 4;
  int4 v = make_int4(0, 0, 0, 0);
  if (base + 3 < n) v = *reinterpret_cast<const int4*>(counts + base);
  else {
    if (base < n) v.x = counts[base];
    if (base + 1 < n) v.y = counts[base + 1];
    if (base + 2 < n) v.z = counts[base + 2];
  }
  int tsum = v.x + v.y + v.z + v.w;
  int s = tsum;
#pragma unroll
  for (int off = 1; off < 64; off <<= 1) {
    int y = __shfl_up(s, off, 64);
    if (lane >= off) s += y;
  }
  if (lane == 63) wsum[wv] = s;
  __syncthreads();
  int woff = 0;
  for (int w = 0; w < wv; ++w) woff += wsum[w];
  int o0 = woff + s - tsum;
  if (base < n) partial[base] = o0;
  if (base + 1 < n) partial[base + 1] = o0 + v.x;
  if (base + 2 < n) partial[base + 2] = o0 + v.x + v.y;
  if (base + 3 < n) partial[base + 3] = o0 + v.x + v.y + v.z;
  if (tid == 255) blocksums[blockIdx.x] = woff + s;
}

__global__ void scan_b(const int* __restrict__ blocksums, int* __restrict__ blockoff,
                       int nb, int* __restrict__ offsets, int n) {
  int lane = threadIdx.x;
  int v = (lane < nb) ? blocksums[lane] : 0;
  int s = v;
#pragma unroll
  for (int off = 1; off < 64; off <<= 1) {
    int y = __shfl_up(s, off, 64);
    if (lane >= off) s += y;
  }
  if (lane < nb) blockoff[lane] = s - v;
  if (lane == 63) offsets[n] = s;
}

__global__ void scan_c(const int* __restrict__ partial, const int* __restrict__ blockoff,
                       int* __restrict__ offsets, int* __restrict__ cursor, int n) {
  int i = blockIdx.x * 256 + threadIdx.x;
  if (i < n) {
    int v = partial[i] + blockoff[i >> 10];
    offsets[i] = v;
    cursor[i] = v;
  }
}

__global__ void k2_scatter(const int* __restrict__ dst, int* __restrict__ cursor,
                           int* __restrict__ csr, int E) {
  int e = blockIdx.x * blockDim.x + threadIdx.x;
  if (e < E) {
    int p = atomicAdd(&cursor[dst[e]], 1);
    csr[p] = e;
  }
}

// K3: edge-parallel scores in CSR position order. 16 lanes per edge, float4 gathers.
__global__ void k3_scores(const float* __restrict__ Q, const float* __restrict__ KB,
                          const float* __restrict__ QR,
                          const int* __restrict__ csr, const int* __restrict__ srcp,
                          const int* __restrict__ dstp, const int* __restrict__ etp,
                          float* __restrict__ scores, int E) {
  int tid = threadIdx.x;
  int lane = tid & 63;
  int li = lane & 15, sub = lane >> 4, wv = tid >> 6;
  int pos = blockIdx.x * 16 + wv * 4 + sub;
  if (pos >= E) return;
  int e = csr[pos];
  int dn = dstp[e], sn = srcp[e], r = etp[e];
  float4 q = *reinterpret_cast<const float4*>(Q + (size_t)dn * 64 + li * 4);
  float4 k = *reinterpret_cast<const float4*>(KB + (size_t)sn * 64 + li * 4);
  float p = q.x * k.x + q.y * k.y + q.z * k.z + q.w * k.w;
#pragma unroll
  for (int off = 1; off < 16; off <<= 1) p += __shfl_xor(p, off, 64);
  if (li == 0) scores[pos] = (p + QR[(size_t)dn * NREL + r]) * SCALE;
}

#define ACC_SWITCH(rr, v)                    \
  switch (rr) {                              \
    case 0: acc[0] += (v); break;            \
    case 1: acc[1] += (v); break;            \
    case 2: acc[2] += (v); break;            \
    case 3: acc[3] += (v); break;            \
    case 4: acc[4] += (v); break;            \
    case 5: acc[5] += (v); break;            \
    case 6: acc[6] += (v); break;            \
    case 7: acc[7] += (v); break;            \
  }

// K4: one wave per node; readlane-scalarized broadcast loop; bf16 x gathers.
__global__ void k4_agg(const __hip_bfloat16* __restrict__ xb,
                       const float* __restrict__ scores,
                       const int* __restrict__ offsets, const int* __restrict__ csr,
                       const int* __restrict__ srcp, const int* __restrict__ etp,
                       __hip_bfloat16* __restrict__ A, int n_nodes) {
  int lane = threadIdx.x & 63, wv = threadIdx.x >> 6;
  int n = blockIdx.x * 4 + wv;
  if (n >= n_nodes) return;
  int s0 = offsets[n], s1 = offsets[n + 1];
  int deg = s1 - s0;
  float acc[8] = {0.f, 0.f, 0.f, 0.f, 0.f, 0.f, 0.f, 0.f};
  if (deg > 0 && deg <= 64) {
    int p = s0 + lane;
    bool valid = p < s1;
    int e = valid ? csr[p] : 0;
    float sc = valid ? scores[p] : -1e30f;
    int sl = valid ? srcp[e] : 0;
    int rl = valid ? etp[e] : 0;
    float m = wave_max64(sc);
    float ex = valid ? __expf(sc - m) : 0.f;
    float t = wave_sum64(ex);
    float wl = ex * (1.0f / t);
    for (int i = 0; i < deg; ++i) {
      float wgt = __int_as_float(__builtin_amdgcn_readlane(__float_as_int(wl), i));
      int sn = __builtin_amdgcn_readlane(sl, i);
      int rr = __builtin_amdgcn_readlane(rl, i);
      float v = wgt * __bfloat162float(xb[((size_t)sn << 6) + lane]);
      ACC_SWITCH(rr, v)
    }
  } else if (deg > 64) {
    float m = -1e30f;
    for (int c = s0; c < s1; c += 64) {
      int p = c + lane;
      float s = (p < s1) ? scores[p] : -1e30f;
      m = fmaxf(m, s);
    }
    m = wave_max64(m);
    float t = 0.f;
    for (int c = s0; c < s1; c += 64) {
      int p = c + lane;
      t += (p < s1) ? __expf(scores[p] - m) : 0.f;
    }
    t = wave_sum64(t);
    float inv = 1.0f / t;
    for (int c = s0; c < s1; c += 64) {
      int p = c + lane;
      bool valid = p < s1;
      int e = valid ? csr[p] : 0;
      int sl = valid ? srcp[e] : 0;
      int rl = valid ? etp[e] : 0;
      float wl = valid ? __expf(scores[p] - m) * inv : 0.f;
      int cnt = min(64, s1 - c);
      for (int i = 0; i < cnt; ++i) {
        float wgt = __int_as_float(__builtin_amdgcn_readlane(__float_as_int(wl), i));
        int sn = __builtin_amdgcn_readlane(sl, i);
        int rr = __builtin_amdgcn_readlane(rl, i);
        float v = wgt * __bfloat162float(xb[((size_t)sn << 6) + lane]);
        ACC_SWITCH(rr, v)
      }
    }
  }
#pragma unroll
  for (int r = 0; r < 8; ++r)
    A[(size_t)n * 512 + r * 64 + lane] = __float2bfloat16(acc[r]);
}

// K5: out = relu(LN(A(50000x512 bf16) @ (Whi+Wlo) + bias)) via MFMA, LDS-free.
__global__ void __launch_bounds__(256) k5_mfma_ln(
    const __hip_bfloat16* __restrict__ A,
    const __hip_bfloat16* __restrict__ Whi,
    const __hip_bfloat16* __restrict__ Wlo,
    const float* __restrict__ bias,
    const float* __restrict__ ln_g, const float* __restrict__ ln_b,
    float* __restrict__ out, int n_nodes) {
  int tid = threadIdx.x;
  int lane = tid & 63, w = tid >> 6;
  int li = lane & 15, gr = lane >> 4;
  int n0 = blockIdx.x * 64;
  int arow_n = n0 + w * 16 + li;
  bool rvalid = arow_n < n_nodes;
  const __hip_bfloat16* arow = A + (size_t)arow_n * 512 + gr * 8;
  const bf16x8v* wh = reinterpret_cast<const bf16x8v*>(Whi);
  const bf16x8v* wl = reinterpret_cast<const bf16x8v*>(Wlo);
  f32x4v acc[4];
#pragma unroll
  for (int ct = 0; ct < 4; ++ct) acc[ct] = (f32x4v){0.f, 0.f, 0.f, 0.f};
  for (int ks = 0; ks < 16; ++ks) {
    uint4 au = make_uint4(0u, 0u, 0u, 0u);
    if (rvalid) au = *reinterpret_cast<const uint4*>(arow + ks * 32);
    bf16x8v a = __builtin_bit_cast(bf16x8v, au);
#pragma unroll
    for (int ct = 0; ct < 4; ++ct) {
      bf16x8v bh = wh[(ct * 16 + ks) * 64 + lane];
      bf16x8v bl = wl[(ct * 16 + ks) * 64 + lane];
      acc[ct] = __builtin_amdgcn_mfma_f32_16x16x32_bf16(a, bh, acc[ct], 0, 0, 0);
      acc[ct] = __builtin_amdgcn_mfma_f32_16x16x32_bf16(a, bl, acc[ct], 0, 0, 0);
    }
  }
  float bi[4], g[4], bb[4];
#pragma unroll
  for (int ct = 0; ct < 4; ++ct) {
    int col = ct * 16 + li;
    bi[ct] = bias[col];
    g[ct] = ln_g[col];
    bb[ct] = ln_b[col];
  }
#pragma unroll
  for (int reg = 0; reg < 4; ++reg) {
    float v[4];
#pragma unroll
    for (int ct = 0; ct < 4; ++ct) v[ct] = acc[ct][reg] + bi[ct];
    float s = v[0] + v[1] + v[2] + v[3];
    s += __shfl_xor(s, 1, 64);
    s += __shfl_xor(s, 2, 64);
    s += __shfl_xor(s, 4, 64);
    s += __shfl_xor(s, 8, 64);
    float mu = s * (1.0f / 64.0f);
    float sq = 0.f;
#pragma unroll
    for (int ct = 0; ct < 4; ++ct) {
      float d = v[ct] - mu;
      sq += d * d;
    }
    sq += __shfl_xor(sq, 1, 64);
    sq += __shfl_xor(sq, 2, 64);
    sq += __shfl_xor(sq, 4, 64);
    sq += __shfl_xor(sq, 8, 64);
    float inv = rsqrtf(sq * (1.0f / 64.0f) + LN_EPS);
    int n = n0 + w * 16 + gr * 4 + reg;
    if (n < n_nodes) {
#pragma unroll
      for (int ct = 0; ct < 4; ++ct) {
        float y = (v[ct] - mu) * inv * g[ct] + bb[ct];
        out[(size_t)n * 64 + ct * 16 + li] = fmaxf(y, 0.f);
      }
    }
  }
}

extern "C" void kernel_launch(void* const* d_in, const int* in_sizes, int n_in,
                              void* d_out, int out_size, void* d_ws, size_t ws_size,
                              hipStream_t stream) {
  (void)n_in; (void)out_size; (void)ws_size;
  const float* x = (const float*)d_in[0];
  const int* ei = (const int*)d_in[1];
  const int* et = (const int*)d_in[2];
  const float* W_r = (const float*)d_in[4];
  const float* Wq_w = (const float*)d_in[5];
  const float* Wq_b = (const float*)d_in[6];
  const float* Wk_w = (const float*)d_in[7];
  const float* bias = (const float*)d_in[10];
  const float* ln_g = (const float*)d_in[11];
  const float* ln_b = (const float*)d_in[12];

  int N = in_sizes[0] / NDIM;
  int E = in_sizes[2];
  const int* srcp = ei;
  const int* dstp = ei + E;

  char* p = (char*)d_ws;
  auto alloc = [&](size_t bytes) {
    void* r = (void*)p;
    p += (bytes + 255) & ~(size_t)255;
    return r;
  };
  float* Q = (float*)alloc((size_t)N * NDIM * 4);
  float* KB = (float*)alloc((size_t)N * NDIM * 4);
  float* QR = (float*)alloc((size_t)N * NREL * 4);
  float* relkey = (float*)alloc(NREL * NDIM * 4);
  __hip_bfloat16* xbf = (__hip_bfloat16*)alloc((size_t)N * NDIM * 2);
  int* counts = (int*)alloc((size_t)N * 4);
  int* partial = (int*)alloc((size_t)N * 4);
  int* offsets = (int*)alloc((size_t)(N + 1) * 4);
  int* cursor = (int*)alloc((size_t)N * 4);
  int* blocksums = (int*)alloc(64 * 4);
  int* blockoff = (int*)alloc(64 * 4);
  int* csr = (int*)alloc((size_t)E * 4);
  float* scores = (float*)alloc((size_t)E * 4);
  __hip_bfloat16* A = (__hip_bfloat16*)alloc((size_t)N * (NREL * NDIM) * 2);
  __hip_bfloat16* Whi = (__hip_bfloat16*)alloc(4 * 16 * 64 * 8 * 2);
  __hip_bfloat16* Wlo = (__hip_bfloat16*)alloc(4 * 16 * 64 * 8 * 2);

  int nscan = (N + 1023) / 1024;

  hipMemsetAsync(counts, 0, (size_t)N * 4, stream);
  k0_relkey<<<1, 256, 0, stream>>>(W_r, Wk_w, relkey);
  k0b_packw<<<(4 * 16 * 64 * 8 + 255) / 256, 256, 0, stream>>>(W_r, Whi, Wlo);
  k1c_xbf<<<1024, 256, 0, stream>>>(x, xbf, N * NDIM / 4);
  k1_qkb<<<(N + 63) / 64, 256, 0, stream>>>(x, Wq_w, Wq_b, Wk_w, relkey, Q, KB, QR, N);
  k2_hist<<<(E + 255) / 256, 256, 0, stream>>>(dstp, counts, E);
  scan_a<<<nscan, 256, 0, stream>>>(counts, partial, blocksums, N);
  scan_b<<<1, 64, 0, stream>>>(blocksums, blockoff, nscan, offsets, N);
  scan_c<<<(N + 255) / 256, 256, 0, stream>>>(partial, blockoff, offsets, cursor, N);
  k2_scatter<<<(E + 255) / 256, 256, 0, stream>>>(dstp, cursor, csr, E);
  k3_scores<<<(E + 15) / 16, 256, 0, stream>>>(Q, KB, QR, csr, srcp, dstp, et, scores, E);
  k4_agg<<<(N + 3) / 4, 256, 0, stream>>>(xbf, scores, offsets, csr, srcp, et, A, N);
  k5_mfma_ln<<<(N + 63) / 64, 256, 0, stream>>>(A, Whi, Wlo, bias, ln_g, ln_b,
                                                (float*)d_out, N);
}

// Round 10
// 372.405 us; speedup vs baseline: 2.4718x; 1.0845x over previous
//
#include <hip/hip_runtime.h>
#include <hip/hip_bf16.h>

#define NDIM 64
#define NREL 8
#define SCALE 0.125f
#define LN_EPS 1e-5f

typedef __bf16 bf16x8v __attribute__((ext_vector_type(8)));
typedef float f32x4v __attribute__((ext_vector_type(4)));

__device__ __forceinline__ float wave_sum64(float v) {
#pragma unroll
  for (int off = 32; off > 0; off >>= 1) v += __shfl_xor(v, off, 64);
  return v;
}
__device__ __forceinline__ float wave_max64(float v) {
#pragma unroll
  for (int off = 32; off > 0; off >>= 1) v = fmaxf(v, __shfl_xor(v, off, 64));
  return v;
}
__device__ __forceinline__ unsigned short f2bf_u(float f) {
  __hip_bfloat16 h = __float2bfloat16(f);
  return *reinterpret_cast<unsigned short*>(&h);
}
__device__ __forceinline__ float bfu2f(unsigned short u) {
  return __uint_as_float(((unsigned)u) << 16);
}

// K0: relkey[r][o] = mean_last(W_r[r]) @ Wk2   (Wk_bias cancels in segment softmax)
__global__ void k0_relkey(const float* __restrict__ W_r,
                          const float* __restrict__ Wk_w,
                          float* __restrict__ relkey) {
  __shared__ float relemb[NREL * NDIM];
  int tid = threadIdx.x;
  for (int idx = tid; idx < NREL * NDIM; idx += 256) {
    int r = idx >> 6, i = idx & 63;
    const float* wr = W_r + (size_t)(r * NDIM + i) * NDIM;
    float s = 0.f;
#pragma unroll
    for (int o = 0; o < NDIM; ++o) s += wr[o];
    relemb[idx] = s * (1.0f / NDIM);
  }
  __syncthreads();
  for (int idx = tid; idx < NREL * NDIM; idx += 256) {
    int r = idx >> 6, o = idx & 63;
    float s = 0.f;
#pragma unroll
    for (int i = 0; i < NDIM; ++i) s += relemb[r * NDIM + i] * Wk_w[(NDIM + i) * NDIM + o];
    relkey[idx] = s;
  }
}

// K0b: pack W_r (viewed as [512][64]) into MFMA B-fragment order, hi/lo bf16 split.
__global__ void k0b_packw(const float* __restrict__ W_r,
                          __hip_bfloat16* __restrict__ Whi,
                          __hip_bfloat16* __restrict__ Wlo) {
  int idx = blockIdx.x * 256 + threadIdx.x;
  if (idx >= 4 * 16 * 64 * 8) return;
  int j = idx & 7;
  int l = (idx >> 3) & 63;
  int ks = (idx >> 9) & 15;
  int ct = idx >> 13;
  int k = ks * 32 + (l >> 4) * 8 + j;
  int col = ct * 16 + (l & 15);
  float v = W_r[(size_t)k * 64 + col];
  __hip_bfloat16 h = __float2bfloat16(v);
  Whi[idx] = h;
  Wlo[idx] = __float2bfloat16(v - __bfloat162float(h));
}

// K1c: xbf = bf16(x), vectorized grid-stride copy.
__global__ void k1c_xbf(const float* __restrict__ x, __hip_bfloat16* __restrict__ xbf,
                        int total4) {
  int i = blockIdx.x * blockDim.x + threadIdx.x;
  int stride = gridDim.x * blockDim.x;
  for (; i < total4; i += stride) {
    float4 v = *reinterpret_cast<const float4*>(x + (size_t)i * 4);
    ushort4 u;
    u.x = f2bf_u(v.x); u.y = f2bf_u(v.y); u.z = f2bf_u(v.z); u.w = f2bf_u(v.w);
    *reinterpret_cast<ushort4*>(reinterpret_cast<unsigned short*>(xbf) +
                                (size_t)i * 4) = u;
  }
}

// K1: Q(fp32) = x@Wq + bq; KBbf(bf16) = x@Wk1; fused QR[n][r] = Q[n].relkey[r].
__global__ void k1_qkb(const float* __restrict__ x,
                       const float* __restrict__ Wq_w,
                       const float* __restrict__ Wq_bias,
                       const float* __restrict__ Wk_w,
                       const float* __restrict__ relkey,
                       float* __restrict__ Q, __hip_bfloat16* __restrict__ KBbf,
                       float* __restrict__ QR, int n_nodes) {
  __shared__ float xs[64][68];
  __shared__ float ws[64][128];
  __shared__ float rks[NREL][NDIM];
  int tid = threadIdx.x;
  int n0 = blockIdx.x * 64;
  for (int idx = tid; idx < 64 * 128; idx += 256) {
    int r = idx >> 7, c = idx & 127;
    ws[r][c] = (c < 64) ? Wq_w[r * 64 + c] : Wk_w[r * 64 + (c - 64)];
  }
  for (int idx = tid; idx < NREL * NDIM; idx += 256)
    rks[idx >> 6][idx & 63] = relkey[idx];
  for (int idx = tid; idx < 64 * 16; idx += 256) {
    int r = idx >> 4, c4 = (idx & 15) * 4;
    int n = n0 + r;
    float4 v = make_float4(0.f, 0.f, 0.f, 0.f);
    if (n < n_nodes) v = *reinterpret_cast<const float4*>(x + (size_t)n * 64 + c4);
    *reinterpret_cast<float4*>(&xs[r][c4]) = v;
  }
  __syncthreads();
  int tx = tid & 15, ty = tid >> 4;
  float acc[4][8] = {};
  for (int k = 0; k < 64; k += 4) {
    float4 a[4];
#pragma unroll
    for (int i = 0; i < 4; ++i) a[i] = *reinterpret_cast<float4*>(&xs[ty * 4 + i][k]);
#pragma unroll
    for (int kk = 0; kk < 4; ++kk) {
      float4 w0 = *reinterpret_cast<float4*>(&ws[k + kk][tx * 8]);
      float4 w1 = *reinterpret_cast<float4*>(&ws[k + kk][tx * 8 + 4]);
#pragma unroll
      for (int i = 0; i < 4; ++i) {
        float av = (kk == 0) ? a[i].x : (kk == 1) ? a[i].y : (kk == 2) ? a[i].z : a[i].w;
        acc[i][0] += av * w0.x; acc[i][1] += av * w0.y;
        acc[i][2] += av * w0.z; acc[i][3] += av * w0.w;
        acc[i][4] += av * w1.x; acc[i][5] += av * w1.y;
        acc[i][6] += av * w1.z; acc[i][7] += av * w1.w;
      }
    }
  }
  float qv[4][8];
#pragma unroll
  for (int i = 0; i < 4; ++i) {
    int n = n0 + ty * 4 + i;
    bool nv = n < n_nodes;
#pragma unroll
    for (int j = 0; j < 8; ++j) {
      int c = tx * 8 + j;
      if (c < 64) {
        qv[i][j] = acc[i][j] + Wq_bias[c];
        if (nv) Q[(size_t)n * 64 + c] = qv[i][j];
      } else {
        qv[i][j] = 0.f;
      }
    }
    // KB half (tx>=8): 8 consecutive bf16 columns -> pack into one ushort4x2 store
    if (nv && tx >= 8) {
      ushort4 u0, u1;
      u0.x = f2bf_u(acc[i][0]); u0.y = f2bf_u(acc[i][1]);
      u0.z = f2bf_u(acc[i][2]); u0.w = f2bf_u(acc[i][3]);
      u1.x = f2bf_u(acc[i][4]); u1.y = f2bf_u(acc[i][5]);
      u1.z = f2bf_u(acc[i][6]); u1.w = f2bf_u(acc[i][7]);
      unsigned short* kp = reinterpret_cast<unsigned short*>(KBbf) +
                           ((size_t)n << 6) + (tx - 8) * 8;
      *reinterpret_cast<ushort4*>(kp) = u0;
      *reinterpret_cast<ushort4*>(kp + 4) = u1;
    }
  }
#pragma unroll
  for (int r = 0; r < NREL; ++r) {
    float rk8[8];
    *reinterpret_cast<float4*>(&rk8[0]) =
        *reinterpret_cast<float4*>(&rks[r][(tx & 7) * 8]);
    *reinterpret_cast<float4*>(&rk8[4]) =
        *reinterpret_cast<float4*>(&rks[r][(tx & 7) * 8 + 4]);
#pragma unroll
    for (int i = 0; i < 4; ++i) {
      float pq = 0.f;
#pragma unroll
      for (int j = 0; j < 8; ++j) pq += qv[i][j] * rk8[j];
      pq += __shfl_xor(pq, 1, 64);
      pq += __shfl_xor(pq, 2, 64);
      pq += __shfl_xor(pq, 4, 64);
      pq += __shfl_xor(pq, 8, 64);
      int n = n0 + ty * 4 + i;
      if (tx == r && n < n_nodes) QR[(size_t)n * NREL + r] = pq;
    }
  }
}

__global__ void k2_hist(const int* __restrict__ dst, int* __restrict__ counts, int E) {
  int e = blockIdx.x * blockDim.x + threadIdx.x;
  if (e < E) atomicAdd(&counts[dst[e]], 1);
}

// hierarchical scan: A (per-1024-block exclusive) -> B (block sums) -> C (add)
__global__ void scan_a(const int* __restrict__ counts, int* __restrict__ partial,
                       int* __restrict__ blocksums, int n) {
  __shared__ int wsum[4];
  int tid = threadIdx.x, lane = tid & 63, wv = tid >> 6;
  int base = blockIdx.x * 1024 + tid * 4;
  int4 v = make_int4(0, 0, 0, 0);
  if (base + 3 < n) v = *reinterpret_cast<const int4*>(counts + base);
  else {
    if (base < n) v.x = counts[base];
    if (base + 1 < n) v.y = counts[base + 1];
    if (base + 2 < n) v.z = counts[base + 2];
  }
  int tsum = v.x + v.y + v.z + v.w;
  int s = tsum;
#pragma unroll
  for (int off = 1; off < 64; off <<= 1) {
    int y = __shfl_up(s, off, 64);
    if (lane >= off) s += y;
  }
  if (lane == 63) wsum[wv] = s;
  __syncthreads();
  int woff = 0;
  for (int w = 0; w < wv; ++w) woff += wsum[w];
  int o0 = woff + s - tsum;
  if (base < n) partial[base] = o0;
  if (base + 1 < n) partial[base + 1] = o0 + v.x;
  if (base + 2 < n) partial[base + 2] = o0 + v.x + v.y;
  if (base + 3 < n) partial[base + 3] = o0 + v.x + v.y + v.z;
  if (tid == 255) blocksums[blockIdx.x] = woff + s;
}

__global__ void scan_b(const int* __restrict__ blocksums, int* __restrict__ blockoff,
                       int nb, int* __restrict__ offsets, int n) {
  int lane = threadIdx.x;
  int v = (lane < nb) ? blocksums[lane] : 0;
  int s = v;
#pragma unroll
  for (int off = 1; off < 64; off <<= 1) {
    int y = __shfl_up(s, off, 64);
    if (lane >= off) s += y;
  }
  if (lane < nb) blockoff[lane] = s - v;
  if (lane == 63) offsets[n] = s;
}

__global__ void scan_c(const int* __restrict__ partial, const int* __restrict__ blockoff,
                       int* __restrict__ offsets, int* __restrict__ cursor, int n) {
  int i = blockIdx.x * 256 + threadIdx.x;
  if (i < n) {
    int v = partial[i] + blockoff[i >> 10];
    offsets[i] = v;
    cursor[i] = v;
  }
}

// scatter: permute src/dst/et into CSR position order (no csr indirection later)
__global__ void k2_scatter(const int* __restrict__ dst, const int* __restrict__ src,
                           const int* __restrict__ et, int* __restrict__ cursor,
                           int* __restrict__ src_pos, int* __restrict__ dst_pos,
                           int* __restrict__ et_pos, int E) {
  int e = blockIdx.x * blockDim.x + threadIdx.x;
  if (e < E) {
    int d = dst[e];
    int p = atomicAdd(&cursor[d], 1);
    src_pos[p] = src[e];
    dst_pos[p] = d;
    et_pos[p] = et[e];
  }
}

// K3: edge-parallel scores in CSR position order. 16 lanes per edge;
// contiguous permuted metadata; bf16 KB gathers (8B/lane).
__global__ void k3_scores(const float* __restrict__ Q,
                          const __hip_bfloat16* __restrict__ KBbf,
                          const float* __restrict__ QR,
                          const int* __restrict__ src_pos,
                          const int* __restrict__ dst_pos,
                          const int* __restrict__ et_pos,
                          float* __restrict__ scores, int E) {
  int tid = threadIdx.x;
  int lane = tid & 63;
  int li = lane & 15, sub = lane >> 4, wv = tid >> 6;
  int pos = blockIdx.x * 16 + wv * 4 + sub;
  if (pos >= E) return;
  int dn = dst_pos[pos], sn = src_pos[pos], r = et_pos[pos];
  float4 q = *reinterpret_cast<const float4*>(Q + (size_t)dn * 64 + li * 4);
  ushort4 u = *reinterpret_cast<const ushort4*>(
      reinterpret_cast<const unsigned short*>(KBbf) + ((size_t)sn << 6) + li * 4);
  float p = q.x * bfu2f(u.x) + q.y * bfu2f(u.y) + q.z * bfu2f(u.z) + q.w * bfu2f(u.w);
#pragma unroll
  for (int off = 1; off < 16; off <<= 1) p += __shfl_xor(p, off, 64);
  if (li == 0) scores[pos] = (p + QR[(size_t)dn * NREL + r]) * SCALE;
}

#define ACC_SWITCH(rr, v)                    \
  switch (rr) {                              \
    case 0: acc[0] += (v); break;            \
    case 1: acc[1] += (v); break;            \
    case 2: acc[2] += (v); break;            \
    case 3: acc[3] += (v); break;            \
    case 4: acc[4] += (v); break;            \
    case 5: acc[5] += (v); break;            \
    case 6: acc[6] += (v); break;            \
    case 7: acc[7] += (v); break;            \
  }

// K4: one wave per node; contiguous permuted metadata; bf16 x gathers;
// readlane-scalarized broadcast loop.
__global__ void k4_agg(const __hip_bfloat16* __restrict__ xb,
                       const float* __restrict__ scores,
                       const int* __restrict__ offsets,
                       const int* __restrict__ src_pos, const int* __restrict__ et_pos,
                       __hip_bfloat16* __restrict__ A, int n_nodes) {
  int lane = threadIdx.x & 63, wv = threadIdx.x >> 6;
  int n = blockIdx.x * 4 + wv;
  if (n >= n_nodes) return;
  int s0 = offsets[n], s1 = offsets[n + 1];
  int deg = s1 - s0;
  float acc[8] = {0.f, 0.f, 0.f, 0.f, 0.f, 0.f, 0.f, 0.f};
  if (deg > 0 && deg <= 64) {
    int p = s0 + lane;
    bool valid = p < s1;
    float sc = valid ? scores[p] : -1e30f;
    int sl = valid ? src_pos[p] : 0;
    int rl = valid ? et_pos[p] : 0;
    float m = wave_max64(sc);
    float ex = valid ? __expf(sc - m) : 0.f;
    float t = wave_sum64(ex);
    float wl = ex * (1.0f / t);
    for (int i = 0; i < deg; ++i) {
      float wgt = __int_as_float(__builtin_amdgcn_readlane(__float_as_int(wl), i));
      int sn = __builtin_amdgcn_readlane(sl, i);
      int rr = __builtin_amdgcn_readlane(rl, i);
      float v = wgt * __bfloat162float(xb[((size_t)sn << 6) + lane]);
      ACC_SWITCH(rr, v)
    }
  } else if (deg > 64) {
    float m = -1e30f;
    for (int c = s0; c < s1; c += 64) {
      int p = c + lane;
      float s = (p < s1) ? scores[p] : -1e30f;
      m = fmaxf(m, s);
    }
    m = wave_max64(m);
    float t = 0.f;
    for (int c = s0; c < s1; c += 64) {
      int p = c + lane;
      t += (p < s1) ? __expf(scores[p] - m) : 0.f;
    }
    t = wave_sum64(t);
    float inv = 1.0f / t;
    for (int c = s0; c < s1; c += 64) {
      int p = c + lane;
      bool valid = p < s1;
      int sl = valid ? src_pos[p] : 0;
      int rl = valid ? et_pos[p] : 0;
      float wl = valid ? __expf(scores[p] - m) * inv : 0.f;
      int cnt = min(64, s1 - c);
      for (int i = 0; i < cnt; ++i) {
        float wgt = __int_as_float(__builtin_amdgcn_readlane(__float_as_int(wl), i));
        int sn = __builtin_amdgcn_readlane(sl, i);
        int rr = __builtin_amdgcn_readlane(rl, i);
        float v = wgt * __bfloat162float(xb[((size_t)sn << 6) + lane]);
        ACC_SWITCH(rr, v)
      }
    }
  }
#pragma unroll
  for (int r = 0; r < 8; ++r)
    A[(size_t)n * 512 + r * 64 + lane] = __float2bfloat16(acc[r]);
}

// K5: out = relu(LN(A(50000x512 bf16) @ (Whi+Wlo) + bias)) via MFMA, LDS-free.
__global__ void __launch_bounds__(256) k5_mfma_ln(
    const __hip_bfloat16* __restrict__ A,
    const __hip_bfloat16* __restrict__ Whi,
    const __hip_bfloat16* __restrict__ Wlo,
    const float* __restrict__ bias,
    const float* __restrict__ ln_g, const float* __restrict__ ln_b,
    float* __restrict__ out, int n_nodes) {
  int tid = threadIdx.x;
  int lane = tid & 63, w = tid >> 6;
  int li = lane & 15, gr = lane >> 4;
  int n0 = blockIdx.x * 64;
  int arow_n = n0 + w * 16 + li;
  bool rvalid = arow_n < n_nodes;
  const __hip_bfloat16* arow = A + (size_t)arow_n * 512 + gr * 8;
  const bf16x8v* wh = reinterpret_cast<const bf16x8v*>(Whi);
  const bf16x8v* wl = reinterpret_cast<const bf16x8v*>(Wlo);
  f32x4v acc[4];
#pragma unroll
  for (int ct = 0; ct < 4; ++ct) acc[ct] = (f32x4v){0.f, 0.f, 0.f, 0.f};
  for (int ks = 0; ks < 16; ++ks) {
    uint4 au = make_uint4(0u, 0u, 0u, 0u);
    if (rvalid) au = *reinterpret_cast<const uint4*>(arow + ks * 32);
    bf16x8v a = __builtin_bit_cast(bf16x8v, au);
#pragma unroll
    for (int ct = 0; ct < 4; ++ct) {
      bf16x8v bh = wh[(ct * 16 + ks) * 64 + lane];
      bf16x8v bl = wl[(ct * 16 + ks) * 64 + lane];
      acc[ct] = __builtin_amdgcn_mfma_f32_16x16x32_bf16(a, bh, acc[ct], 0, 0, 0);
      acc[ct] = __builtin_amdgcn_mfma_f32_16x16x32_bf16(a, bl, acc[ct], 0, 0, 0);
    }
  }
  float bi[4], g[4], bb[4];
#pragma unroll
  for (int ct = 0; ct < 4; ++ct) {
    int col = ct * 16 + li;
    bi[ct] = bias[col];
    g[ct] = ln_g[col];
    bb[ct] = ln_b[col];
  }
#pragma unroll
  for (int reg = 0; reg < 4; ++reg) {
    float v[4];
#pragma unroll
    for (int ct = 0; ct < 4; ++ct) v[ct] = acc[ct][reg] + bi[ct];
    float s = v[0] + v[1] + v[2] + v[3];
    s += __shfl_xor(s, 1, 64);
    s += __shfl_xor(s, 2, 64);
    s += __shfl_xor(s, 4, 64);
    s += __shfl_xor(s, 8, 64);
    float mu = s * (1.0f / 64.0f);
    float sq = 0.f;
#pragma unroll
    for (int ct = 0; ct < 4; ++ct) {
      float d = v[ct] - mu;
      sq += d * d;
    }
    sq += __shfl_xor(sq, 1, 64);
    sq += __shfl_xor(sq, 2, 64);
    sq += __shfl_xor(sq, 4, 64);
    sq += __shfl_xor(sq, 8, 64);
    float inv = rsqrtf(sq * (1.0f / 64.0f) + LN_EPS);
    int n = n0 + w * 16 + gr * 4 + reg;
    if (n < n_nodes) {
#pragma unroll
      for (int ct = 0; ct < 4; ++ct) {
        float y = (v[ct] - mu) * inv * g[ct] + bb[ct];
        out[(size_t)n * 64 + ct * 16 + li] = fmaxf(y, 0.f);
      }
    }
  }
}

extern "C" void kernel_launch(void* const* d_in, const int* in_sizes, int n_in,
                              void* d_out, int out_size, void* d_ws, size_t ws_size,
                              hipStream_t stream) {
  (void)n_in; (void)out_size; (void)ws_size;
  const float* x = (const float*)d_in[0];
  const int* ei = (const int*)d_in[1];
  const int* et = (const int*)d_in[2];
  const float* W_r = (const float*)d_in[4];
  const float* Wq_w = (const float*)d_in[5];
  const float* Wq_b = (const float*)d_in[6];
  const float* Wk_w = (const float*)d_in[7];
  const float* bias = (const float*)d_in[10];
  const float* ln_g = (const float*)d_in[11];
  const float* ln_b = (const float*)d_in[12];

  int N = in_sizes[0] / NDIM;
  int E = in_sizes[2];
  const int* srcp = ei;
  const int* dstp = ei + E;

  char* p = (char*)d_ws;
  auto alloc = [&](size_t bytes) {
    void* r = (void*)p;
    p += (bytes + 255) & ~(size_t)255;
    return r;
  };
  float* Q = (float*)alloc((size_t)N * NDIM * 4);
  __hip_bfloat16* KBbf = (__hip_bfloat16*)alloc((size_t)N * NDIM * 2);
  float* QR = (float*)alloc((size_t)N * NREL * 4);
  float* relkey = (float*)alloc(NREL * NDIM * 4);
  __hip_bfloat16* xbf = (__hip_bfloat16*)alloc((size_t)N * NDIM * 2);
  int* counts = (int*)alloc((size_t)N * 4);
  int* partial = (int*)alloc((size_t)N * 4);
  int* offsets = (int*)alloc((size_t)(N + 1) * 4);
  int* cursor = (int*)alloc((size_t)N * 4);
  int* blocksums = (int*)alloc(64 * 4);
  int* blockoff = (int*)alloc(64 * 4);
  int* src_pos = (int*)alloc((size_t)E * 4);
  int* dst_pos = (int*)alloc((size_t)E * 4);
  int* et_pos = (int*)alloc((size_t)E * 4);
  float* scores = (float*)alloc((size_t)E * 4);
  __hip_bfloat16* A = (__hip_bfloat16*)alloc((size_t)N * (NREL * NDIM) * 2);
  __hip_bfloat16* Whi = (__hip_bfloat16*)alloc(4 * 16 * 64 * 8 * 2);
  __hip_bfloat16* Wlo = (__hip_bfloat16*)alloc(4 * 16 * 64 * 8 * 2);

  int nscan = (N + 1023) / 1024;

  hipMemsetAsync(counts, 0, (size_t)N * 4, stream);
  k0_relkey<<<1, 256, 0, stream>>>(W_r, Wk_w, relkey);
  k0b_packw<<<(4 * 16 * 64 * 8 + 255) / 256, 256, 0, stream>>>(W_r, Whi, Wlo);
  k1c_xbf<<<1024, 256, 0, stream>>>(x, xbf, N * NDIM / 4);
  k1_qkb<<<(N + 63) / 64, 256, 0, stream>>>(x, Wq_w, Wq_b, Wk_w, relkey, Q, KBbf, QR, N);
  k2_hist<<<(E + 255) / 256, 256, 0, stream>>>(dstp, counts, E);
  scan_a<<<nscan, 256, 0, stream>>>(counts, partial, blocksums, N);
  scan_b<<<1, 64, 0, stream>>>(blocksums, blockoff, nscan, offsets, N);
  scan_c<<<(N + 255) / 256, 256, 0, stream>>>(partial, blockoff, offsets, cursor, N);
  k2_scatter<<<(E + 255) / 256, 256, 0, stream>>>(dstp, srcp, et, cursor, src_pos,
                                                  dst_pos, et_pos, E);
  k3_scores<<<(E + 15) / 16, 256, 0, stream>>>(Q, KBbf, QR, src_pos, dst_pos, et_pos,
                                               scores, E);
  k4_agg<<<(N + 3) / 4, 256, 0, stream>>>(xbf, scores, offsets, src_pos, et_pos, A, N);
  k5_mfma_ln<<<(N + 63) / 64, 256, 0, stream>>>(A, Whi, Wlo, bias, ln_g, ln_b,
                                                (float*)d_out, N);
}

// Round 11
// 345.180 us; speedup vs baseline: 2.6668x; 1.0789x over previous
//
#include <hip/hip_runtime.h>
#include <hip/hip_bf16.h>

#define NDIM 64
#define NREL 8
#define SCALE 0.125f
#define LN_EPS 1e-5f
#define SRC_MASK 0x07FFFFFF

typedef __bf16 bf16x8v __attribute__((ext_vector_type(8)));
typedef float f32x4v __attribute__((ext_vector_type(4)));

__device__ __forceinline__ float wave_sum64(float v) {
#pragma unroll
  for (int off = 32; off > 0; off >>= 1) v += __shfl_xor(v, off, 64);
  return v;
}
__device__ __forceinline__ float wave_max64(float v) {
#pragma unroll
  for (int off = 32; off > 0; off >>= 1) v = fmaxf(v, __shfl_xor(v, off, 64));
  return v;
}
__device__ __forceinline__ unsigned short f2bf_u(float f) {
  __hip_bfloat16 h = __float2bfloat16(f);
  return *reinterpret_cast<unsigned short*>(&h);
}
__device__ __forceinline__ float bfu2f(unsigned short u) {
  return __uint_as_float(((unsigned)u) << 16);
}
__device__ __forceinline__ float rdl_f(float v, int i) {
  return __int_as_float(__builtin_amdgcn_readlane(__float_as_int(v), i));
}

// K0: relkey[r][o] = mean_last(W_r[r]) @ Wk2   (Wk_bias cancels in segment softmax)
__global__ void k0_relkey(const float* __restrict__ W_r,
                          const float* __restrict__ Wk_w,
                          float* __restrict__ relkey) {
  __shared__ float relemb[NREL * NDIM];
  int tid = threadIdx.x;
  for (int idx = tid; idx < NREL * NDIM; idx += 256) {
    int r = idx >> 6, i = idx & 63;
    const float* wr = W_r + (size_t)(r * NDIM + i) * NDIM;
    float s = 0.f;
#pragma unroll
    for (int o = 0; o < NDIM; ++o) s += wr[o];
    relemb[idx] = s * (1.0f / NDIM);
  }
  __syncthreads();
  for (int idx = tid; idx < NREL * NDIM; idx += 256) {
    int r = idx >> 6, o = idx & 63;
    float s = 0.f;
#pragma unroll
    for (int i = 0; i < NDIM; ++i) s += relemb[r * NDIM + i] * Wk_w[(NDIM + i) * NDIM + o];
    relkey[idx] = s;
  }
}

// K0b: pack W_r (viewed as [512][64]) into MFMA B-fragment order, hi/lo bf16 split.
__global__ void k0b_packw(const float* __restrict__ W_r,
                          __hip_bfloat16* __restrict__ Whi,
                          __hip_bfloat16* __restrict__ Wlo) {
  int idx = blockIdx.x * 256 + threadIdx.x;
  if (idx >= 4 * 16 * 64 * 8) return;
  int j = idx & 7;
  int l = (idx >> 3) & 63;
  int ks = (idx >> 9) & 15;
  int ct = idx >> 13;
  int k = ks * 32 + (l >> 4) * 8 + j;
  int col = ct * 16 + (l & 15);
  float v = W_r[(size_t)k * 64 + col];
  __hip_bfloat16 h = __float2bfloat16(v);
  Whi[idx] = h;
  Wlo[idx] = __float2bfloat16(v - __bfloat162float(h));
}

// K1c: xbf = bf16(x), vectorized grid-stride copy.
__global__ void k1c_xbf(const float* __restrict__ x, __hip_bfloat16* __restrict__ xbf,
                        int total4) {
  int i = blockIdx.x * blockDim.x + threadIdx.x;
  int stride = gridDim.x * blockDim.x;
  for (; i < total4; i += stride) {
    float4 v = *reinterpret_cast<const float4*>(x + (size_t)i * 4);
    ushort4 u;
    u.x = f2bf_u(v.x); u.y = f2bf_u(v.y); u.z = f2bf_u(v.z); u.w = f2bf_u(v.w);
    *reinterpret_cast<ushort4*>(reinterpret_cast<unsigned short*>(xbf) +
                                (size_t)i * 4) = u;
  }
}

// K1: Q(fp32) = x@Wq + bq; KBbf(bf16) = x@Wk1; fused QR[n][r] = Q[n].relkey[r].
__global__ void k1_qkb(const float* __restrict__ x,
                       const float* __restrict__ Wq_w,
                       const float* __restrict__ Wq_bias,
                       const float* __restrict__ Wk_w,
                       const float* __restrict__ relkey,
                       float* __restrict__ Q, __hip_bfloat16* __restrict__ KBbf,
                       float* __restrict__ QR, int n_nodes) {
  __shared__ float xs[64][68];
  __shared__ float ws[64][128];
  __shared__ float rks[NREL][NDIM];
  int tid = threadIdx.x;
  int n0 = blockIdx.x * 64;
  for (int idx = tid; idx < 64 * 128; idx += 256) {
    int r = idx >> 7, c = idx & 127;
    ws[r][c] = (c < 64) ? Wq_w[r * 64 + c] : Wk_w[r * 64 + (c - 64)];
  }
  for (int idx = tid; idx < NREL * NDIM; idx += 256)
    rks[idx >> 6][idx & 63] = relkey[idx];
  for (int idx = tid; idx < 64 * 16; idx += 256) {
    int r = idx >> 4, c4 = (idx & 15) * 4;
    int n = n0 + r;
    float4 v = make_float4(0.f, 0.f, 0.f, 0.f);
    if (n < n_nodes) v = *reinterpret_cast<const float4*>(x + (size_t)n * 64 + c4);
    *reinterpret_cast<float4*>(&xs[r][c4]) = v;
  }
  __syncthreads();
  int tx = tid & 15, ty = tid >> 4;
  float acc[4][8] = {};
  for (int k = 0; k < 64; k += 4) {
    float4 a[4];
#pragma unroll
    for (int i = 0; i < 4; ++i) a[i] = *reinterpret_cast<float4*>(&xs[ty * 4 + i][k]);
#pragma unroll
    for (int kk = 0; kk < 4; ++kk) {
      float4 w0 = *reinterpret_cast<float4*>(&ws[k + kk][tx * 8]);
      float4 w1 = *reinterpret_cast<float4*>(&ws[k + kk][tx * 8 + 4]);
#pragma unroll
      for (int i = 0; i < 4; ++i) {
        float av = (kk == 0) ? a[i].x : (kk == 1) ? a[i].y : (kk == 2) ? a[i].z : a[i].w;
        acc[i][0] += av * w0.x; acc[i][1] += av * w0.y;
        acc[i][2] += av * w0.z; acc[i][3] += av * w0.w;
        acc[i][4] += av * w1.x; acc[i][5] += av * w1.y;
        acc[i][6] += av * w1.z; acc[i][7] += av * w1.w;
      }
    }
  }
  float qv[4][8];
#pragma unroll
  for (int i = 0; i < 4; ++i) {
    int n = n0 + ty * 4 + i;
    bool nv = n < n_nodes;
#pragma unroll
    for (int j = 0; j < 8; ++j) {
      int c = tx * 8 + j;
      if (c < 64) {
        qv[i][j] = acc[i][j] + Wq_bias[c];
        if (nv) Q[(size_t)n * 64 + c] = qv[i][j];
      } else {
        qv[i][j] = 0.f;
      }
    }
    if (nv && tx >= 8) {
      ushort4 u0, u1;
      u0.x = f2bf_u(acc[i][0]); u0.y = f2bf_u(acc[i][1]);
      u0.z = f2bf_u(acc[i][2]); u0.w = f2bf_u(acc[i][3]);
      u1.x = f2bf_u(acc[i][4]); u1.y = f2bf_u(acc[i][5]);
      u1.z = f2bf_u(acc[i][6]); u1.w = f2bf_u(acc[i][7]);
      unsigned short* kp = reinterpret_cast<unsigned short*>(KBbf) +
                           ((size_t)n << 6) + (tx - 8) * 8;
      *reinterpret_cast<ushort4*>(kp) = u0;
      *reinterpret_cast<ushort4*>(kp + 4) = u1;
    }
  }
#pragma unroll
  for (int r = 0; r < NREL; ++r) {
    float rk8[8];
    *reinterpret_cast<float4*>(&rk8[0]) =
        *reinterpret_cast<float4*>(&rks[r][(tx & 7) * 8]);
    *reinterpret_cast<float4*>(&rk8[4]) =
        *reinterpret_cast<float4*>(&rks[r][(tx & 7) * 8 + 4]);
#pragma unroll
    for (int i = 0; i < 4; ++i) {
      float pq = 0.f;
#pragma unroll
      for (int j = 0; j < 8; ++j) pq += qv[i][j] * rk8[j];
      pq += __shfl_xor(pq, 1, 64);
      pq += __shfl_xor(pq, 2, 64);
      pq += __shfl_xor(pq, 4, 64);
      pq += __shfl_xor(pq, 8, 64);
      int n = n0 + ty * 4 + i;
      if (tx == r && n < n_nodes) QR[(size_t)n * NREL + r] = pq;
    }
  }
}

__global__ void k2_hist(const int* __restrict__ dst, int* __restrict__ counts, int E) {
  int e = blockIdx.x * blockDim.x + threadIdx.x;
  if (e < E) atomicAdd(&counts[dst[e]], 1);
}

// hierarchical scan: A (per-1024-block exclusive) -> B (block sums) -> C (add)
__global__ void scan_a(const int* __restrict__ counts, int* __restrict__ partial,
                       int* __restrict__ blocksums, int n) {
  __shared__ int wsum[4];
  int tid = threadIdx.x, lane = tid & 63, wv = tid >> 6;
  int base = blockIdx.x * 1024 + tid * 4;
  int4 v = make_int4(0, 0, 0, 0);
  if (base + 3 < n) v = *reinterpret_cast<const int4*>(counts + base);
  else {
    if (base < n) v.x = counts[base];
    if (base + 1 < n) v.y = counts[base + 1];
    if (base + 2 < n) v.z = counts[base + 2];
  }
  int tsum = v.x + v.y + v.z + v.w;
  int s = tsum;
#pragma unroll
  for (int off = 1; off < 64; off <<= 1) {
    int y = __shfl_up(s, off, 64);
    if (lane >= off) s += y;
  }
  if (lane == 63) wsum[wv] = s;
  __syncthreads();
  int woff = 0;
  for (int w = 0; w < wv; ++w) woff += wsum[w];
  int o0 = woff + s - tsum;
  if (base < n) partial[base] = o0;
  if (base + 1 < n) partial[base + 1] = o0 + v.x;
  if (base + 2 < n) partial[base + 2] = o0 + v.x + v.y;
  if (base + 3 < n) partial[base + 3] = o0 + v.x + v.y + v.z;
  if (tid == 255) blocksums[blockIdx.x] = woff + s;
}

__global__ void scan_b(const int* __restrict__ blocksums, int* __restrict__ blockoff,
                       int nb, int* __restrict__ offsets, int n) {
  int lane = threadIdx.x;
  int v = (lane < nb) ? blocksums[lane] : 0;
  int s = v;
#pragma unroll
  for (int off = 1; off < 64; off <<= 1) {
    int y = __shfl_up(s, off, 64);
    if (lane >= off) s += y;
  }
  if (lane < nb) blockoff[lane] = s - v;
  if (lane == 63) offsets[n] = s;
}

__global__ void scan_c(const int* __restrict__ partial, const int* __restrict__ blockoff,
                       int* __restrict__ offsets, int* __restrict__ cursor, int n) {
  int i = blockIdx.x * 256 + threadIdx.x;
  if (i < n) {
    int v = partial[i] + blockoff[i >> 10];
    offsets[i] = v;
    cursor[i] = v;
  }
}

// scatter: permute (src|et<<27) and dst into CSR position order
__global__ void k2_scatter(const int* __restrict__ dst, const int* __restrict__ src,
                           const int* __restrict__ et, int* __restrict__ cursor,
                           int* __restrict__ se_pos, int* __restrict__ dst_pos, int E) {
  int e = blockIdx.x * blockDim.x + threadIdx.x;
  if (e < E) {
    int d = dst[e];
    int p = atomicAdd(&cursor[d], 1);
    se_pos[p] = src[e] | (et[e] << 27);
    dst_pos[p] = d;
  }
}

// K3: edge-parallel scores in CSR position order. 16 lanes per edge;
// packed metadata; bf16 KB gathers; coalesced score store (lanes 0-3).
__global__ void k3_scores(const float* __restrict__ Q,
                          const __hip_bfloat16* __restrict__ KBbf,
                          const float* __restrict__ QR,
                          const int* __restrict__ se_pos,
                          const int* __restrict__ dst_pos,
                          float* __restrict__ scores, int E) {
  int tid = threadIdx.x;
  int lane = tid & 63;
  int li = lane & 15, sub = lane >> 4, wv = tid >> 6;
  int pos_base = blockIdx.x * 16 + wv * 4;
  int pos = pos_base + sub;
  int pc = min(pos, E - 1);
  int se = se_pos[pc];
  int dn = dst_pos[pc];
  int sn = se & SRC_MASK, r = se >> 27;
  float4 q = *reinterpret_cast<const float4*>(Q + (size_t)dn * 64 + li * 4);
  ushort4 u = *reinterpret_cast<const ushort4*>(
      reinterpret_cast<const unsigned short*>(KBbf) + ((size_t)sn << 6) + li * 4);
  float p = q.x * bfu2f(u.x) + q.y * bfu2f(u.y) + q.z * bfu2f(u.z) + q.w * bfu2f(u.w);
#pragma unroll
  for (int off = 1; off < 16; off <<= 1) p += __shfl_xor(p, off, 64);
  float sc = (p + QR[(size_t)dn * NREL + r]) * SCALE;  // valid on all 16 lanes
  float sg = __shfl(sc, (lane & 3) * 16, 64);          // lanes 0-3 pick group scores
  if (lane < 4 && pos_base + lane < E) scores[pos_base + lane] = sg;
}

#define ACC_SWITCH(rr, v)                    \
  switch (rr) {                              \
    case 0: acc[0] += (v); break;            \
    case 1: acc[1] += (v); break;            \
    case 2: acc[2] += (v); break;            \
    case 3: acc[3] += (v); break;            \
    case 4: acc[4] += (v); break;            \
    case 5: acc[5] += (v); break;            \
    case 6: acc[6] += (v); break;            \
    case 7: acc[7] += (v); break;            \
  }

// K4: one wave per node; packed metadata; bf16 x gathers; 4x-unrolled
// readlane broadcast loop (4 gathers in flight).
__global__ void k4_agg(const __hip_bfloat16* __restrict__ xb,
                       const float* __restrict__ scores,
                       const int* __restrict__ offsets,
                       const int* __restrict__ se_pos,
                       __hip_bfloat16* __restrict__ A, int n_nodes) {
  int lane = threadIdx.x & 63, wv = threadIdx.x >> 6;
  int n = blockIdx.x * 4 + wv;
  if (n >= n_nodes) return;
  const unsigned short* xbp = reinterpret_cast<const unsigned short*>(xb);
  int s0 = offsets[n], s1 = offsets[n + 1];
  int deg = s1 - s0;
  float acc[8] = {0.f, 0.f, 0.f, 0.f, 0.f, 0.f, 0.f, 0.f};
  if (deg > 0 && deg <= 64) {
    int p = s0 + lane;
    bool valid = p < s1;
    float sc = valid ? scores[p] : -1e30f;
    int se = valid ? se_pos[p] : 0;
    float m = wave_max64(sc);
    float ex = valid ? __expf(sc - m) : 0.f;
    float t = wave_sum64(ex);
    float wl = ex * (1.0f / t);
    int i = 0;
    for (; i + 4 <= deg; i += 4) {
      float w0 = rdl_f(wl, i), w1 = rdl_f(wl, i + 1);
      float w2 = rdl_f(wl, i + 2), w3 = rdl_f(wl, i + 3);
      int se0 = __builtin_amdgcn_readlane(se, i);
      int se1 = __builtin_amdgcn_readlane(se, i + 1);
      int se2 = __builtin_amdgcn_readlane(se, i + 2);
      int se3 = __builtin_amdgcn_readlane(se, i + 3);
      unsigned short u0 = xbp[((size_t)(se0 & SRC_MASK) << 6) + lane];
      unsigned short u1 = xbp[((size_t)(se1 & SRC_MASK) << 6) + lane];
      unsigned short u2 = xbp[((size_t)(se2 & SRC_MASK) << 6) + lane];
      unsigned short u3 = xbp[((size_t)(se3 & SRC_MASK) << 6) + lane];
      float v0 = w0 * bfu2f(u0);
      float v1 = w1 * bfu2f(u1);
      float v2 = w2 * bfu2f(u2);
      float v3 = w3 * bfu2f(u3);
      int r0 = (unsigned)se0 >> 27, r1 = (unsigned)se1 >> 27;
      int r2 = (unsigned)se2 >> 27, r3 = (unsigned)se3 >> 27;
      ACC_SWITCH(r0, v0)
      ACC_SWITCH(r1, v1)
      ACC_SWITCH(r2, v2)
      ACC_SWITCH(r3, v3)
    }
    for (; i < deg; ++i) {
      float wgt = rdl_f(wl, i);
      int sei = __builtin_amdgcn_readlane(se, i);
      float v = wgt * bfu2f(xbp[((size_t)(sei & SRC_MASK) << 6) + lane]);
      int rr = (unsigned)sei >> 27;
      ACC_SWITCH(rr, v)
    }
  } else if (deg > 64) {
    float m = -1e30f;
    for (int c = s0; c < s1; c += 64) {
      int p = c + lane;
      float s = (p < s1) ? scores[p] : -1e30f;
      m = fmaxf(m, s);
    }
    m = wave_max64(m);
    float t = 0.f;
    for (int c = s0; c < s1; c += 64) {
      int p = c + lane;
      t += (p < s1) ? __expf(scores[p] - m) : 0.f;
    }
    t = wave_sum64(t);
    float inv = 1.0f / t;
    for (int c = s0; c < s1; c += 64) {
      int p = c + lane;
      bool valid = p < s1;
      int se = valid ? se_pos[p] : 0;
      float wl = valid ? __expf(scores[p] - m) * inv : 0.f;
      int cnt = min(64, s1 - c);
      for (int i = 0; i < cnt; ++i) {
        float wgt = rdl_f(wl, i);
        int sei = __builtin_amdgcn_readlane(se, i);
        float v = wgt * bfu2f(xbp[((size_t)(sei & SRC_MASK) << 6) + lane]);
        int rr = (unsigned)sei >> 27;
        ACC_SWITCH(rr, v)
      }
    }
  }
#pragma unroll
  for (int r = 0; r < 8; ++r)
    A[(size_t)n * 512 + r * 64 + lane] = __float2bfloat16(acc[r]);
}

// K5: out = relu(LN(A(50000x512 bf16) @ (Whi+Wlo) + bias)) via MFMA, LDS-free.
__global__ void __launch_bounds__(256) k5_mfma_ln(
    const __hip_bfloat16* __restrict__ A,
    const __hip_bfloat16* __restrict__ Whi,
    const __hip_bfloat16* __restrict__ Wlo,
    const float* __restrict__ bias,
    const float* __restrict__ ln_g, const float* __restrict__ ln_b,
    float* __restrict__ out, int n_nodes) {
  int tid = threadIdx.x;
  int lane = tid & 63, w = tid >> 6;
  int li = lane & 15, gr = lane >> 4;
  int n0 = blockIdx.x * 64;
  int arow_n = n0 + w * 16 + li;
  bool rvalid = arow_n < n_nodes;
  const __hip_bfloat16* arow = A + (size_t)arow_n * 512 + gr * 8;
  const bf16x8v* wh = reinterpret_cast<const bf16x8v*>(Whi);
  const bf16x8v* wl = reinterpret_cast<const bf16x8v*>(Wlo);
  f32x4v acc[4];
#pragma unroll
  for (int ct = 0; ct < 4; ++ct) acc[ct] = (f32x4v){0.f, 0.f, 0.f, 0.f};
  for (int ks = 0; ks < 16; ++ks) {
    uint4 au = make_uint4(0u, 0u, 0u, 0u);
    if (rvalid) au = *reinterpret_cast<const uint4*>(arow + ks * 32);
    bf16x8v a = __builtin_bit_cast(bf16x8v, au);
#pragma unroll
    for (int ct = 0; ct < 4; ++ct) {
      bf16x8v bh = wh[(ct * 16 + ks) * 64 + lane];
      bf16x8v bl = wl[(ct * 16 + ks) * 64 + lane];
      acc[ct] = __builtin_amdgcn_mfma_f32_16x16x32_bf16(a, bh, acc[ct], 0, 0, 0);
      acc[ct] = __builtin_amdgcn_mfma_f32_16x16x32_bf16(a, bl, acc[ct], 0, 0, 0);
    }
  }
  float bi[4], g[4], bb[4];
#pragma unroll
  for (int ct = 0; ct < 4; ++ct) {
    int col = ct * 16 + li;
    bi[ct] = bias[col];
    g[ct] = ln_g[col];
    bb[ct] = ln_b[col];
  }
#pragma unroll
  for (int reg = 0; reg < 4; ++reg) {
    float v[4];
#pragma unroll
    for (int ct = 0; ct < 4; ++ct) v[ct] = acc[ct][reg] + bi[ct];
    float s = v[0] + v[1] + v[2] + v[3];
    s += __shfl_xor(s, 1, 64);
    s += __shfl_xor(s, 2, 64);
    s += __shfl_xor(s, 4, 64);
    s += __shfl_xor(s, 8, 64);
    float mu = s * (1.0f / 64.0f);
    float sq = 0.f;
#pragma unroll
    for (int ct = 0; ct < 4; ++ct) {
      float d = v[ct] - mu;
      sq += d * d;
    }
    sq += __shfl_xor(sq, 1, 64);
    sq += __shfl_xor(sq, 2, 64);
    sq += __shfl_xor(sq, 4, 64);
    sq += __shfl_xor(sq, 8, 64);
    float inv = rsqrtf(sq * (1.0f / 64.0f) + LN_EPS);
    int n = n0 + w * 16 + gr * 4 + reg;
    if (n < n_nodes) {
#pragma unroll
      for (int ct = 0; ct < 4; ++ct) {
        float y = (v[ct] - mu) * inv * g[ct] + bb[ct];
        out[(size_t)n * 64 + ct * 16 + li] = fmaxf(y, 0.f);
      }
    }
  }
}

extern "C" void kernel_launch(void* const* d_in, const int* in_sizes, int n_in,
                              void* d_out, int out_size, void* d_ws, size_t ws_size,
                              hipStream_t stream) {
  (void)n_in; (void)out_size; (void)ws_size;
  const float* x = (const float*)d_in[0];
  const int* ei = (const int*)d_in[1];
  const int* et = (const int*)d_in[2];
  const float* W_r = (const float*)d_in[4];
  const float* Wq_w = (const float*)d_in[5];
  const float* Wq_b = (const float*)d_in[6];
  const float* Wk_w = (const float*)d_in[7];
  const float* bias = (const float*)d_in[10];
  const float* ln_g = (const float*)d_in[11];
  const float* ln_b = (const float*)d_in[12];

  int N = in_sizes[0] / NDIM;
  int E = in_sizes[2];
  const int* srcp = ei;
  const int* dstp = ei + E;

  char* p = (char*)d_ws;
  auto alloc = [&](size_t bytes) {
    void* r = (void*)p;
    p += (bytes + 255) & ~(size_t)255;
    return r;
  };
  float* Q = (float*)alloc((size_t)N * NDIM * 4);
  __hip_bfloat16* KBbf = (__hip_bfloat16*)alloc((size_t)N * NDIM * 2);
  float* QR = (float*)alloc((size_t)N * NREL * 4);
  float* relkey = (float*)alloc(NREL * NDIM * 4);
  __hip_bfloat16* xbf = (__hip_bfloat16*)alloc((size_t)N * NDIM * 2);
  int* counts = (int*)alloc((size_t)N * 4);
  int* partial = (int*)alloc((size_t)N * 4);
  int* offsets = (int*)alloc((size_t)(N + 1) * 4);
  int* cursor = (int*)alloc((size_t)N * 4);
  int* blocksums = (int*)alloc(64 * 4);
  int* blockoff = (int*)alloc(64 * 4);
  int* se_pos = (int*)alloc((size_t)E * 4);
  int* dst_pos = (int*)alloc((size_t)E * 4);
  float* scores = (float*)alloc((size_t)E * 4);
  __hip_bfloat16* A = (__hip_bfloat16*)alloc((size_t)N * (NREL * NDIM) * 2);
  __hip_bfloat16* Whi = (__hip_bfloat16*)alloc(4 * 16 * 64 * 8 * 2);
  __hip_bfloat16* Wlo = (__hip_bfloat16*)alloc(4 * 16 * 64 * 8 * 2);

  int nscan = (N + 1023) / 1024;

  hipMemsetAsync(counts, 0, (size_t)N * 4, stream);
  k0_relkey<<<1, 256, 0, stream>>>(W_r, Wk_w, relkey);
  k0b_packw<<<(4 * 16 * 64 * 8 + 255) / 256, 256, 0, stream>>>(W_r, Whi, Wlo);
  k1c_xbf<<<1024, 256, 0, stream>>>(x, xbf, N * NDIM / 4);
  k1_qkb<<<(N + 63) / 64, 256, 0, stream>>>(x, Wq_w, Wq_b, Wk_w, relkey, Q, KBbf, QR, N);
  k2_hist<<<(E + 255) / 256, 256, 0, stream>>>(dstp, counts, E);
  scan_a<<<nscan, 256, 0, stream>>>(counts, partial, blocksums, N);
  scan_b<<<1, 64, 0, stream>>>(blocksums, blockoff, nscan, offsets, N);
  scan_c<<<(N + 255) / 256, 256, 0, stream>>>(partial, blockoff, offsets, cursor, N);
  k2_scatter<<<(E + 255) / 256, 256, 0, stream>>>(dstp, srcp, et, cursor, se_pos,
                                                  dst_pos, E);
  k3_scores<<<(E + 15) / 16, 256, 0, stream>>>(Q, KBbf, QR, se_pos, dst_pos, scores, E);
  k4_agg<<<(N + 3) / 4, 256, 0, stream>>>(xbf, scores, offsets, se_pos, A, N);
  k5_mfma_ln<<<(N + 63) / 64, 256, 0, stream>>>(A, Whi, Wlo, bias, ln_g, ln_b,
                                                (float*)d_out, N);
}

// Round 12
// 299.965 us; speedup vs baseline: 3.0687x; 1.1507x over previous
//
#include <hip/hip_runtime.h>
#include <hip/hip_bf16.h>

#define NDIM 64
#define NREL 8
#define SCALE 0.125f
#define LN_EPS 1e-5f
#define SRC_MASK 0x07FFFFFF

typedef __bf16 bf16x8v __attribute__((ext_vector_type(8)));
typedef float f32x4v __attribute__((ext_vector_type(4)));

__device__ __forceinline__ float wave_sum64(float v) {
#pragma unroll
  for (int off = 32; off > 0; off >>= 1) v += __shfl_xor(v, off, 64);
  return v;
}
__device__ __forceinline__ float wave_max64(float v) {
#pragma unroll
  for (int off = 32; off > 0; off >>= 1) v = fmaxf(v, __shfl_xor(v, off, 64));
  return v;
}
__device__ __forceinline__ unsigned short f2bf_u(float f) {
  __hip_bfloat16 h = __float2bfloat16(f);
  return *reinterpret_cast<unsigned short*>(&h);
}
__device__ __forceinline__ float bfu2f(unsigned short u) {
  return __uint_as_float(((unsigned)u) << 16);
}
__device__ __forceinline__ float rdl_f(float v, int i) {
  return __int_as_float(__builtin_amdgcn_readlane(__float_as_int(v), i));
}

// K0 fused: blocks 0..127 pack W_r into MFMA B-fragment order (hi/lo bf16);
// last block computes relkey[r][o] = mean_last(W_r[r]) @ Wk2.
__global__ void k0_fused(const float* __restrict__ W_r,
                         const float* __restrict__ Wk_w,
                         __hip_bfloat16* __restrict__ Whi,
                         __hip_bfloat16* __restrict__ Wlo,
                         float* __restrict__ relkey) {
  int tid = threadIdx.x;
  if (blockIdx.x < 128) {
    int idx = blockIdx.x * 256 + tid;
    int j = idx & 7;
    int l = (idx >> 3) & 63;
    int ks = (idx >> 9) & 15;
    int ct = idx >> 13;
    int k = ks * 32 + (l >> 4) * 8 + j;
    int col = ct * 16 + (l & 15);
    float v = W_r[(size_t)k * 64 + col];
    __hip_bfloat16 h = __float2bfloat16(v);
    Whi[idx] = h;
    Wlo[idx] = __float2bfloat16(v - __bfloat162float(h));
    return;
  }
  __shared__ float relemb[NREL * NDIM];
  for (int idx = tid; idx < NREL * NDIM; idx += 256) {
    int r = idx >> 6, i = idx & 63;
    const float* wr = W_r + (size_t)(r * NDIM + i) * NDIM;
    float s = 0.f;
#pragma unroll
    for (int o = 0; o < NDIM; ++o) s += wr[o];
    relemb[idx] = s * (1.0f / NDIM);
  }
  __syncthreads();
  for (int idx = tid; idx < NREL * NDIM; idx += 256) {
    int r = idx >> 6, o = idx & 63;
    float s = 0.f;
#pragma unroll
    for (int i = 0; i < NDIM; ++i) s += relemb[r * NDIM + i] * Wk_w[(NDIM + i) * NDIM + o];
    relkey[idx] = s;
  }
}

// K1c: xbf = bf16(x), vectorized grid-stride copy.
__global__ void k1c_xbf(const float* __restrict__ x, __hip_bfloat16* __restrict__ xbf,
                        int total4) {
  int i = blockIdx.x * blockDim.x + threadIdx.x;
  int stride = gridDim.x * blockDim.x;
  for (; i < total4; i += stride) {
    float4 v = *reinterpret_cast<const float4*>(x + (size_t)i * 4);
    ushort4 u;
    u.x = f2bf_u(v.x); u.y = f2bf_u(v.y); u.z = f2bf_u(v.z); u.w = f2bf_u(v.w);
    *reinterpret_cast<ushort4*>(reinterpret_cast<unsigned short*>(xbf) +
                                (size_t)i * 4) = u;
  }
}

// K1: Q(fp32) = x@Wq + bq; KBbf(bf16) = x@Wk1; fused QR[n][r] = Q[n].relkey[r].
__global__ void k1_qkb(const float* __restrict__ x,
                       const float* __restrict__ Wq_w,
                       const float* __restrict__ Wq_bias,
                       const float* __restrict__ Wk_w,
                       const float* __restrict__ relkey,
                       float* __restrict__ Q, __hip_bfloat16* __restrict__ KBbf,
                       float* __restrict__ QR, int n_nodes) {
  __shared__ float xs[64][68];
  __shared__ float ws[64][128];
  __shared__ float rks[NREL][NDIM];
  int tid = threadIdx.x;
  int n0 = blockIdx.x * 64;
  for (int idx = tid; idx < 64 * 128; idx += 256) {
    int r = idx >> 7, c = idx & 127;
    ws[r][c] = (c < 64) ? Wq_w[r * 64 + c] : Wk_w[r * 64 + (c - 64)];
  }
  for (int idx = tid; idx < NREL * NDIM; idx += 256)
    rks[idx >> 6][idx & 63] = relkey[idx];
  for (int idx = tid; idx < 64 * 16; idx += 256) {
    int r = idx >> 4, c4 = (idx & 15) * 4;
    int n = n0 + r;
    float4 v = make_float4(0.f, 0.f, 0.f, 0.f);
    if (n < n_nodes) v = *reinterpret_cast<const float4*>(x + (size_t)n * 64 + c4);
    *reinterpret_cast<float4*>(&xs[r][c4]) = v;
  }
  __syncthreads();
  int tx = tid & 15, ty = tid >> 4;
  float acc[4][8] = {};
  for (int k = 0; k < 64; k += 4) {
    float4 a[4];
#pragma unroll
    for (int i = 0; i < 4; ++i) a[i] = *reinterpret_cast<float4*>(&xs[ty * 4 + i][k]);
#pragma unroll
    for (int kk = 0; kk < 4; ++kk) {
      float4 w0 = *reinterpret_cast<float4*>(&ws[k + kk][tx * 8]);
      float4 w1 = *reinterpret_cast<float4*>(&ws[k + kk][tx * 8 + 4]);
#pragma unroll
      for (int i = 0; i < 4; ++i) {
        float av = (kk == 0) ? a[i].x : (kk == 1) ? a[i].y : (kk == 2) ? a[i].z : a[i].w;
        acc[i][0] += av * w0.x; acc[i][1] += av * w0.y;
        acc[i][2] += av * w0.z; acc[i][3] += av * w0.w;
        acc[i][4] += av * w1.x; acc[i][5] += av * w1.y;
        acc[i][6] += av * w1.z; acc[i][7] += av * w1.w;
      }
    }
  }
  float qv[4][8];
#pragma unroll
  for (int i = 0; i < 4; ++i) {
    int n = n0 + ty * 4 + i;
    bool nv = n < n_nodes;
#pragma unroll
    for (int j = 0; j < 8; ++j) {
      int c = tx * 8 + j;
      if (c < 64) {
        qv[i][j] = acc[i][j] + Wq_bias[c];
        if (nv) Q[(size_t)n * 64 + c] = qv[i][j];
      } else {
        qv[i][j] = 0.f;
      }
    }
    if (nv && tx >= 8) {
      ushort4 u0, u1;
      u0.x = f2bf_u(acc[i][0]); u0.y = f2bf_u(acc[i][1]);
      u0.z = f2bf_u(acc[i][2]); u0.w = f2bf_u(acc[i][3]);
      u1.x = f2bf_u(acc[i][4]); u1.y = f2bf_u(acc[i][5]);
      u1.z = f2bf_u(acc[i][6]); u1.w = f2bf_u(acc[i][7]);
      unsigned short* kp = reinterpret_cast<unsigned short*>(KBbf) +
                           ((size_t)n << 6) + (tx - 8) * 8;
      *reinterpret_cast<ushort4*>(kp) = u0;
      *reinterpret_cast<ushort4*>(kp + 4) = u1;
    }
  }
#pragma unroll
  for (int r = 0; r < NREL; ++r) {
    float rk8[8];
    *reinterpret_cast<float4*>(&rk8[0]) =
        *reinterpret_cast<float4*>(&rks[r][(tx & 7) * 8]);
    *reinterpret_cast<float4*>(&rk8[4]) =
        *reinterpret_cast<float4*>(&rks[r][(tx & 7) * 8 + 4]);
#pragma unroll
    for (int i = 0; i < 4; ++i) {
      float pq = 0.f;
#pragma unroll
      for (int j = 0; j < 8; ++j) pq += qv[i][j] * rk8[j];
      pq += __shfl_xor(pq, 1, 64);
      pq += __shfl_xor(pq, 2, 64);
      pq += __shfl_xor(pq, 4, 64);
      pq += __shfl_xor(pq, 8, 64);
      int n = n0 + ty * 4 + i;
      if (tx == r && n < n_nodes) QR[(size_t)n * NREL + r] = pq;
    }
  }
}

// hist with rank output: rank[e] = arrival index of e within its dst bucket.
__global__ void k2_hist(const int* __restrict__ dst, int* __restrict__ counts,
                        int* __restrict__ rank, int E) {
  int e = blockIdx.x * blockDim.x + threadIdx.x;
  if (e < E) rank[e] = atomicAdd(&counts[dst[e]], 1);
}

// hierarchical scan: A (per-1024-block exclusive) -> B (block sums) -> C (add)
__global__ void scan_a(const int* __restrict__ counts, int* __restrict__ partial,
                       int* __restrict__ blocksums, int n) {
  __shared__ int wsum[4];
  int tid = threadIdx.x, lane = tid & 63, wv = tid >> 6;
  int base = blockIdx.x * 1024 + tid * 4;
  int4 v = make_int4(0, 0, 0, 0);
  if (base + 3 < n) v = *reinterpret_cast<const int4*>(counts + base);
  else {
    if (base < n) v.x = counts[base];
    if (base + 1 < n) v.y = counts[base + 1];
    if (base + 2 < n) v.z = counts[base + 2];
  }
  int tsum = v.x + v.y + v.z + v.w;
  int s = tsum;
#pragma unroll
  for (int off = 1; off < 64; off <<= 1) {
    int y = __shfl_up(s, off, 64);
    if (lane >= off) s += y;
  }
  if (lane == 63) wsum[wv] = s;
  __syncthreads();
  int woff = 0;
  for (int w = 0; w < wv; ++w) woff += wsum[w];
  int o0 = woff + s - tsum;
  if (base < n) partial[base] = o0;
  if (base + 1 < n) partial[base + 1] = o0 + v.x;
  if (base + 2 < n) partial[base + 2] = o0 + v.x + v.y;
  if (base + 3 < n) partial[base + 3] = o0 + v.x + v.y + v.z;
  if (tid == 255) blocksums[blockIdx.x] = woff + s;
}

__global__ void scan_b(const int* __restrict__ blocksums, int* __restrict__ blockoff,
                       int nb, int* __restrict__ offsets, int n) {
  int lane = threadIdx.x;
  int v = (lane < nb) ? blocksums[lane] : 0;
  int s = v;
#pragma unroll
  for (int off = 1; off < 64; off <<= 1) {
    int y = __shfl_up(s, off, 64);
    if (lane >= off) s += y;
  }
  if (lane < nb) blockoff[lane] = s - v;
  if (lane == 63) offsets[n] = s;
}

__global__ void scan_c(const int* __restrict__ partial, const int* __restrict__ blockoff,
                       int* __restrict__ offsets, int n) {
  int i = blockIdx.x * 256 + threadIdx.x;
  if (i < n) offsets[i] = partial[i] + blockoff[i >> 10];
}

// scatter: atomic-free. p = offsets[dst] + rank; one 8B store {src|et<<27, dst}.
__global__ void k2_scatter(const int* __restrict__ dst, const int* __restrict__ src,
                           const int* __restrict__ et, const int* __restrict__ rank,
                           const int* __restrict__ offsets,
                           int2* __restrict__ ed2, int E) {
  int e = blockIdx.x * blockDim.x + threadIdx.x;
  if (e < E) {
    int d = dst[e];
    int p = offsets[d] + rank[e];
    ed2[p] = make_int2(src[e] | (et[e] << 27), d);
  }
}

// K3: edge-parallel scores in CSR position order. 16 lanes per edge;
// packed int2 metadata; bf16 KB gathers; coalesced score store (lanes 0-3).
__global__ void k3_scores(const float* __restrict__ Q,
                          const __hip_bfloat16* __restrict__ KBbf,
                          const float* __restrict__ QR,
                          const int2* __restrict__ ed2,
                          float* __restrict__ scores, int E) {
  int tid = threadIdx.x;
  int lane = tid & 63;
  int li = lane & 15, sub = lane >> 4, wv = tid >> 6;
  int pos_base = blockIdx.x * 16 + wv * 4;
  int pos = pos_base + sub;
  int pc = min(pos, E - 1);
  int2 ed = ed2[pc];
  int sn = ed.x & SRC_MASK, r = (unsigned)ed.x >> 27;
  int dn = ed.y;
  float4 q = *reinterpret_cast<const float4*>(Q + (size_t)dn * 64 + li * 4);
  ushort4 u = *reinterpret_cast<const ushort4*>(
      reinterpret_cast<const unsigned short*>(KBbf) + ((size_t)sn << 6) + li * 4);
  float p = q.x * bfu2f(u.x) + q.y * bfu2f(u.y) + q.z * bfu2f(u.z) + q.w * bfu2f(u.w);
#pragma unroll
  for (int off = 1; off < 16; off <<= 1) p += __shfl_xor(p, off, 64);
  float sc = (p + QR[(size_t)dn * NREL + r]) * SCALE;
  float sg = __shfl(sc, (lane & 3) * 16, 64);
  if (lane < 4 && pos_base + lane < E) scores[pos_base + lane] = sg;
}

#define ACC_SWITCH(rr, v)                    \
  switch (rr) {                              \
    case 0: acc[0] += (v); break;            \
    case 1: acc[1] += (v); break;            \
    case 2: acc[2] += (v); break;            \
    case 3: acc[3] += (v); break;            \
    case 4: acc[4] += (v); break;            \
    case 5: acc[5] += (v); break;            \
    case 6: acc[6] += (v); break;            \
    case 7: acc[7] += (v); break;            \
  }

// K4: one wave per node; packed metadata; bf16 x gathers; 4x-unrolled
// readlane broadcast loop (4 gathers in flight).
__global__ void k4_agg(const __hip_bfloat16* __restrict__ xb,
                       const float* __restrict__ scores,
                       const int* __restrict__ offsets,
                       const int2* __restrict__ ed2,
                       __hip_bfloat16* __restrict__ A, int n_nodes) {
  int lane = threadIdx.x & 63, wv = threadIdx.x >> 6;
  int n = blockIdx.x * 4 + wv;
  if (n >= n_nodes) return;
  const unsigned short* xbp = reinterpret_cast<const unsigned short*>(xb);
  int s0 = offsets[n], s1 = offsets[n + 1];
  int deg = s1 - s0;
  float acc[8] = {0.f, 0.f, 0.f, 0.f, 0.f, 0.f, 0.f, 0.f};
  if (deg > 0 && deg <= 64) {
    int p = s0 + lane;
    bool valid = p < s1;
    float sc = valid ? scores[p] : -1e30f;
    int se = valid ? ed2[p].x : 0;
    float m = wave_max64(sc);
    float ex = valid ? __expf(sc - m) : 0.f;
    float t = wave_sum64(ex);
    float wl = ex * (1.0f / t);
    int i = 0;
    for (; i + 4 <= deg; i += 4) {
      float w0 = rdl_f(wl, i), w1 = rdl_f(wl, i + 1);
      float w2 = rdl_f(wl, i + 2), w3 = rdl_f(wl, i + 3);
      int se0 = __builtin_amdgcn_readlane(se, i);
      int se1 = __builtin_amdgcn_readlane(se, i + 1);
      int se2 = __builtin_amdgcn_readlane(se, i + 2);
      int se3 = __builtin_amdgcn_readlane(se, i + 3);
      unsigned short u0 = xbp[((size_t)(se0 & SRC_MASK) << 6) + lane];
      unsigned short u1 = xbp[((size_t)(se1 & SRC_MASK) << 6) + lane];
      unsigned short u2 = xbp[((size_t)(se2 & SRC_MASK) << 6) + lane];
      unsigned short u3 = xbp[((size_t)(se3 & SRC_MASK) << 6) + lane];
      float v0 = w0 * bfu2f(u0);
      float v1 = w1 * bfu2f(u1);
      float v2 = w2 * bfu2f(u2);
      float v3 = w3 * bfu2f(u3);
      int r0 = (unsigned)se0 >> 27, r1 = (unsigned)se1 >> 27;
      int r2 = (unsigned)se2 >> 27, r3 = (unsigned)se3 >> 27;
      ACC_SWITCH(r0, v0)
      ACC_SWITCH(r1, v1)
      ACC_SWITCH(r2, v2)
      ACC_SWITCH(r3, v3)
    }
    for (; i < deg; ++i) {
      float wgt = rdl_f(wl, i);
      int sei = __builtin_amdgcn_readlane(se, i);
      float v = wgt * bfu2f(xbp[((size_t)(sei & SRC_MASK) << 6) + lane]);
      int rr = (unsigned)sei >> 27;
      ACC_SWITCH(rr, v)
    }
  } else if (deg > 64) {
    float m = -1e30f;
    for (int c = s0; c < s1; c += 64) {
      int p = c + lane;
      float s = (p < s1) ? scores[p] : -1e30f;
      m = fmaxf(m, s);
    }
    m = wave_max64(m);
    float t = 0.f;
    for (int c = s0; c < s1; c += 64) {
      int p = c + lane;
      t += (p < s1) ? __expf(scores[p] - m) : 0.f;
    }
    t = wave_sum64(t);
    float inv = 1.0f / t;
    for (int c = s0; c < s1; c += 64) {
      int p = c + lane;
      bool valid = p < s1;
      int se = valid ? ed2[p].x : 0;
      float wl = valid ? __expf(scores[p] - m) * inv : 0.f;
      int cnt = min(64, s1 - c);
      for (int i = 0; i < cnt; ++i) {
        float wgt = rdl_f(wl, i);
        int sei = __builtin_amdgcn_readlane(se, i);
        float v = wgt * bfu2f(xbp[((size_t)(sei & SRC_MASK) << 6) + lane]);
        int rr = (unsigned)sei >> 27;
        ACC_SWITCH(rr, v)
      }
    }
  }
#pragma unroll
  for (int r = 0; r < 8; ++r)
    A[(size_t)n * 512 + r * 64 + lane] = __float2bfloat16(acc[r]);
}

// K5: out = relu(LN(A(50000x512 bf16) @ (Whi+Wlo) + bias)) via MFMA, LDS-free.
__global__ void __launch_bounds__(256) k5_mfma_ln(
    const __hip_bfloat16* __restrict__ A,
    const __hip_bfloat16* __restrict__ Whi,
    const __hip_bfloat16* __restrict__ Wlo,
    const float* __restrict__ bias,
    const float* __restrict__ ln_g, const float* __restrict__ ln_b,
    float* __restrict__ out, int n_nodes) {
  int tid = threadIdx.x;
  int lane = tid & 63, w = tid >> 6;
  int li = lane & 15, gr = lane >> 4;
  int n0 = blockIdx.x * 64;
  int arow_n = n0 + w * 16 + li;
  bool rvalid = arow_n < n_nodes;
  const __hip_bfloat16* arow = A + (size_t)arow_n * 512 + gr * 8;
  const bf16x8v* wh = reinterpret_cast<const bf16x8v*>(Whi);
  const bf16x8v* wl = reinterpret_cast<const bf16x8v*>(Wlo);
  f32x4v acc[4];
#pragma unroll
  for (int ct = 0; ct < 4; ++ct) acc[ct] = (f32x4v){0.f, 0.f, 0.f, 0.f};
  for (int ks = 0; ks < 16; ++ks) {
    uint4 au = make_uint4(0u, 0u, 0u, 0u);
    if (rvalid) au = *reinterpret_cast<const uint4*>(arow + ks * 32);
    bf16x8v a = __builtin_bit_cast(bf16x8v, au);
#pragma unroll
    for (int ct = 0; ct < 4; ++ct) {
      bf16x8v bh = wh[(ct * 16 + ks) * 64 + lane];
      bf16x8v bl = wl[(ct * 16 + ks) * 64 + lane];
      acc[ct] = __builtin_amdgcn_mfma_f32_16x16x32_bf16(a, bh, acc[ct], 0, 0, 0);
      acc[ct] = __builtin_amdgcn_mfma_f32_16x16x32_bf16(a, bl, acc[ct], 0, 0, 0);
    }
  }
  float bi[4], g[4], bb[4];
#pragma unroll
  for (int ct = 0; ct < 4; ++ct) {
    int col = ct * 16 + li;
    bi[ct] = bias[col];
    g[ct] = ln_g[col];
    bb[ct] = ln_b[col];
  }
#pragma unroll
  for (int reg = 0; reg < 4; ++reg) {
    float v[4];
#pragma unroll
    for (int ct = 0; ct < 4; ++ct) v[ct] = acc[ct][reg] + bi[ct];
    float s = v[0] + v[1] + v[2] + v[3];
    s += __shfl_xor(s, 1, 64);
    s += __shfl_xor(s, 2, 64);
    s += __shfl_xor(s, 4, 64);
    s += __shfl_xor(s, 8, 64);
    float mu = s * (1.0f / 64.0f);
    float sq = 0.f;
#pragma unroll
    for (int ct = 0; ct < 4; ++ct) {
      float d = v[ct] - mu;
      sq += d * d;
    }
    sq += __shfl_xor(sq, 1, 64);
    sq += __shfl_xor(sq, 2, 64);
    sq += __shfl_xor(sq, 4, 64);
    sq += __shfl_xor(sq, 8, 64);
    float inv = rsqrtf(sq * (1.0f / 64.0f) + LN_EPS);
    int n = n0 + w * 16 + gr * 4 + reg;
    if (n < n_nodes) {
#pragma unroll
      for (int ct = 0; ct < 4; ++ct) {
        float y = (v[ct] - mu) * inv * g[ct] + bb[ct];
        out[(size_t)n * 64 + ct * 16 + li] = fmaxf(y, 0.f);
      }
    }
  }
}

extern "C" void kernel_launch(void* const* d_in, const int* in_sizes, int n_in,
                              void* d_out, int out_size, void* d_ws, size_t ws_size,
                              hipStream_t stream) {
  (void)n_in; (void)out_size; (void)ws_size;
  const float* x = (const float*)d_in[0];
  const int* ei = (const int*)d_in[1];
  const int* et = (const int*)d_in[2];
  const float* W_r = (const float*)d_in[4];
  const float* Wq_w = (const float*)d_in[5];
  const float* Wq_b = (const float*)d_in[6];
  const float* Wk_w = (const float*)d_in[7];
  const float* bias = (const float*)d_in[10];
  const float* ln_g = (const float*)d_in[11];
  const float* ln_b = (const float*)d_in[12];

  int N = in_sizes[0] / NDIM;
  int E = in_sizes[2];
  const int* srcp = ei;
  const int* dstp = ei + E;

  char* p = (char*)d_ws;
  auto alloc = [&](size_t bytes) {
    void* r = (void*)p;
    p += (bytes + 255) & ~(size_t)255;
    return r;
  };
  float* Q = (float*)alloc((size_t)N * NDIM * 4);
  __hip_bfloat16* KBbf = (__hip_bfloat16*)alloc((size_t)N * NDIM * 2);
  float* QR = (float*)alloc((size_t)N * NREL * 4);
  float* relkey = (float*)alloc(NREL * NDIM * 4);
  __hip_bfloat16* xbf = (__hip_bfloat16*)alloc((size_t)N * NDIM * 2);
  int* counts = (int*)alloc((size_t)N * 4);
  int* partial = (int*)alloc((size_t)N * 4);
  int* offsets = (int*)alloc((size_t)(N + 1) * 4);
  int* rank = (int*)alloc((size_t)E * 4);
  int* blocksums = (int*)alloc(64 * 4);
  int* blockoff = (int*)alloc(64 * 4);
  int2* ed2 = (int2*)alloc((size_t)E * 8);
  float* scores = (float*)alloc((size_t)E * 4);
  __hip_bfloat16* A = (__hip_bfloat16*)alloc((size_t)N * (NREL * NDIM) * 2);
  __hip_bfloat16* Whi = (__hip_bfloat16*)alloc(4 * 16 * 64 * 8 * 2);
  __hip_bfloat16* Wlo = (__hip_bfloat16*)alloc(4 * 16 * 64 * 8 * 2);

  int nscan = (N + 1023) / 1024;

  hipMemsetAsync(counts, 0, (size_t)N * 4, stream);
  k0_fused<<<129, 256, 0, stream>>>(W_r, Wk_w, Whi, Wlo, relkey);
  k1c_xbf<<<1024, 256, 0, stream>>>(x, xbf, N * NDIM / 4);
  k1_qkb<<<(N + 63) / 64, 256, 0, stream>>>(x, Wq_w, Wq_b, Wk_w, relkey, Q, KBbf, QR, N);
  k2_hist<<<(E + 255) / 256, 256, 0, stream>>>(dstp, counts, rank, E);
  scan_a<<<nscan, 256, 0, stream>>>(counts, partial, blocksums, N);
  scan_b<<<1, 64, 0, stream>>>(blocksums, blockoff, nscan, offsets, N);
  scan_c<<<(N + 255) / 256, 256, 0, stream>>>(partial, blockoff, offsets, N);
  k2_scatter<<<(E + 255) / 256, 256, 0, stream>>>(dstp, srcp, et, rank, offsets, ed2, E);
  k3_scores<<<(E + 15) / 16, 256, 0, stream>>>(Q, KBbf, QR, ed2, scores, E);
  k4_agg<<<(N + 3) / 4, 256, 0, stream>>>(xbf, scores, offsets, ed2, A, N);
  k5_mfma_ln<<<(N + 63) / 64, 256, 0, stream>>>(A, Whi, Wlo, bias, ln_g, ln_b,
                                                (float*)d_out, N);
}

// Round 13
// 272.776 us; speedup vs baseline: 3.3746x; 1.0997x over previous
//
#include <hip/hip_runtime.h>
#include <hip/hip_bf16.h>

#define NDIM 64
#define NREL 8
#define SCALE 0.125f
#define LN_EPS 1e-5f
#define SRC_MASK 0x07FFFFFF

typedef __bf16 bf16x8v __attribute__((ext_vector_type(8)));
typedef float f32x4v __attribute__((ext_vector_type(4)));

__device__ __forceinline__ float wave_sum64(float v) {
#pragma unroll
  for (int off = 32; off > 0; off >>= 1) v += __shfl_xor(v, off, 64);
  return v;
}
__device__ __forceinline__ float wave_max64(float v) {
#pragma unroll
  for (int off = 32; off > 0; off >>= 1) v = fmaxf(v, __shfl_xor(v, off, 64));
  return v;
}
__device__ __forceinline__ unsigned short f2bf_u(float f) {
  __hip_bfloat16 h = __float2bfloat16(f);
  return *reinterpret_cast<unsigned short*>(&h);
}
__device__ __forceinline__ float bfu2f(unsigned short u) {
  return __uint_as_float(((unsigned)u) << 16);
}
__device__ __forceinline__ float rdl_f(float v, int i) {
  return __int_as_float(__builtin_amdgcn_readlane(__float_as_int(v), i));
}

// K0 fused:
//  blocks 0..127  : pack W_r (512x64) into MFMA B-frags, hi/lo bf16
//  blocks 128..159: pack [Wq|Wk1] (64x128) into MFMA B-frags, hi/lo bf16
//  block 160      : relkey[r][o] = mean_last(W_r[r]) @ Wk2
__global__ void k0_fused(const float* __restrict__ W_r,
                         const float* __restrict__ Wq_w,
                         const float* __restrict__ Wk_w,
                         __hip_bfloat16* __restrict__ Whi,
                         __hip_bfloat16* __restrict__ Wlo,
                         __hip_bfloat16* __restrict__ Wqhi,
                         __hip_bfloat16* __restrict__ Wqlo,
                         float* __restrict__ relkey) {
  int tid = threadIdx.x;
  int b = blockIdx.x;
  if (b < 128) {
    int idx = b * 256 + tid;
    int j = idx & 7;
    int l = (idx >> 3) & 63;
    int ks = (idx >> 9) & 15;
    int ct = idx >> 13;
    int k = ks * 32 + (l >> 4) * 8 + j;
    int col = ct * 16 + (l & 15);
    float v = W_r[(size_t)k * 64 + col];
    __hip_bfloat16 h = __float2bfloat16(v);
    Whi[idx] = h;
    Wlo[idx] = __float2bfloat16(v - __bfloat162float(h));
    return;
  }
  if (b < 160) {
    int idx = (b - 128) * 256 + tid;  // 0..8191
    int j = idx & 7;
    int l = (idx >> 3) & 63;
    int ks = (idx >> 9) & 1;
    int ct = idx >> 10;  // 0..7
    int k = ks * 32 + (l >> 4) * 8 + j;
    int col = ct * 16 + (l & 15);
    float v = (col < 64) ? Wq_w[k * 64 + col] : Wk_w[k * 64 + (col - 64)];
    __hip_bfloat16 h = __float2bfloat16(v);
    Wqhi[idx] = h;
    Wqlo[idx] = __float2bfloat16(v - __bfloat162float(h));
    return;
  }
  __shared__ float relemb[NREL * NDIM];
  for (int idx = tid; idx < NREL * NDIM; idx += 256) {
    int r = idx >> 6, i = idx & 63;
    const float* wr = W_r + (size_t)(r * NDIM + i) * NDIM;
    float s = 0.f;
#pragma unroll
    for (int o = 0; o < NDIM; ++o) s += wr[o];
    relemb[idx] = s * (1.0f / NDIM);
  }
  __syncthreads();
  for (int idx = tid; idx < NREL * NDIM; idx += 256) {
    int r = idx >> 6, o = idx & 63;
    float s = 0.f;
#pragma unroll
    for (int i = 0; i < NDIM; ++i) s += relemb[r * NDIM + i] * Wk_w[(NDIM + i) * NDIM + o];
    relkey[idx] = s;
  }
}

// K1c: xbf = bf16(x), vectorized grid-stride copy.
__global__ void k1c_xbf(const float* __restrict__ x, __hip_bfloat16* __restrict__ xbf,
                        int total4) {
  int i = blockIdx.x * blockDim.x + threadIdx.x;
  int stride = gridDim.x * blockDim.x;
  for (; i < total4; i += stride) {
    float4 v = *reinterpret_cast<const float4*>(x + (size_t)i * 4);
    ushort4 u;
    u.x = f2bf_u(v.x); u.y = f2bf_u(v.y); u.z = f2bf_u(v.z); u.w = f2bf_u(v.w);
    *reinterpret_cast<ushort4*>(reinterpret_cast<unsigned short*>(xbf) +
                                (size_t)i * 4) = u;
  }
}

// K1: MFMA, LDS-free. [Q|KB] = x @ [Wq|Wk1] via 3-term hi/lo bf16 split
// (xhi*whi + xhi*wlo + xlo*whi ~ fp32). Fused QR[n][r] = Q[n].relkey[r].
__global__ void __launch_bounds__(256) k1_mfma(
    const float* __restrict__ x,
    const float* __restrict__ Wq_bias,
    const __hip_bfloat16* __restrict__ Wqhi,
    const __hip_bfloat16* __restrict__ Wqlo,
    const float* __restrict__ relkey,
    float* __restrict__ Q, __hip_bfloat16* __restrict__ KBbf,
    float* __restrict__ QR, int n_nodes) {
  int tid = threadIdx.x;
  int lane = tid & 63, w = tid >> 6;
  int li = lane & 15, gr = lane >> 4;
  int n0 = blockIdx.x * 64;
  int arow = n0 + w * 16 + li;
  bool rv = arow < n_nodes;
  bf16x8v ahi[2], alo[2];
#pragma unroll
  for (int ks = 0; ks < 2; ++ks) {
    float xv[8];
    float4 v0 = make_float4(0.f, 0.f, 0.f, 0.f), v1 = v0;
    if (rv) {
      const float* xp = x + (size_t)arow * 64 + ks * 32 + gr * 8;
      v0 = *reinterpret_cast<const float4*>(xp);
      v1 = *reinterpret_cast<const float4*>(xp + 4);
    }
    xv[0] = v0.x; xv[1] = v0.y; xv[2] = v0.z; xv[3] = v0.w;
    xv[4] = v1.x; xv[5] = v1.y; xv[6] = v1.z; xv[7] = v1.w;
    unsigned short uh[8], ul[8];
#pragma unroll
    for (int j = 0; j < 8; ++j) {
      uh[j] = f2bf_u(xv[j]);
      ul[j] = f2bf_u(xv[j] - bfu2f(uh[j]));
    }
    ahi[ks] = __builtin_bit_cast(bf16x8v, *reinterpret_cast<uint4*>(uh));
    alo[ks] = __builtin_bit_cast(bf16x8v, *reinterpret_cast<uint4*>(ul));
  }
  const bf16x8v* bh = reinterpret_cast<const bf16x8v*>(Wqhi);
  const bf16x8v* bl = reinterpret_cast<const bf16x8v*>(Wqlo);
  f32x4v acc[8];
#pragma unroll
  for (int ct = 0; ct < 8; ++ct) acc[ct] = (f32x4v){0.f, 0.f, 0.f, 0.f};
#pragma unroll
  for (int ct = 0; ct < 8; ++ct) {
#pragma unroll
    for (int ks = 0; ks < 2; ++ks) {
      bf16x8v Bh = bh[(ct * 2 + ks) * 64 + lane];
      bf16x8v Bl = bl[(ct * 2 + ks) * 64 + lane];
      acc[ct] = __builtin_amdgcn_mfma_f32_16x16x32_bf16(ahi[ks], Bh, acc[ct], 0, 0, 0);
      acc[ct] = __builtin_amdgcn_mfma_f32_16x16x32_bf16(ahi[ks], Bl, acc[ct], 0, 0, 0);
      acc[ct] = __builtin_amdgcn_mfma_f32_16x16x32_bf16(alo[ks], Bh, acc[ct], 0, 0, 0);
    }
  }
  // epilogue: rows n = n0 + w*16 + gr*4 + reg; col = ct*16 + li
  float rk[NREL][4];
#pragma unroll
  for (int r = 0; r < NREL; ++r)
#pragma unroll
    for (int ct = 0; ct < 4; ++ct) rk[r][ct] = relkey[r * 64 + ct * 16 + li];
  float bq[4];
#pragma unroll
  for (int ct = 0; ct < 4; ++ct) bq[ct] = Wq_bias[ct * 16 + li];
#pragma unroll
  for (int reg = 0; reg < 4; ++reg) {
    int n = n0 + w * 16 + gr * 4 + reg;
    bool nv = n < n_nodes;
    float qv[4];
#pragma unroll
    for (int ct = 0; ct < 4; ++ct) {
      qv[ct] = acc[ct][reg] + bq[ct];
      if (nv) Q[(size_t)n * 64 + ct * 16 + li] = qv[ct];
    }
    if (nv) {
      unsigned short* kp = reinterpret_cast<unsigned short*>(KBbf) + ((size_t)n << 6);
#pragma unroll
      for (int ct = 4; ct < 8; ++ct)
        kp[(ct - 4) * 16 + li] = f2bf_u(acc[ct][reg]);
    }
#pragma unroll
    for (int r = 0; r < NREL; ++r) {
      float pq = qv[0] * rk[r][0] + qv[1] * rk[r][1] +
                 qv[2] * rk[r][2] + qv[3] * rk[r][3];
      pq += __shfl_xor(pq, 1, 64);
      pq += __shfl_xor(pq, 2, 64);
      pq += __shfl_xor(pq, 4, 64);
      pq += __shfl_xor(pq, 8, 64);
      if (nv && li == r) QR[(size_t)n * NREL + r] = pq;
    }
  }
}

// hist with rank output: rank[e] = arrival index of e within its dst bucket.
__global__ void k2_hist(const int* __restrict__ dst, int* __restrict__ counts,
                        int* __restrict__ rank, int E) {
  int e = blockIdx.x * blockDim.x + threadIdx.x;
  if (e < E) rank[e] = atomicAdd(&counts[dst[e]], 1);
}

// hierarchical scan: A (per-1024-block exclusive) -> B (block sums) -> C (add)
__global__ void scan_a(const int* __restrict__ counts, int* __restrict__ partial,
                       int* __restrict__ blocksums, int n) {
  __shared__ int wsum[4];
  int tid = threadIdx.x, lane = tid & 63, wv = tid >> 6;
  int base = blockIdx.x * 1024 + tid * 4;
  int4 v = make_int4(0, 0, 0, 0);
  if (base + 3 < n) v = *reinterpret_cast<const int4*>(counts + base);
  else {
    if (base < n) v.x = counts[base];
    if (base + 1 < n) v.y = counts[base + 1];
    if (base + 2 < n) v.z = counts[base + 2];
  }
  int tsum = v.x + v.y + v.z + v.w;
  int s = tsum;
#pragma unroll
  for (int off = 1; off < 64; off <<= 1) {
    int y = __shfl_up(s, off, 64);
    if (lane >= off) s += y;
  }
  if (lane == 63) wsum[wv] = s;
  __syncthreads();
  int woff = 0;
  for (int w = 0; w < wv; ++w) woff += wsum[w];
  int o0 = woff + s - tsum;
  if (base < n) partial[base] = o0;
  if (base + 1 < n) partial[base + 1] = o0 + v.x;
  if (base + 2 < n) partial[base + 2] = o0 + v.x + v.y;
  if (base + 3 < n) partial[base + 3] = o0 + v.x + v.y + v.z;
  if (tid == 255) blocksums[blockIdx.x] = woff + s;
}

__global__ void scan_b(const int* __restrict__ blocksums, int* __restrict__ blockoff,
                       int nb, int* __restrict__ offsets, int n) {
  int lane = threadIdx.x;
  int v = (lane < nb) ? blocksums[lane] : 0;
  int s = v;
#pragma unroll
  for (int off = 1; off < 64; off <<= 1) {
    int y = __shfl_up(s, off, 64);
    if (lane >= off) s += y;
  }
  if (lane < nb) blockoff[lane] = s - v;
  if (lane == 63) offsets[n] = s;
}

__global__ void scan_c(const int* __restrict__ partial, const int* __restrict__ blockoff,
                       int* __restrict__ offsets, int n) {
  int i = blockIdx.x * 256 + threadIdx.x;
  if (i < n) offsets[i] = partial[i] + blockoff[i >> 10];
}

// scatter: atomic-free. p = offsets[dst] + rank; one 8B store {src|et<<27, dst}.
__global__ void k2_scatter(const int* __restrict__ dst, const int* __restrict__ src,
                           const int* __restrict__ et, const int* __restrict__ rank,
                           const int* __restrict__ offsets,
                           int2* __restrict__ ed2, int E) {
  int e = blockIdx.x * blockDim.x + threadIdx.x;
  if (e < E) {
    int d = dst[e];
    int p = offsets[d] + rank[e];
    ed2[p] = make_int2(src[e] | (et[e] << 27), d);
  }
}

// K3: edge-parallel scores in CSR position order. 16 lanes per edge;
// packed int2 metadata; bf16 KB gathers; coalesced score store (lanes 0-3).
__global__ void k3_scores(const float* __restrict__ Q,
                          const __hip_bfloat16* __restrict__ KBbf,
                          const float* __restrict__ QR,
                          const int2* __restrict__ ed2,
                          float* __restrict__ scores, int E) {
  int tid = threadIdx.x;
  int lane = tid & 63;
  int li = lane & 15, sub = lane >> 4, wv = tid >> 6;
  int pos_base = blockIdx.x * 16 + wv * 4;
  int pos = pos_base + sub;
  int pc = min(pos, E - 1);
  int2 ed = ed2[pc];
  int sn = ed.x & SRC_MASK, r = (unsigned)ed.x >> 27;
  int dn = ed.y;
  float4 q = *reinterpret_cast<const float4*>(Q + (size_t)dn * 64 + li * 4);
  ushort4 u = *reinterpret_cast<const ushort4*>(
      reinterpret_cast<const unsigned short*>(KBbf) + ((size_t)sn << 6) + li * 4);
  float p = q.x * bfu2f(u.x) + q.y * bfu2f(u.y) + q.z * bfu2f(u.z) + q.w * bfu2f(u.w);
#pragma unroll
  for (int off = 1; off < 16; off <<= 1) p += __shfl_xor(p, off, 64);
  float sc = (p + QR[(size_t)dn * NREL + r]) * SCALE;
  float sg = __shfl(sc, (lane & 3) * 16, 64);
  if (lane < 4 && pos_base + lane < E) scores[pos_base + lane] = sg;
}

#define ACC_SWITCH(rr, v)                    \
  switch (rr) {                              \
    case 0: acc[0] += (v); break;            \
    case 1: acc[1] += (v); break;            \
    case 2: acc[2] += (v); break;            \
    case 3: acc[3] += (v); break;            \
    case 4: acc[4] += (v); break;            \
    case 5: acc[5] += (v); break;            \
    case 6: acc[6] += (v); break;            \
    case 7: acc[7] += (v); break;            \
  }

// K4: one wave per node; packed metadata; bf16 x gathers; 4x-unrolled
// readlane broadcast loop (4 gathers in flight).
__global__ void k4_agg(const __hip_bfloat16* __restrict__ xb,
                       const float* __restrict__ scores,
                       const int* __restrict__ offsets,
                       const int2* __restrict__ ed2,
                       __hip_bfloat16* __restrict__ A, int n_nodes) {
  int lane = threadIdx.x & 63, wv = threadIdx.x >> 6;
  int n = blockIdx.x * 4 + wv;
  if (n >= n_nodes) return;
  const unsigned short* xbp = reinterpret_cast<const unsigned short*>(xb);
  int s0 = offsets[n], s1 = offsets[n + 1];
  int deg = s1 - s0;
  float acc[8] = {0.f, 0.f, 0.f, 0.f, 0.f, 0.f, 0.f, 0.f};
  if (deg > 0 && deg <= 64) {
    int p = s0 + lane;
    bool valid = p < s1;
    float sc = valid ? scores[p] : -1e30f;
    int se = valid ? ed2[p].x : 0;
    float m = wave_max64(sc);
    float ex = valid ? __expf(sc - m) : 0.f;
    float t = wave_sum64(ex);
    float wl = ex * (1.0f / t);
    int i = 0;
    for (; i + 4 <= deg; i += 4) {
      float w0 = rdl_f(wl, i), w1 = rdl_f(wl, i + 1);
      float w2 = rdl_f(wl, i + 2), w3 = rdl_f(wl, i + 3);
      int se0 = __builtin_amdgcn_readlane(se, i);
      int se1 = __builtin_amdgcn_readlane(se, i + 1);
      int se2 = __builtin_amdgcn_readlane(se, i + 2);
      int se3 = __builtin_amdgcn_readlane(se, i + 3);
      unsigned short u0 = xbp[((size_t)(se0 & SRC_MASK) << 6) + lane];
      unsigned short u1 = xbp[((size_t)(se1 & SRC_MASK) << 6) + lane];
      unsigned short u2 = xbp[((size_t)(se2 & SRC_MASK) << 6) + lane];
      unsigned short u3 = xbp[((size_t)(se3 & SRC_MASK) << 6) + lane];
      float v0 = w0 * bfu2f(u0);
      float v1 = w1 * bfu2f(u1);
      float v2 = w2 * bfu2f(u2);
      float v3 = w3 * bfu2f(u3);
      int r0 = (unsigned)se0 >> 27, r1 = (unsigned)se1 >> 27;
      int r2 = (unsigned)se2 >> 27, r3 = (unsigned)se3 >> 27;
      ACC_SWITCH(r0, v0)
      ACC_SWITCH(r1, v1)
      ACC_SWITCH(r2, v2)
      ACC_SWITCH(r3, v3)
    }
    for (; i < deg; ++i) {
      float wgt = rdl_f(wl, i);
      int sei = __builtin_amdgcn_readlane(se, i);
      float v = wgt * bfu2f(xbp[((size_t)(sei & SRC_MASK) << 6) + lane]);
      int rr = (unsigned)sei >> 27;
      ACC_SWITCH(rr, v)
    }
  } else if (deg > 64) {
    float m = -1e30f;
    for (int c = s0; c < s1; c += 64) {
      int p = c + lane;
      float s = (p < s1) ? scores[p] : -1e30f;
      m = fmaxf(m, s);
    }
    m = wave_max64(m);
    float t = 0.f;
    for (int c = s0; c < s1; c += 64) {
      int p = c + lane;
      t += (p < s1) ? __expf(scores[p] - m) : 0.f;
    }
    t = wave_sum64(t);
    float inv = 1.0f / t;
    for (int c = s0; c < s1; c += 64) {
      int p = c + lane;
      bool valid = p < s1;
      int se = valid ? ed2[p].x : 0;
      float wl = valid ? __expf(scores[p] - m) * inv : 0.f;
      int cnt = min(64, s1 - c);
      for (int i = 0; i < cnt; ++i) {
        float wgt = rdl_f(wl, i);
        int sei = __builtin_amdgcn_readlane(se, i);
        float v = wgt * bfu2f(xbp[((size_t)(sei & SRC_MASK) << 6) + lane]);
        int rr = (unsigned)sei >> 27;
        ACC_SWITCH(rr, v)
      }
    }
  }
#pragma unroll
  for (int r = 0; r < 8; ++r)
    A[(size_t)n * 512 + r * 64 + lane] = __float2bfloat16(acc[r]);
}

// K5: out = relu(LN(A(50000x512 bf16) @ (Whi+Wlo) + bias)) via MFMA, LDS-free.
__global__ void __launch_bounds__(256) k5_mfma_ln(
    const __hip_bfloat16* __restrict__ A,
    const __hip_bfloat16* __restrict__ Whi,
    const __hip_bfloat16* __restrict__ Wlo,
    const float* __restrict__ bias,
    const float* __restrict__ ln_g, const float* __restrict__ ln_b,
    float* __restrict__ out, int n_nodes) {
  int tid = threadIdx.x;
  int lane = tid & 63, w = tid >> 6;
  int li = lane & 15, gr = lane >> 4;
  int n0 = blockIdx.x * 64;
  int arow_n = n0 + w * 16 + li;
  bool rvalid = arow_n < n_nodes;
  const __hip_bfloat16* arow = A + (size_t)arow_n * 512 + gr * 8;
  const bf16x8v* wh = reinterpret_cast<const bf16x8v*>(Whi);
  const bf16x8v* wl = reinterpret_cast<const bf16x8v*>(Wlo);
  f32x4v acc[4];
#pragma unroll
  for (int ct = 0; ct < 4; ++ct) acc[ct] = (f32x4v){0.f, 0.f, 0.f, 0.f};
  for (int ks = 0; ks < 16; ++ks) {
    uint4 au = make_uint4(0u, 0u, 0u, 0u);
    if (rvalid) au = *reinterpret_cast<const uint4*>(arow + ks * 32);
    bf16x8v a = __builtin_bit_cast(bf16x8v, au);
#pragma unroll
    for (int ct = 0; ct < 4; ++ct) {
      bf16x8v bh = wh[(ct * 16 + ks) * 64 + lane];
      bf16x8v bl = wl[(ct * 16 + ks) * 64 + lane];
      acc[ct] = __builtin_amdgcn_mfma_f32_16x16x32_bf16(a, bh, acc[ct], 0, 0, 0);
      acc[ct] = __builtin_amdgcn_mfma_f32_16x16x32_bf16(a, bl, acc[ct], 0, 0, 0);
    }
  }
  float bi[4], g[4], bb[4];
#pragma unroll
  for (int ct = 0; ct < 4; ++ct) {
    int col = ct * 16 + li;
    bi[ct] = bias[col];
    g[ct] = ln_g[col];
    bb[ct] = ln_b[col];
  }
#pragma unroll
  for (int reg = 0; reg < 4; ++reg) {
    float v[4];
#pragma unroll
    for (int ct = 0; ct < 4; ++ct) v[ct] = acc[ct][reg] + bi[ct];
    float s = v[0] + v[1] + v[2] + v[3];
    s += __shfl_xor(s, 1, 64);
    s += __shfl_xor(s, 2, 64);
    s += __shfl_xor(s, 4, 64);
    s += __shfl_xor(s, 8, 64);
    float mu = s * (1.0f / 64.0f);
    float sq = 0.f;
#pragma unroll
    for (int ct = 0; ct < 4; ++ct) {
      float d = v[ct] - mu;
      sq += d * d;
    }
    sq += __shfl_xor(sq, 1, 64);
    sq += __shfl_xor(sq, 2, 64);
    sq += __shfl_xor(sq, 4, 64);
    sq += __shfl_xor(sq, 8, 64);
    float inv = rsqrtf(sq * (1.0f / 64.0f) + LN_EPS);
    int n = n0 + w * 16 + gr * 4 + reg;
    if (n < n_nodes) {
#pragma unroll
      for (int ct = 0; ct < 4; ++ct) {
        float y = (v[ct] - mu) * inv * g[ct] + bb[ct];
        out[(size_t)n * 64 + ct * 16 + li] = fmaxf(y, 0.f);
      }
    }
  }
}

extern "C" void kernel_launch(void* const* d_in, const int* in_sizes, int n_in,
                              void* d_out, int out_size, void* d_ws, size_t ws_size,
                              hipStream_t stream) {
  (void)n_in; (void)out_size; (void)ws_size;
  const float* x = (const float*)d_in[0];
  const int* ei = (const int*)d_in[1];
  const int* et = (const int*)d_in[2];
  const float* W_r = (const float*)d_in[4];
  const float* Wq_w = (const float*)d_in[5];
  const float* Wq_b = (const float*)d_in[6];
  const float* Wk_w = (const float*)d_in[7];
  const float* bias = (const float*)d_in[10];
  const float* ln_g = (const float*)d_in[11];
  const float* ln_b = (const float*)d_in[12];

  int N = in_sizes[0] / NDIM;
  int E = in_sizes[2];
  const int* srcp = ei;
  const int* dstp = ei + E;

  char* p = (char*)d_ws;
  auto alloc = [&](size_t bytes) {
    void* r = (void*)p;
    p += (bytes + 255) & ~(size_t)255;
    return r;
  };
  float* Q = (float*)alloc((size_t)N * NDIM * 4);
  __hip_bfloat16* KBbf = (__hip_bfloat16*)alloc((size_t)N * NDIM * 2);
  float* QR = (float*)alloc((size_t)N * NREL * 4);
  float* relkey = (float*)alloc(NREL * NDIM * 4);
  __hip_bfloat16* xbf = (__hip_bfloat16*)alloc((size_t)N * NDIM * 2);
  int* counts = (int*)alloc((size_t)N * 4);
  int* partial = (int*)alloc((size_t)N * 4);
  int* offsets = (int*)alloc((size_t)(N + 1) * 4);
  int* rank = (int*)alloc((size_t)E * 4);
  int* blocksums = (int*)alloc(64 * 4);
  int* blockoff = (int*)alloc(64 * 4);
  int2* ed2 = (int2*)alloc((size_t)E * 8);
  float* scores = (float*)alloc((size_t)E * 4);
  __hip_bfloat16* A = (__hip_bfloat16*)alloc((size_t)N * (NREL * NDIM) * 2);
  __hip_bfloat16* Whi = (__hip_bfloat16*)alloc(4 * 16 * 64 * 8 * 2);
  __hip_bfloat16* Wlo = (__hip_bfloat16*)alloc(4 * 16 * 64 * 8 * 2);
  __hip_bfloat16* Wqhi = (__hip_bfloat16*)alloc(8 * 2 * 64 * 8 * 2);
  __hip_bfloat16* Wqlo = (__hip_bfloat16*)alloc(8 * 2 * 64 * 8 * 2);

  int nscan = (N + 1023) / 1024;

  hipMemsetAsync(counts, 0, (size_t)N * 4, stream);
  k0_fused<<<161, 256, 0, stream>>>(W_r, Wq_w, Wk_w, Whi, Wlo, Wqhi, Wqlo, relkey);
  k1c_xbf<<<1024, 256, 0, stream>>>(x, xbf, N * NDIM / 4);
  k1_mfma<<<(N + 63) / 64, 256, 0, stream>>>(x, Wq_b, Wqhi, Wqlo, relkey, Q, KBbf,
                                             QR, N);
  k2_hist<<<(E + 255) / 256, 256, 0, stream>>>(dstp, counts, rank, E);
  scan_a<<<nscan, 256, 0, stream>>>(counts, partial, blocksums, N);
  scan_b<<<1, 64, 0, stream>>>(blocksums, blockoff, nscan, offsets, N);
  scan_c<<<(N + 255) / 256, 256, 0, stream>>>(partial, blockoff, offsets, N);
  k2_scatter<<<(E + 255) / 256, 256, 0, stream>>>(dstp, srcp, et, rank, offsets, ed2, E);
  k3_scores<<<(E + 15) / 16, 256, 0, stream>>>(Q, KBbf, QR, ed2, scores, E);
  k4_agg<<<(N + 3) / 4, 256, 0, stream>>>(xbf, scores, offsets, ed2, A, N);
  k5_mfma_ln<<<(N + 63) / 64, 256, 0, stream>>>(A, Whi, Wlo, bias, ln_g, ln_b,
                                                (float*)d_out, N);
}